// Round 16
// baseline (640.302 us; speedup 1.0000x reference)
//
#include <hip/hip_runtime.h>
#include <cmath>

// ---------------------------------------------------------------------------
// SutraV04 round 15 = round 14 (569 us) + smsg_k eliminated: S' computed
// on-the-fly in the U-GEMM A-gather (MODE 12). Saves 4 launches + 67 MB
// S' round-trip; identical numerics (same f2bf point).
// ---------------------------------------------------------------------------

constexpr int N_   = 512;
constexpr int B_   = 32;
constexpr int BN_  = B_ * N_;   // 16384
constexpr int M1_  = BN_ * 4;   // 65536

typedef short bf16x8 __attribute__((ext_vector_type(8)));
typedef float f32x4  __attribute__((ext_vector_type(4)));

__device__ __forceinline__ float gelu_f(float x) {
  return 0.5f * x * (1.0f + erff(x * 0.70710678118654752440f));
}
__device__ __forceinline__ float sigm_f(float x) {
  return 1.0f / (1.0f + expf(-x));
}
__device__ __forceinline__ unsigned short f2bf(float f) {
  union { float f; unsigned int u; } c; c.f = f;
  unsigned int u = c.u;
  u += 0x7FFFu + ((u >> 16) & 1u);
  return (unsigned short)(u >> 16);
}
__device__ __forceinline__ float bf2f(unsigned short u) {
  union { unsigned int u; float f; } c; c.u = ((unsigned int)u) << 16;
  return c.f;
}
__device__ __forceinline__ int phys(int g, int r) {      // 64-row tiles
  return ((g << 6) | (r ^ g)) << 3;
}
__device__ __forceinline__ int phys128(int g, int r) {   // 128-row tiles
  return ((g << 7) | (r ^ g)) << 3;
}
__device__ __forceinline__ int phys16(int g, int r) {    // 16-row tiles
  return ((g << 4) | (r ^ g)) << 3;
}

// XCD-aware block remap: same-A-panel blocks (all nB of a chunk of mB) land
// on one XCD (flat % 8). Bijective; falls back to identity if nby % 8 != 0.
__device__ __forceinline__ void xcd_map(int& mB, int& nB) {
  int nbx = gridDim.x, nby = gridDim.y;
  if ((nby & 7) == 0) {
    int flat = blockIdx.y * nbx + blockIdx.x;
    int chunk = nby >> 3;
    int xcd = flat & 7, s2 = flat >> 3;
    int q = s2 / nbx;
    mB = xcd * chunk + q;
    nB = s2 - q * nbx;
  } else {
    mB = blockIdx.y; nB = blockIdx.x;
  }
}

// ---- 128x128-tile MFMA GEMM ----------------------------------------------
// AMODE: 0 f32 [m][K]; 1 bf16 [m][K].  EPI: 0 none, 1 gelu. COUT: 0 f32, 1 bf16.
template<int AMODE, int EPI, int COUT>
__global__ __launch_bounds__(256)
void gemm_big(const void* __restrict__ A, const unsigned short* __restrict__ Bt,
              const float* __restrict__ bias, void* __restrict__ C,
              int M, int Nn, int K, int bstride, int ldC)
{
  __shared__ short As[4 * 128 * 8];
  __shared__ short Bs[4 * 128 * 8];
  const int t  = threadIdx.x;
  int mB, nB;
  xcd_map(mB, nB);
  const int m0 = mB * 128, n0 = nB * 128;
  const int lane = t & 63, w = t >> 6;
  const int wr = w >> 1, wc = w & 1;
  const int fr = lane & 15, fg = lane >> 4;

  f32x4 acc[4][4] = {};

  for (int k0 = 0; k0 < K; k0 += 32) {
    #pragma unroll
    for (int c = 0; c < 2; ++c) {
      int idx = t + c * 256;
      int row = idx >> 2, g = idx & 3;
      int kk = k0 + g * 8;
      bf16x8 av;
      if constexpr (AMODE == 1) {
        av = *(const bf16x8*)&((const unsigned short*)A)[(size_t)(m0 + row) * K + kk];
      } else {
        const float4* p = (const float4*)&((const float*)A)[(size_t)(m0 + row) * K + kk];
        float4 a = p[0], b = p[1];
        av[0]=(short)f2bf(a.x); av[1]=(short)f2bf(a.y); av[2]=(short)f2bf(a.z); av[3]=(short)f2bf(a.w);
        av[4]=(short)f2bf(b.x); av[5]=(short)f2bf(b.y); av[6]=(short)f2bf(b.z); av[7]=(short)f2bf(b.w);
      }
      *(bf16x8*)&As[phys128(g, row)] = av;
      *(bf16x8*)&Bs[phys128(g, row)] =
          *(const bf16x8*)&Bt[(size_t)(n0 + row) * bstride + kk];
    }
    __syncthreads();

    bf16x8 a[4], b[4];
    #pragma unroll
    for (int i = 0; i < 4; ++i)
      a[i] = *(const bf16x8*)&As[phys128(fg, wr * 64 + i * 16 + fr)];
    #pragma unroll
    for (int j = 0; j < 4; ++j)
      b[j] = *(const bf16x8*)&Bs[phys128(fg, wc * 64 + j * 16 + fr)];
    #pragma unroll
    for (int i = 0; i < 4; ++i)
      #pragma unroll
      for (int j = 0; j < 4; ++j)
        acc[i][j] = __builtin_amdgcn_mfma_f32_16x16x32_bf16(a[i], b[j], acc[i][j], 0, 0, 0);
    __syncthreads();
  }

  #pragma unroll
  for (int i = 0; i < 4; ++i)
    #pragma unroll
    for (int j = 0; j < 4; ++j) {
      int col = n0 + wc * 64 + j * 16 + fr;
      float bcol = bias ? bias[col] : 0.0f;
      #pragma unroll
      for (int r = 0; r < 4; ++r) {
        int row = m0 + wr * 64 + i * 16 + fg * 4 + r;
        float vv = acc[i][j][r] + bcol;
        if constexpr (EPI == 1) vv = gelu_f(vv);
        if constexpr (COUT == 0)
          ((float*)C)[(size_t)row * ldC + col] = vv;
        else
          ((unsigned short*)C)[(size_t)row * ldC + col] = f2bf(vv);
      }
    }
}

// ---- 64-tile gather GEMM --------------------------------------------------
// MODE: 6 emb/pos rows; 8 transposed f32 gather P2[k*256+m]; 9 bf16 patch-mean;
//       11 concat(f32 A | bf16 P2); 12 concat(bf16 h | on-the-fly S' from hsn)
// BSRC: 0 bf16 Bt; 1 fp32.  EPI: 0 none, 1 gelu.  COUT: 0 f32, 1 bf16.
template<int MODE, int BSRC, int EPI, int COUT>
__global__ __launch_bounds__(256)
void gemm_mfma(const float* __restrict__ A, const void* __restrict__ Bsrc,
               const float* __restrict__ bias, void* __restrict__ C,
               int M, int Nn, int K, int bstride, int ldC,
               const float* __restrict__ P2,
               const float* __restrict__ emb, const float* __restrict__ pos)
{
  __shared__ short As[4 * 64 * 8];
  __shared__ short Bs[4 * 64 * 8];
  const int tid  = threadIdx.x;
  int mB, nB;
  xcd_map(mB, nB);
  const int m0 = mB * 64, n0 = nB * 64;
  const int srow = tid >> 2, sg = tid & 3;
  const int lane = tid & 63, w = tid >> 6;
  const int wr   = w >> 1,  wc = w & 1;
  const int fr   = lane & 15, fg = lane >> 4;

  f32x4 acc[2][2] = {};

  for (int k0 = 0; k0 < K; k0 += 32) {
    {
      int m = m0 + srow, k = k0 + sg * 8;
      bf16x8 tv;
      if constexpr (MODE == 12) {
        if (k < 256) {
          tv = *(const bf16x8*)&((const unsigned short*)A)[(size_t)m * 256 + k];
        } else {
          const unsigned short* hsn = (const unsigned short*)P2;
          int d = k - 256;
          int n = m & (N_ - 1);
          bf16x8 hs = *(const bf16x8*)&hsn[(size_t)m * 512 + d];
          float a8[8] = {};
          #pragma unroll
          for (int kk = 0; kk < 5; ++kk) {
            if (n + kk - 4 >= 0) {
              bf16x8 hv = *(const bf16x8*)&hsn[(size_t)(m + kk - 4) * 512 + 256 + d];
              #pragma unroll
              for (int e = 0; e < 8; ++e)
                a8[e] += gelu_f(bf2f((unsigned short)hs[e]) + bf2f((unsigned short)hv[e]));
            }
          }
          float sc1 = 1.0f / (float)((n < 4 ? n : 4) + 1);
          #pragma unroll
          for (int e = 0; e < 8; ++e) tv[e] = (short)f2bf(a8[e] * sc1);
        }
      } else if constexpr (MODE == 11) {
        if (k < 256) {
          const float4* p = (const float4*)(A + (size_t)m * 256 + k);
          float4 a = p[0], b = p[1];
          tv[0]=(short)f2bf(a.x); tv[1]=(short)f2bf(a.y); tv[2]=(short)f2bf(a.z); tv[3]=(short)f2bf(a.w);
          tv[4]=(short)f2bf(b.x); tv[5]=(short)f2bf(b.y); tv[6]=(short)f2bf(b.z); tv[7]=(short)f2bf(b.w);
        } else {
          tv = *(const bf16x8*)&((const unsigned short*)P2)[(size_t)m * 256 + (k - 256)];
        }
      } else {
        float v[8];
        if constexpr (MODE == 6) {
          const float* src = nullptr;
          if (m < 256) src = emb + (size_t)m * 256 + k;
          else if (m < 260) src = pos + (size_t)(m - 256) * 256 + k;
          if (src) {
            const float4* p = (const float4*)src;
            float4 a = p[0], b = p[1];
            v[0]=a.x; v[1]=a.y; v[2]=a.z; v[3]=a.w; v[4]=b.x; v[5]=b.y; v[6]=b.z; v[7]=b.w;
          } else {
            #pragma unroll
            for (int j = 0; j < 8; ++j) v[j] = 0.f;
          }
        } else if constexpr (MODE == 8) {
          #pragma unroll
          for (int j = 0; j < 8; ++j) v[j] = P2[(size_t)(k + j) * 256 + m];
        } else { // 9
          const unsigned short* Ab = (const unsigned short*)A;
          const unsigned short* base = Ab + (size_t)m * 1024 + k;
          bf16x8 r0 = *(const bf16x8*)(base);
          bf16x8 r1 = *(const bf16x8*)(base + 256);
          bf16x8 r2 = *(const bf16x8*)(base + 512);
          bf16x8 r3 = *(const bf16x8*)(base + 768);
          #pragma unroll
          for (int j = 0; j < 8; ++j)
            v[j] = 0.25f * (bf2f((unsigned short)r0[j]) + bf2f((unsigned short)r1[j]) +
                            bf2f((unsigned short)r2[j]) + bf2f((unsigned short)r3[j]));
        }
        #pragma unroll
        for (int j = 0; j < 8; ++j) tv[j] = (short)f2bf(v[j]);
      }
      *(bf16x8*)&As[phys(sg, srow)] = tv;
    }
    if constexpr (BSRC == 0) {
      const unsigned short* Bt = (const unsigned short*)Bsrc;
      *(bf16x8*)&Bs[phys(sg, srow)] =
          *(const bf16x8*)&Bt[(size_t)(n0 + srow) * bstride + k0 + sg * 8];
    } else {
      const float* Bf = (const float*)Bsrc;
      const float4* p = (const float4*)(Bf + (size_t)(n0 + srow) * bstride + k0 + sg * 8);
      float4 a = p[0], b = p[1];
      bf16x8 tv;
      tv[0]=(short)f2bf(a.x); tv[1]=(short)f2bf(a.y); tv[2]=(short)f2bf(a.z); tv[3]=(short)f2bf(a.w);
      tv[4]=(short)f2bf(b.x); tv[5]=(short)f2bf(b.y); tv[6]=(short)f2bf(b.z); tv[7]=(short)f2bf(b.w);
      *(bf16x8*)&Bs[phys(sg, srow)] = tv;
    }
    __syncthreads();

    bf16x8 a0 = *(const bf16x8*)&As[phys(fg, wr * 32 + fr)];
    bf16x8 a1 = *(const bf16x8*)&As[phys(fg, wr * 32 + 16 + fr)];
    bf16x8 b0 = *(const bf16x8*)&Bs[phys(fg, wc * 32 + fr)];
    bf16x8 b1 = *(const bf16x8*)&Bs[phys(fg, wc * 32 + 16 + fr)];
    acc[0][0] = __builtin_amdgcn_mfma_f32_16x16x32_bf16(a0, b0, acc[0][0], 0, 0, 0);
    acc[0][1] = __builtin_amdgcn_mfma_f32_16x16x32_bf16(a0, b1, acc[0][1], 0, 0, 0);
    acc[1][0] = __builtin_amdgcn_mfma_f32_16x16x32_bf16(a1, b0, acc[1][0], 0, 0, 0);
    acc[1][1] = __builtin_amdgcn_mfma_f32_16x16x32_bf16(a1, b1, acc[1][1], 0, 0, 0);
    __syncthreads();
  }

  #pragma unroll
  for (int i = 0; i < 2; ++i) {
    #pragma unroll
    for (int j = 0; j < 2; ++j) {
      int row0 = m0 + wr * 32 + i * 16 + fg * 4;
      int col  = n0 + wc * 32 + j * 16 + fr;
      float bcol = bias ? bias[col] : 0.0f;
      #pragma unroll
      for (int r = 0; r < 4; ++r) {
        float vv = acc[i][j][r] + bcol;
        if constexpr (EPI == 1) vv = gelu_f(vv);
        int row = row0 + r;
        if constexpr (COUT == 0)
          ((float*)C)[(size_t)row * ldC + col] = vv;
        else
          ((unsigned short*)C)[(size_t)row * ldC + col] = f2bf(vv);
      }
    }
  }
}

// ---- fused upd-GEMM + residual + LN; 16-row full-width tile ---------------
template<int OUTM>
__global__ __launch_bounds__(256)
void gemm_ln(const unsigned short* __restrict__ U, const unsigned short* __restrict__ u2T,
             const float* __restrict__ bias, unsigned short* __restrict__ h,
             const float* __restrict__ g, const float* __restrict__ bb,
             const float* __restrict__ hp, float* __restrict__ outp)
{
  __shared__ short As[4 * 16 * 8];
  __shared__ short Bs[4 * 256 * 8];
  __shared__ float psum[4][16], pssq[4][16];
  const int m0 = blockIdx.x * 16;
  const int t  = threadIdx.x;
  const int lane = t & 63, w = t >> 6;
  const int fr = lane & 15, fg = lane >> 4;

  f32x4 acc[4] = {};
  for (int k0 = 0; k0 < 256; k0 += 32) {
    if (t < 64) {
      int row = t >> 2, gq = t & 3;
      *(bf16x8*)&As[phys16(gq, row)] =
          *(const bf16x8*)&U[(size_t)(m0 + row) * 256 + k0 + gq * 8];
    }
    const unsigned short* brow = u2T + (size_t)t * 256 + k0;
    #pragma unroll
    for (int gq = 0; gq < 4; ++gq)
      *(bf16x8*)&Bs[((gq << 8) | (t ^ gq)) << 3] = *(const bf16x8*)(brow + gq * 8);
    __syncthreads();
    bf16x8 a = *(const bf16x8*)&As[phys16(fg, fr)];
    #pragma unroll
    for (int j = 0; j < 4; ++j) {
      int n = 64 * w + 16 * j + fr;
      bf16x8 b = *(const bf16x8*)&Bs[((fg << 8) | (n ^ fg)) << 3];
      acc[j] = __builtin_amdgcn_mfma_f32_16x16x32_bf16(a, b, acc[j], 0, 0, 0);
    }
    __syncthreads();
  }

  float bcol[4], gv[4], bv[4];
  #pragma unroll
  for (int j = 0; j < 4; ++j) {
    int col = 64 * w + 16 * j + fr;
    bcol[j] = bias[col]; gv[j] = g[col]; bv[j] = bb[col];
  }
  float vsum[4] = {}, vssq[4] = {};
  #pragma unroll
  for (int j = 0; j < 4; ++j) {
    int col = 64 * w + 16 * j + fr;
    #pragma unroll
    for (int r = 0; r < 4; ++r) {
      int row = m0 + 4 * fg + r;
      float v = acc[j][r] + bcol[j] + bf2f(h[(size_t)row * 256 + col]);
      acc[j][r] = v;
      vsum[r] += v;
      vssq[r] += v * v;
    }
  }
  #pragma unroll
  for (int off = 1; off < 16; off <<= 1) {
    #pragma unroll
    for (int r = 0; r < 4; ++r) {
      vsum[r] += __shfl_xor(vsum[r], off, 64);
      vssq[r] += __shfl_xor(vssq[r], off, 64);
    }
  }
  if (fr == 0) {
    #pragma unroll
    for (int r = 0; r < 4; ++r) {
      psum[w][4 * fg + r] = vsum[r];
      pssq[w][4 * fg + r] = vssq[r];
    }
  }
  __syncthreads();

  float rem = 0.f;
  if constexpr (OUTM == 3) rem = 1.0f - hp[m0 >> 9];
  #pragma unroll
  for (int r = 0; r < 4; ++r) {
    int rr = 4 * fg + r;
    float s  = psum[0][rr] + psum[1][rr] + psum[2][rr] + psum[3][rr];
    float q2 = pssq[0][rr] + pssq[1][rr] + pssq[2][rr] + pssq[3][rr];
    float mean = s * (1.0f / 256.0f);
    float var  = q2 * (1.0f / 256.0f) - mean * mean;
    float inv  = rsqrtf(var + 1e-5f);
    int row = m0 + rr;
    #pragma unroll
    for (int j = 0; j < 4; ++j) {
      int col = 64 * w + 16 * j + fr;
      float y = (acc[j][r] - mean) * inv * gv[j] + bv[j];
      h[(size_t)row * 256 + col] = f2bf(y);
      if constexpr (OUTM == 3) outp[(size_t)row * 256 + col] += rem * y;
    }
  }
}

// ---- causal tri-tile scores (bf16 out), XCD-swizzled ----------------------
__global__ __launch_bounds__(256)
void scores_tri(const unsigned short* __restrict__ qkv, unsigned short* __restrict__ sc)
{
  int flat = blockIdx.x;
  int xcd = flat & 7, s = flat >> 3;
  int bhi = s / 36, tile = s - bhi * 36;
  int b = bhi * 8 + xcd;
  int ti = 0;
  while ((ti + 1) * (ti + 2) / 2 <= tile) ++ti;
  int tj = tile - ti * (ti + 1) / 2;
  const int m0 = ti * 64, n0 = tj * 64;
  const unsigned short* Aq = qkv + (size_t)b * N_ * 768;
  const unsigned short* Bk = Aq + 256;

  __shared__ short As[4 * 64 * 8];
  __shared__ short Bs[4 * 64 * 8];
  const int tid  = threadIdx.x;
  const int srow = tid >> 2, sg = tid & 3;
  const int lane = tid & 63, w = tid >> 6;
  const int wr   = w >> 1,  wc = w & 1;
  const int fr   = lane & 15, fg = lane >> 4;

  f32x4 acc[2][2] = {};
  for (int k0 = 0; k0 < 256; k0 += 32) {
    *(bf16x8*)&As[phys(sg, srow)] =
        *(const bf16x8*)&Aq[(size_t)(m0 + srow) * 768 + k0 + sg * 8];
    *(bf16x8*)&Bs[phys(sg, srow)] =
        *(const bf16x8*)&Bk[(size_t)(n0 + srow) * 768 + k0 + sg * 8];
    __syncthreads();
    bf16x8 a0 = *(const bf16x8*)&As[phys(fg, wr * 32 + fr)];
    bf16x8 a1 = *(const bf16x8*)&As[phys(fg, wr * 32 + 16 + fr)];
    bf16x8 b0 = *(const bf16x8*)&Bs[phys(fg, wc * 32 + fr)];
    bf16x8 b1 = *(const bf16x8*)&Bs[phys(fg, wc * 32 + 16 + fr)];
    acc[0][0] = __builtin_amdgcn_mfma_f32_16x16x32_bf16(a0, b0, acc[0][0], 0, 0, 0);
    acc[0][1] = __builtin_amdgcn_mfma_f32_16x16x32_bf16(a0, b1, acc[0][1], 0, 0, 0);
    acc[1][0] = __builtin_amdgcn_mfma_f32_16x16x32_bf16(a1, b0, acc[1][0], 0, 0, 0);
    acc[1][1] = __builtin_amdgcn_mfma_f32_16x16x32_bf16(a1, b1, acc[1][1], 0, 0, 0);
    __syncthreads();
  }
  unsigned short* scb = sc + (size_t)b * N_ * N_;
  #pragma unroll
  for (int i = 0; i < 2; ++i) {
    #pragma unroll
    for (int j = 0; j < 2; ++j) {
      int row0 = m0 + wr * 32 + i * 16 + fg * 4;
      int col  = n0 + wc * 32 + j * 16 + fr;
      #pragma unroll
      for (int r = 0; r < 4; ++r) {
        int row = row0 + r;
        float vv = acc[i][j][r] * 0.0625f;
        if (col > row) vv = -__builtin_inff();
        scb[(size_t)row * N_ + col] = f2bf(vv);
      }
    }
  }
}

// ---- weight prep ----------------------------------------------------------
struct PrepJobs {
  const float* src[12];
  unsigned short* dst[12];
  int rows[12];
  int dstride[12];
  int strt[12];
};
__global__ __launch_bounds__(256)
void prep_w_k(PrepJobs pj)
{
  int jid = blockIdx.y;
  const float* src = pj.src[jid];
  unsigned short* dst = pj.dst[jid];
  int ds = pj.dstride[jid];
  int total = pj.rows[jid] << 8;
  if (pj.strt[jid]) {
    for (int i = blockIdx.x * 256 + threadIdx.x; i < total; i += gridDim.x * 256) {
      int k = i & 255, n = i >> 8;
      dst[(size_t)n * ds + k] = f2bf(src[i]);
    }
  } else {
    for (int i = blockIdx.x * 256 + threadIdx.x; i < total; i += gridDim.x * 256) {
      int k = i & 255, n = i >> 8;
      dst[(size_t)n * ds + k] = f2bf(src[(size_t)k * 256 + n]);
    }
  }
}

// ---- bias prep ------------------------------------------------------------
__global__ __launch_bounds__(256)
void biasprep_k(const float* __restrict__ upd_b1, const float* __restrict__ msg_b2,
                const float* __restrict__ upd_w1, const float* __restrict__ msg_b1,
                const float* __restrict__ o_b, const float* __restrict__ br_w,
                const float* __restrict__ br_b, const float* __restrict__ q_b,
                const float* __restrict__ k_b, const float* __restrict__ v_b,
                float* __restrict__ biasU, float* __restrict__ biasHsn,
                float* __restrict__ biasB2, float* __restrict__ bQKV)
{
  int c = threadIdx.x;
  float s = upd_b1[c];
  for (int k = 0; k < 256; ++k)
    s += msg_b2[k] * upd_w1[(size_t)(256 + k) * 256 + c];
  biasU[c] = s;
  biasHsn[c] = msg_b1[c];
  biasHsn[256 + c] = 0.f;
  float s2 = br_b[c];
  for (int k = 0; k < 256; ++k)
    s2 += o_b[k] * br_w[(size_t)k * 256 + c];
  biasB2[c] = s2;
  bQKV[c] = q_b[c]; bQKV[256 + c] = k_b[c]; bQKV[512 + c] = v_b[c];
}

// ---- GRU pointwise (vectorized, 4 elems/thread, h bf16) -------------------
template<int FIRST>
__global__ __launch_bounds__(256)
void gru_pw_k(const unsigned short* __restrict__ gh, const float* __restrict__ bhh,
              const float* __restrict__ embW, const int* __restrict__ x,
              const float* __restrict__ bih,
              unsigned short* __restrict__ h, unsigned short* __restrict__ local, int t)
{
  int i   = blockIdx.x * 256 + threadIdx.x;   // over BN*64 groups
  int row = i >> 6, d0 = (i & 63) << 2;
  int tok = x[row * 4 + t];
  const float* er = embW + (size_t)tok * 768;
  const float* pr = embW + (size_t)(256 + t) * 768;
  float4 e0 = *(const float4*)(er + d0);
  float4 e1 = *(const float4*)(er + 256 + d0);
  float4 e2 = *(const float4*)(er + 512 + d0);
  float4 p0 = *(const float4*)(pr + d0);
  float4 p1 = *(const float4*)(pr + 256 + d0);
  float4 p2 = *(const float4*)(pr + 512 + d0);
  float4 q0 = *(const float4*)(bih + d0);
  float4 q1 = *(const float4*)(bih + 256 + d0);
  float4 q2 = *(const float4*)(bih + 512 + d0);
  float ir[4]  = {e0.x+p0.x+q0.x, e0.y+p0.y+q0.y, e0.z+p0.z+q0.z, e0.w+p0.w+q0.w};
  float iz[4]  = {e1.x+p1.x+q1.x, e1.y+p1.y+q1.y, e1.z+p1.z+q1.z, e1.w+p1.w+q1.w};
  float inn[4] = {e2.x+p2.x+q2.x, e2.y+p2.y+q2.y, e2.z+p2.z+q2.z, e2.w+p2.w+q2.w};
  float hr[4], hz[4], hn[4];
  if constexpr (FIRST) {
    float4 b0 = *(const float4*)(bhh + d0);
    float4 b1 = *(const float4*)(bhh + 256 + d0);
    float4 b2 = *(const float4*)(bhh + 512 + d0);
    hr[0]=b0.x; hr[1]=b0.y; hr[2]=b0.z; hr[3]=b0.w;
    hz[0]=b1.x; hz[1]=b1.y; hz[2]=b1.z; hz[3]=b1.w;
    hn[0]=b2.x; hn[1]=b2.y; hn[2]=b2.z; hn[3]=b2.w;
  } else {
    const unsigned short* gr = gh + (size_t)row * 768;
    ushort4 u0 = *(const ushort4*)(gr + d0);
    ushort4 u1 = *(const ushort4*)(gr + 256 + d0);
    ushort4 u2 = *(const ushort4*)(gr + 512 + d0);
    hr[0]=bf2f(u0.x); hr[1]=bf2f(u0.y); hr[2]=bf2f(u0.z); hr[3]=bf2f(u0.w);
    hz[0]=bf2f(u1.x); hz[1]=bf2f(u1.y); hz[2]=bf2f(u1.z); hz[3]=bf2f(u1.w);
    hn[0]=bf2f(u2.x); hn[1]=bf2f(u2.y); hn[2]=bf2f(u2.z); hn[3]=bf2f(u2.w);
  }
  ushort4 hprev = {0, 0, 0, 0};
  if constexpr (!FIRST) hprev = *(const ushort4*)&h[(size_t)row * 256 + d0];
  float hp4[4] = {bf2f(hprev.x), bf2f(hprev.y), bf2f(hprev.z), bf2f(hprev.w)};
  ushort4 oh;
  #pragma unroll
  for (int e = 0; e < 4; ++e) {
    float r  = sigm_f(ir[e] + hr[e]);
    float zg = sigm_f(iz[e] + hz[e]);
    float nn = tanhf(inn[e] + r * hn[e]);
    float hnew;
    if constexpr (FIRST) hnew = (1.0f - zg) * nn;
    else                 hnew = (1.0f - zg) * nn + zg * hp4[e];
    ((unsigned short*)&oh)[e] = f2bf(hnew);
  }
  *(ushort4*)&h[(size_t)row * 256 + d0] = oh;
  *(ushort4*)&local[((size_t)row * 4 + t) * 256 + d0] = oh;
}

// ---- LayerNorm bf16 in place (pp_ln on local) -----------------------------
__global__ __launch_bounds__(256)
void ln_bf16_k(unsigned short* __restrict__ X, const float* __restrict__ g,
               const float* __restrict__ bb)
{
  int wave = threadIdx.x >> 6, lane = threadIdx.x & 63;
  int row  = blockIdx.x * 4 + wave;
  unsigned short* xr = X + (size_t)row * 256;
  ushort4 u = *(const ushort4*)&xr[lane * 4];
  float x[4] = {bf2f(u.x), bf2f(u.y), bf2f(u.z), bf2f(u.w)};
  float s = x[0] + x[1] + x[2] + x[3];
  #pragma unroll
  for (int off = 1; off < 64; off <<= 1) s += __shfl_xor(s, off, 64);
  float mean = s * (1.0f / 256.0f);
  float ss = 0.f;
  #pragma unroll
  for (int j = 0; j < 4; ++j) { float d = x[j] - mean; ss += d * d; }
  #pragma unroll
  for (int off = 1; off < 64; off <<= 1) ss += __shfl_xor(ss, off, 64);
  float inv = rsqrtf(ss * (1.0f / 256.0f) + 1e-5f);
  ushort4 o;
  o.x = f2bf((x[0] - mean) * inv * g[lane*4+0] + bb[lane*4+0]);
  o.y = f2bf((x[1] - mean) * inv * g[lane*4+1] + bb[lane*4+1]);
  o.z = f2bf((x[2] - mean) * inv * g[lane*4+2] + bb[lane*4+2]);
  o.w = f2bf((x[3] - mean) * inv * g[lane*4+3] + bb[lane*4+3]);
  *(ushort4*)&xr[lane * 4] = o;
}

// ---- final LN: local bf16 + broad bf16 -> Abuf bf16 -----------------------
__global__ __launch_bounds__(256)
void ln_cvt_k(const unsigned short* __restrict__ X, const unsigned short* __restrict__ Add,
              const float* __restrict__ g, const float* __restrict__ bb,
              unsigned short* __restrict__ Out)
{
  int wave = threadIdx.x >> 6, lane = threadIdx.x & 63;
  int row  = blockIdx.x * 4 + wave;
  ushort4 u = *(const ushort4*)&X[(size_t)row * 256 + lane * 4];
  ushort4 a = *(const ushort4*)&Add[(size_t)(row >> 2) * 256 + lane * 4];
  float x[4] = {bf2f(u.x) + bf2f(a.x), bf2f(u.y) + bf2f(a.y),
                bf2f(u.z) + bf2f(a.z), bf2f(u.w) + bf2f(a.w)};
  float s = x[0] + x[1] + x[2] + x[3];
  #pragma unroll
  for (int off = 1; off < 64; off <<= 1) s += __shfl_xor(s, off, 64);
  float mean = s * (1.0f / 256.0f);
  float ss = 0.f;
  #pragma unroll
  for (int j = 0; j < 4; ++j) { float d = x[j] - mean; ss += d * d; }
  #pragma unroll
  for (int off = 1; off < 64; off <<= 1) ss += __shfl_xor(ss, off, 64);
  float inv = rsqrtf(ss * (1.0f / 256.0f) + 1e-5f);
  ushort4 o;
  o.x = f2bf((x[0] - mean) * inv * g[lane*4+0] + bb[lane*4+0]);
  o.y = f2bf((x[1] - mean) * inv * g[lane*4+1] + bb[lane*4+1]);
  o.z = f2bf((x[2] - mean) * inv * g[lane*4+2] + bb[lane*4+2]);
  o.w = f2bf((x[3] - mean) * inv * g[lane*4+3] + bb[lane*4+3]);
  *(ushort4*)&Out[(size_t)row * 256 + lane * 4] = o;
}

// ---- halting (h bf16) ------------------------------------------------------
__global__ __launch_bounds__(256)
void halt1_k(const unsigned short* __restrict__ h, const float* __restrict__ hw,
             float* __restrict__ part)
{
  int b = blockIdx.x, s = blockIdx.y, tid = threadIdx.x;
  const unsigned short* p = h + ((size_t)b * N_ + s * 32) * 256;
  float acc = 0.f;
  for (int i = tid * 4; i < 32 * 256; i += 1024) {
    ushort4 u = *(const ushort4*)&p[i];
    const float4 w4 = *(const float4*)&hw[i & 255];
    acc += bf2f(u.x) * w4.x + bf2f(u.y) * w4.y + bf2f(u.z) * w4.z + bf2f(u.w) * w4.w;
  }
  __shared__ float red[256];
  red[tid] = acc; __syncthreads();
  for (int off = 128; off > 0; off >>= 1) {
    if (tid < off) red[tid] += red[tid + off];
    __syncthreads();
  }
  if (tid == 0) part[b * 16 + s] = red[0];
}
__global__ __launch_bounds__(64)
void halt2_k(const float* __restrict__ part, const float* __restrict__ hb,
             float* __restrict__ hp)
{
  int b = threadIdx.x;
  if (b < 32) {
    float s = 0.f;
    for (int i = 0; i < 16; ++i) s += part[b * 16 + i];
    hp[b] = sigm_f(s * (1.0f / (float)N_) + hb[0]);
  }
}
__global__ __launch_bounds__(256)
void out2_k(const unsigned short* __restrict__ h, const float* __restrict__ hp,
            float* __restrict__ outp)
{
  int i = blockIdx.x * 256 + threadIdx.x;   // groups of 4
  float hpv = hp[i >> 15];
  ushort4 u = *(const ushort4*)&h[(size_t)i * 4];
  float4 o = {hpv * bf2f(u.x), hpv * bf2f(u.y), hpv * bf2f(u.z), hpv * bf2f(u.w)};
  *(float4*)&outp[(size_t)i * 4] = o;
}

// ---- wave-per-row top-8 + softmax + V gather (sc bf16, qkv stride 768) ----
__global__ __launch_bounds__(256)
void topk_k(const unsigned short* __restrict__ sc, const unsigned short* __restrict__ qkv,
            unsigned short* __restrict__ rpre)
{
  const float NEG = -__builtin_inff();
  int wave = threadIdx.x >> 6, lane = threadIdx.x & 63;
  int rowg = blockIdx.x * 4 + wave;
  int b = rowg >> 9, n = rowg & (N_ - 1);
  const unsigned short* srow = sc + (size_t)rowg * N_;
  float v[8];
  #pragma unroll
  for (int j = 0; j < 8; ++j) {
    int col = lane + j * 64;
    v[j] = (col <= n) ? bf2f(srow[col]) : NEG;
  }
  float tv[8]; int ti[8];
  #pragma unroll
  for (int it = 0; it < 8; ++it) {
    float bv = v[0]; int bi = lane;
    #pragma unroll
    for (int j = 1; j < 8; ++j)
      if (v[j] > bv) { bv = v[j]; bi = lane + j * 64; }
    #pragma unroll
    for (int off = 1; off < 64; off <<= 1) {
      float ov = __shfl_xor(bv, off, 64);
      int   oi = __shfl_xor(bi, off, 64);
      if (ov > bv || (ov == bv && oi < bi)) { bv = ov; bi = oi; }
    }
    tv[it] = bv; ti[it] = bi;
    if ((bi & 63) == lane) v[bi >> 6] = NEG;
  }
  float mx = tv[0];
  float wsum = 0.f, wj[8];
  #pragma unroll
  for (int j = 0; j < 8; ++j) { wj[j] = expf(tv[j] - mx); wsum += wj[j]; }
  float inv = 1.0f / wsum;
  const unsigned short* vb = qkv + 512;
  int d0 = lane * 4;
  float a0 = 0.f, a1 = 0.f, a2 = 0.f, a3 = 0.f;
  #pragma unroll
  for (int j = 0; j < 8; ++j) {
    float wgt = wj[j] * inv;
    ushort4 vv = *(const ushort4*)&vb[((size_t)(b * N_ + ti[j])) * 768 + d0];
    a0 += wgt * bf2f(vv.x); a1 += wgt * bf2f(vv.y);
    a2 += wgt * bf2f(vv.z); a3 += wgt * bf2f(vv.w);
  }
  ushort4 o = {f2bf(a0), f2bf(a1), f2bf(a2), f2bf(a3)};
  *(ushort4*)&rpre[(size_t)rowg * 256 + d0] = o;
}

// ---- KL scalar ------------------------------------------------------------
__global__ void kl_k(const float* __restrict__ hp, float* __restrict__ out)
{
  if (threadIdx.x == 0 && blockIdx.x == 0) {
    float hm = 0.f;
    for (int b = 0; b < 32; ++b) hm += hp[b];
    hm *= (1.0f / 32.0f);
    const float l1e8 = logf(1e-8f);
    float kl = 0.f;
    kl += 0.2f    * (logf(0.2f)    - l1e8);
    kl += 0.16f   * (logf(0.16f)   - l1e8);
    kl += 0.128f  * (logf(0.128f)  - logf(hm + 1e-8f));
    kl += 0.1024f * (logf(0.1024f) - logf(1.0f + 1e-8f));
    out[0] = kl * 0.25f;
  }
}

// ---------------------------------------------------------------------------
extern "C" void kernel_launch(void* const* d_in, const int* in_sizes, int n_in,
                              void* d_out, int out_size, void* d_ws, size_t ws_size,
                              hipStream_t stream)
{
  const int*   x       = (const int*)  d_in[0];
  const float* emb     = (const float*)d_in[1];
  const float* pos     = (const float*)d_in[2];
  const float* gru_wih = (const float*)d_in[3];
  const float* gru_whh = (const float*)d_in[4];
  const float* gru_bih = (const float*)d_in[5];
  const float* gru_bhh = (const float*)d_in[6];
  const float* pp_ln_g = (const float*)d_in[7];
  const float* pp_ln_b = (const float*)d_in[8];
  const float* sum_w   = (const float*)d_in[9];
  const float* sum_b   = (const float*)d_in[10];
  const float* msg_w1  = (const float*)d_in[11];
  const float* msg_b1  = (const float*)d_in[12];
  const float* msg_w2  = (const float*)d_in[13];
  const float* msg_b2  = (const float*)d_in[14];
  const float* upd_w1  = (const float*)d_in[15];
  const float* upd_b1  = (const float*)d_in[16];
  const float* upd_w2  = (const float*)d_in[17];
  const float* upd_b2  = (const float*)d_in[18];
  const float* halt_w  = (const float*)d_in[19];
  const float* halt_b  = (const float*)d_in[20];
  const float* mp_ln_g = (const float*)d_in[21];
  const float* mp_ln_b = (const float*)d_in[22];
  const float* q_w     = (const float*)d_in[23];
  const float* q_b     = (const float*)d_in[24];
  const float* k_w     = (const float*)d_in[25];
  const float* k_b     = (const float*)d_in[26];
  const float* v_w     = (const float*)d_in[27];
  const float* v_b     = (const float*)d_in[28];
  const float* o_w     = (const float*)d_in[29];
  const float* o_b     = (const float*)d_in[30];
  const float* br_w    = (const float*)d_in[31];
  const float* br_b    = (const float*)d_in[32];
  const float* f_ln_g  = (const float*)d_in[33];
  const float* f_ln_b  = (const float*)d_in[34];
  const float* head_w  = (const float*)d_in[35];

  // ---- workspace ----
  constexpr size_t SZ_Q = (size_t)BN_ * 256;
  float* ws     = (float*)d_ws;
  float* R_h    = ws;                  // broad bf16 lives here late
  float* R_outp = R_h    + SZ_Q;
  float* R_b1   = R_outp + SZ_Q;       // gh lo / hsn bf16 / sc bf16 / Abuf
  float* R_b2   = R_b1   + SZ_Q;       // gh hi / U bf16 / sc hi
  float* R_b3   = R_b2   + SZ_Q;       // h bf16 (upper half) / qkv lo
  float* R_rp   = R_b3   + SZ_Q;       // qkv hi + rpre bf16
  unsigned short* R_loc = (unsigned short*)(R_rp + SZ_Q);   // local bf16 (4*SZ_Q shorts)
  unsigned short* wb = R_loc + 4 * SZ_Q;
  unsigned short* sumT  = wb;                  // [256][256]
  unsigned short* W1cT  = sumT  + 65536;       // [512][256]
  unsigned short* u1cT  = W1cT  + 131072;      // [256][512] = [U1a | Wc]
  unsigned short* u2T   = u1cT  + 131072;      // [256][256]
  unsigned short* qkvT  = u2T   + 65536;       // [768][256]
  unsigned short* brWT  = qkvT  + 196608;      // [256][512] = [brW | WobT]
  unsigned short* headT = brWT  + 131072;      // [256][256]
  unsigned short* whhT  = headT + 65536;       // [768][256]
  float* R_embW = (float*)(whhT + 196608);     // [320][768]
  float* R_bU   = R_embW + 320 * 768;
  float* R_bH   = R_bU + 256;
  float* R_bB2  = R_bH + 512;
  float* R_bQKV = R_bB2 + 256;
  float* R_part = R_bQKV + 768;
  float* R_hp   = R_part + 512;

  // bf16 h (GRU recurrence + msg phase): upper half of b3
  unsigned short* R_hb = ((unsigned short*)R_b3) + SZ_Q;

  float* logits = (float*)d_out;
  dim3 blk(256);

  // ---- weight prep ----
  PrepJobs pj;
  const float* srcs[11] = {sum_w, msg_w1, msg_w1 + 65536, upd_w1, upd_w2,
                           q_w, k_w, v_w, br_w, head_w, gru_whh};
  unsigned short* dsts[11] = {sumT, W1cT, W1cT + 65536, u1cT, u2T,
                              qkvT, qkvT + 65536, qkvT + 131072, brWT, headT, whhT};
  int rows[11] = {256,256,256,256,256,256,256,256,256,256,768};
  int dstd[11] = {256,256,256,512,256,256,256,256,512,256,256};
  int strt[11] = {0,0,0,0,0,0,0,0,0,0,1};
  for (int i = 0; i < 11; ++i) {
    pj.src[i]=srcs[i]; pj.dst[i]=dsts[i]; pj.rows[i]=rows[i];
    pj.dstride[i]=dstd[i]; pj.strt[i]=strt[i];
  }
  prep_w_k<<<dim3(64, 11), blk, 0, stream>>>(pj);
  biasprep_k<<<dim3(1), blk, 0, stream>>>(upd_b1, msg_b2, upd_w1, msg_b1,
                                          o_b, br_w, br_b, q_b, k_b, v_b,
                                          R_bU, R_bH, R_bB2, R_bQKV);
  // Wc^T = (msg_w2 @ U1b)^T -> u1cT cols 256..511
  gemm_mfma<8, 1, 0, 1><<<dim3(4, 4), blk, 0, stream>>>(
      nullptr, msg_w2, nullptr, u1cT + 256, 256, 256, 256, 256, 512,
      upd_w1 + 65536, nullptr, nullptr);
  // Wob^T = (o_w @ br_w)^T -> brWT cols 256..511
  gemm_mfma<8, 1, 0, 1><<<dim3(4, 4), blk, 0, stream>>>(
      nullptr, o_w, nullptr, brWT + 256, 256, 256, 256, 256, 512,
      br_w, nullptr, nullptr);
  // embW = [emb; pos] @ wih^T  (nby=5: identity mapping path)
  gemm_mfma<6, 1, 0, 0><<<dim3(12, 5), blk, 0, stream>>>(
      nullptr, gru_wih, nullptr, R_embW, 320, 768, 256, 256, 768,
      nullptr, emb, pos);

  // ---- patch GRU (h bf16 recurrence) ----
  unsigned short* ghB = (unsigned short*)R_b1;
  gru_pw_k<1><<<dim3(BN_ / 4), blk, 0, stream>>>(
      nullptr, gru_bhh, R_embW, x, gru_bih, R_hb, R_loc, 0);
  for (int t = 1; t < 4; ++t) {
    gemm_big<1, 0, 1><<<dim3(6, 128), blk, 0, stream>>>(
        R_hb, whhT, gru_bhh, ghB, BN_, 768, 256, 256, 768);
    gru_pw_k<0><<<dim3(BN_ / 4), blk, 0, stream>>>(
        ghB, gru_bhh, R_embW, x, gru_bih, R_hb, R_loc, t);
  }
  ln_bf16_k<<<dim3(M1_ / 4), blk, 0, stream>>>(R_loc, pp_ln_g, pp_ln_b);

  // summaries -> h (bf16)
  gemm_mfma<9, 0, 0, 1><<<dim3(4, 256), blk, 0, stream>>>(
      (const float*)R_loc, sumT, sum_b, R_hb, BN_, 256, 256, 256, 256,
      nullptr, nullptr, nullptr);

  // ---- message-passing rounds (smsg fused into U-GEMM A-gather) ----
  unsigned short* hsnB = (unsigned short*)R_b1;
  unsigned short* UB   = (unsigned short*)R_b2;
  for (int step = 0; step < 4; ++step) {
    gemm_big<1, 0, 1><<<dim3(4, 128), blk, 0, stream>>>(
        R_hb, W1cT, R_bH, hsnB, BN_, 512, 256, 256, 512);
    // U = gelu([h | S'(hsn)] @ u1cT^T + biasU); S' computed in A-gather
    gemm_mfma<12, 0, 1, 1><<<dim3(4, 256), blk, 0, stream>>>(
        (const float*)R_hb, u1cT, R_bU, UB, BN_, 256, 512, 512, 256,
        (const float*)hsnB, nullptr, nullptr);
    if (step == 3) {
      gemm_ln<3><<<dim3(BN_ / 16), blk, 0, stream>>>(
          UB, u2T, upd_b2, R_hb, mp_ln_g, mp_ln_b, R_hp, R_outp);
    } else {
      gemm_ln<0><<<dim3(BN_ / 16), blk, 0, stream>>>(
          UB, u2T, upd_b2, R_hb, mp_ln_g, mp_ln_b, nullptr, nullptr);
      if (step == 2) {
        halt1_k<<<dim3(32, 16), blk, 0, stream>>>(R_hb, halt_w, R_part);
        halt2_k<<<dim3(1), dim3(64), 0, stream>>>(R_part, halt_b, R_hp);
        out2_k<<<dim3(BN_ / 4), blk, 0, stream>>>(R_hb, R_hp, R_outp);
      }
    }
  }

  // ---- sparse retrieval attention ----
  unsigned short* qkv  = (unsigned short*)R_b3;           // [BN][768] bf16 (h dead)
  unsigned short* rpre = ((unsigned short*)R_rp) + SZ_Q;  // [BN][256] bf16
  unsigned short* sc   = (unsigned short*)R_b1;           // 32x512x512 bf16
  gemm_big<0, 0, 1><<<dim3(6, 128), blk, 0, stream>>>(
      R_outp, qkvT, R_bQKV, qkv, BN_, 768, 256, 256, 768);
  scores_tri<<<dim3(1152), blk, 0, stream>>>(qkv, sc);
  topk_k<<<dim3(BN_ / 4), blk, 0, stream>>>(sc, qkv, rpre);

  // broad = [outp | rpre] @ brWT^T + biasB2  -> bf16 in R_h region
  unsigned short* broadB = (unsigned short*)R_h;
  gemm_mfma<11, 0, 0, 1><<<dim3(4, 256), blk, 0, stream>>>(
      R_outp, brWT, R_bB2, broadB, BN_, 256, 512, 512, 256,
      (const float*)rpre, nullptr, nullptr);

  // final LN + convert -> Abuf (in b1, sc dead), head GEMM (128-tile) -> logits
  unsigned short* Abuf = (unsigned short*)R_b1;
  ln_cvt_k<<<dim3(M1_ / 4), blk, 0, stream>>>(R_loc, broadB, f_ln_g, f_ln_b, Abuf);
  gemm_big<1, 0, 0><<<dim3(2, 512), blk, 0, stream>>>(
      Abuf, headT, nullptr, logits, M1_, 256, 256, 256, 256);

  kl_k<<<dim3(1), dim3(64), 0, stream>>>(R_hp, logits + (size_t)M1_ * 256);
}

// Round 17
// 575.943 us; speedup vs baseline: 1.1117x; 1.1117x over previous
//
#include <hip/hip_runtime.h>
#include <cmath>

// ---------------------------------------------------------------------------
// SutraV04 round 16 = exact revert to round 14 (569 us, best).
// Round 15's smsg-in-GEMM-gather REVERTED: S' gather recomputed 4x (per
// column-block) + 5 erf-gelus on the staging critical path -> 69 us/launch.
// Law (4th confirmation): GEMM staging must be loads + trivial ops only.
// ---------------------------------------------------------------------------

constexpr int N_   = 512;
constexpr int B_   = 32;
constexpr int BN_  = B_ * N_;   // 16384
constexpr int M1_  = BN_ * 4;   // 65536

typedef short bf16x8 __attribute__((ext_vector_type(8)));
typedef float f32x4  __attribute__((ext_vector_type(4)));

__device__ __forceinline__ float gelu_f(float x) {
  return 0.5f * x * (1.0f + erff(x * 0.70710678118654752440f));
}
__device__ __forceinline__ float sigm_f(float x) {
  return 1.0f / (1.0f + expf(-x));
}
__device__ __forceinline__ unsigned short f2bf(float f) {
  union { float f; unsigned int u; } c; c.f = f;
  unsigned int u = c.u;
  u += 0x7FFFu + ((u >> 16) & 1u);
  return (unsigned short)(u >> 16);
}
__device__ __forceinline__ float bf2f(unsigned short u) {
  union { unsigned int u; float f; } c; c.u = ((unsigned int)u) << 16;
  return c.f;
}
__device__ __forceinline__ int phys(int g, int r) {      // 64-row tiles
  return ((g << 6) | (r ^ g)) << 3;
}
__device__ __forceinline__ int phys128(int g, int r) {   // 128-row tiles
  return ((g << 7) | (r ^ g)) << 3;
}
__device__ __forceinline__ int phys16(int g, int r) {    // 16-row tiles
  return ((g << 4) | (r ^ g)) << 3;
}

// XCD-aware block remap: same-A-panel blocks (all nB of a chunk of mB) land
// on one XCD (flat % 8). Bijective; falls back to identity if nby % 8 != 0.
__device__ __forceinline__ void xcd_map(int& mB, int& nB) {
  int nbx = gridDim.x, nby = gridDim.y;
  if ((nby & 7) == 0) {
    int flat = blockIdx.y * nbx + blockIdx.x;
    int chunk = nby >> 3;
    int xcd = flat & 7, s2 = flat >> 3;
    int q = s2 / nbx;
    mB = xcd * chunk + q;
    nB = s2 - q * nbx;
  } else {
    mB = blockIdx.y; nB = blockIdx.x;
  }
}

// ---- 128x128-tile MFMA GEMM ----------------------------------------------
// AMODE: 0 f32 [m][K]; 1 bf16 [m][K].  EPI: 0 none, 1 gelu. COUT: 0 f32, 1 bf16.
template<int AMODE, int EPI, int COUT>
__global__ __launch_bounds__(256)
void gemm_big(const void* __restrict__ A, const unsigned short* __restrict__ Bt,
              const float* __restrict__ bias, void* __restrict__ C,
              int M, int Nn, int K, int bstride, int ldC)
{
  __shared__ short As[4 * 128 * 8];
  __shared__ short Bs[4 * 128 * 8];
  const int t  = threadIdx.x;
  int mB, nB;
  xcd_map(mB, nB);
  const int m0 = mB * 128, n0 = nB * 128;
  const int lane = t & 63, w = t >> 6;
  const int wr = w >> 1, wc = w & 1;
  const int fr = lane & 15, fg = lane >> 4;

  f32x4 acc[4][4] = {};

  for (int k0 = 0; k0 < K; k0 += 32) {
    #pragma unroll
    for (int c = 0; c < 2; ++c) {
      int idx = t + c * 256;
      int row = idx >> 2, g = idx & 3;
      int kk = k0 + g * 8;
      bf16x8 av;
      if constexpr (AMODE == 1) {
        av = *(const bf16x8*)&((const unsigned short*)A)[(size_t)(m0 + row) * K + kk];
      } else {
        const float4* p = (const float4*)&((const float*)A)[(size_t)(m0 + row) * K + kk];
        float4 a = p[0], b = p[1];
        av[0]=(short)f2bf(a.x); av[1]=(short)f2bf(a.y); av[2]=(short)f2bf(a.z); av[3]=(short)f2bf(a.w);
        av[4]=(short)f2bf(b.x); av[5]=(short)f2bf(b.y); av[6]=(short)f2bf(b.z); av[7]=(short)f2bf(b.w);
      }
      *(bf16x8*)&As[phys128(g, row)] = av;
      *(bf16x8*)&Bs[phys128(g, row)] =
          *(const bf16x8*)&Bt[(size_t)(n0 + row) * bstride + kk];
    }
    __syncthreads();

    bf16x8 a[4], b[4];
    #pragma unroll
    for (int i = 0; i < 4; ++i)
      a[i] = *(const bf16x8*)&As[phys128(fg, wr * 64 + i * 16 + fr)];
    #pragma unroll
    for (int j = 0; j < 4; ++j)
      b[j] = *(const bf16x8*)&Bs[phys128(fg, wc * 64 + j * 16 + fr)];
    #pragma unroll
    for (int i = 0; i < 4; ++i)
      #pragma unroll
      for (int j = 0; j < 4; ++j)
        acc[i][j] = __builtin_amdgcn_mfma_f32_16x16x32_bf16(a[i], b[j], acc[i][j], 0, 0, 0);
    __syncthreads();
  }

  #pragma unroll
  for (int i = 0; i < 4; ++i)
    #pragma unroll
    for (int j = 0; j < 4; ++j) {
      int col = n0 + wc * 64 + j * 16 + fr;
      float bcol = bias ? bias[col] : 0.0f;
      #pragma unroll
      for (int r = 0; r < 4; ++r) {
        int row = m0 + wr * 64 + i * 16 + fg * 4 + r;
        float vv = acc[i][j][r] + bcol;
        if constexpr (EPI == 1) vv = gelu_f(vv);
        if constexpr (COUT == 0)
          ((float*)C)[(size_t)row * ldC + col] = vv;
        else
          ((unsigned short*)C)[(size_t)row * ldC + col] = f2bf(vv);
      }
    }
}

// ---- 64-tile gather GEMM --------------------------------------------------
// MODE: 6 emb/pos rows; 8 transposed f32 gather P2[k*256+m]; 9 bf16 patch-mean;
//       10 concat(bf16 A | bf16 P2); 11 concat(f32 A | bf16 P2)
// BSRC: 0 bf16 Bt; 1 fp32.  EPI: 0 none, 1 gelu.  COUT: 0 f32, 1 bf16.
template<int MODE, int BSRC, int EPI, int COUT>
__global__ __launch_bounds__(256)
void gemm_mfma(const float* __restrict__ A, const void* __restrict__ Bsrc,
               const float* __restrict__ bias, void* __restrict__ C,
               int M, int Nn, int K, int bstride, int ldC,
               const float* __restrict__ P2,
               const float* __restrict__ emb, const float* __restrict__ pos)
{
  __shared__ short As[4 * 64 * 8];
  __shared__ short Bs[4 * 64 * 8];
  const int tid  = threadIdx.x;
  int mB, nB;
  xcd_map(mB, nB);
  const int m0 = mB * 64, n0 = nB * 64;
  const int srow = tid >> 2, sg = tid & 3;
  const int lane = tid & 63, w = tid >> 6;
  const int wr   = w >> 1,  wc = w & 1;
  const int fr   = lane & 15, fg = lane >> 4;

  f32x4 acc[2][2] = {};

  for (int k0 = 0; k0 < K; k0 += 32) {
    {
      int m = m0 + srow, k = k0 + sg * 8;
      bf16x8 tv;
      if constexpr (MODE == 10) {
        if (k < 256)
          tv = *(const bf16x8*)&((const unsigned short*)A)[(size_t)m * 256 + k];
        else
          tv = *(const bf16x8*)&((const unsigned short*)P2)[(size_t)m * 256 + (k - 256)];
      } else if constexpr (MODE == 11) {
        if (k < 256) {
          const float4* p = (const float4*)(A + (size_t)m * 256 + k);
          float4 a = p[0], b = p[1];
          tv[0]=(short)f2bf(a.x); tv[1]=(short)f2bf(a.y); tv[2]=(short)f2bf(a.z); tv[3]=(short)f2bf(a.w);
          tv[4]=(short)f2bf(b.x); tv[5]=(short)f2bf(b.y); tv[6]=(short)f2bf(b.z); tv[7]=(short)f2bf(b.w);
        } else {
          tv = *(const bf16x8*)&((const unsigned short*)P2)[(size_t)m * 256 + (k - 256)];
        }
      } else {
        float v[8];
        if constexpr (MODE == 6) {
          const float* src = nullptr;
          if (m < 256) src = emb + (size_t)m * 256 + k;
          else if (m < 260) src = pos + (size_t)(m - 256) * 256 + k;
          if (src) {
            const float4* p = (const float4*)src;
            float4 a = p[0], b = p[1];
            v[0]=a.x; v[1]=a.y; v[2]=a.z; v[3]=a.w; v[4]=b.x; v[5]=b.y; v[6]=b.z; v[7]=b.w;
          } else {
            #pragma unroll
            for (int j = 0; j < 8; ++j) v[j] = 0.f;
          }
        } else if constexpr (MODE == 8) {
          #pragma unroll
          for (int j = 0; j < 8; ++j) v[j] = P2[(size_t)(k + j) * 256 + m];
        } else { // 9
          const unsigned short* Ab = (const unsigned short*)A;
          const unsigned short* base = Ab + (size_t)m * 1024 + k;
          bf16x8 r0 = *(const bf16x8*)(base);
          bf16x8 r1 = *(const bf16x8*)(base + 256);
          bf16x8 r2 = *(const bf16x8*)(base + 512);
          bf16x8 r3 = *(const bf16x8*)(base + 768);
          #pragma unroll
          for (int j = 0; j < 8; ++j)
            v[j] = 0.25f * (bf2f((unsigned short)r0[j]) + bf2f((unsigned short)r1[j]) +
                            bf2f((unsigned short)r2[j]) + bf2f((unsigned short)r3[j]));
        }
        #pragma unroll
        for (int j = 0; j < 8; ++j) tv[j] = (short)f2bf(v[j]);
      }
      *(bf16x8*)&As[phys(sg, srow)] = tv;
    }
    if constexpr (BSRC == 0) {
      const unsigned short* Bt = (const unsigned short*)Bsrc;
      *(bf16x8*)&Bs[phys(sg, srow)] =
          *(const bf16x8*)&Bt[(size_t)(n0 + srow) * bstride + k0 + sg * 8];
    } else {
      const float* Bf = (const float*)Bsrc;
      const float4* p = (const float4*)(Bf + (size_t)(n0 + srow) * bstride + k0 + sg * 8);
      float4 a = p[0], b = p[1];
      bf16x8 tv;
      tv[0]=(short)f2bf(a.x); tv[1]=(short)f2bf(a.y); tv[2]=(short)f2bf(a.z); tv[3]=(short)f2bf(a.w);
      tv[4]=(short)f2bf(b.x); tv[5]=(short)f2bf(b.y); tv[6]=(short)f2bf(b.z); tv[7]=(short)f2bf(b.w);
      *(bf16x8*)&Bs[phys(sg, srow)] = tv;
    }
    __syncthreads();

    bf16x8 a0 = *(const bf16x8*)&As[phys(fg, wr * 32 + fr)];
    bf16x8 a1 = *(const bf16x8*)&As[phys(fg, wr * 32 + 16 + fr)];
    bf16x8 b0 = *(const bf16x8*)&Bs[phys(fg, wc * 32 + fr)];
    bf16x8 b1 = *(const bf16x8*)&Bs[phys(fg, wc * 32 + 16 + fr)];
    acc[0][0] = __builtin_amdgcn_mfma_f32_16x16x32_bf16(a0, b0, acc[0][0], 0, 0, 0);
    acc[0][1] = __builtin_amdgcn_mfma_f32_16x16x32_bf16(a0, b1, acc[0][1], 0, 0, 0);
    acc[1][0] = __builtin_amdgcn_mfma_f32_16x16x32_bf16(a1, b0, acc[1][0], 0, 0, 0);
    acc[1][1] = __builtin_amdgcn_mfma_f32_16x16x32_bf16(a1, b1, acc[1][1], 0, 0, 0);
    __syncthreads();
  }

  #pragma unroll
  for (int i = 0; i < 2; ++i) {
    #pragma unroll
    for (int j = 0; j < 2; ++j) {
      int row0 = m0 + wr * 32 + i * 16 + fg * 4;
      int col  = n0 + wc * 32 + j * 16 + fr;
      float bcol = bias ? bias[col] : 0.0f;
      #pragma unroll
      for (int r = 0; r < 4; ++r) {
        float vv = acc[i][j][r] + bcol;
        if constexpr (EPI == 1) vv = gelu_f(vv);
        int row = row0 + r;
        if constexpr (COUT == 0)
          ((float*)C)[(size_t)row * ldC + col] = vv;
        else
          ((unsigned short*)C)[(size_t)row * ldC + col] = f2bf(vv);
      }
    }
  }
}

// ---- fused upd-GEMM + residual + LN; 16-row full-width tile ---------------
template<int OUTM>
__global__ __launch_bounds__(256)
void gemm_ln(const unsigned short* __restrict__ U, const unsigned short* __restrict__ u2T,
             const float* __restrict__ bias, unsigned short* __restrict__ h,
             const float* __restrict__ g, const float* __restrict__ bb,
             const float* __restrict__ hp, float* __restrict__ outp)
{
  __shared__ short As[4 * 16 * 8];
  __shared__ short Bs[4 * 256 * 8];
  __shared__ float psum[4][16], pssq[4][16];
  const int m0 = blockIdx.x * 16;
  const int t  = threadIdx.x;
  const int lane = t & 63, w = t >> 6;
  const int fr = lane & 15, fg = lane >> 4;

  f32x4 acc[4] = {};
  for (int k0 = 0; k0 < 256; k0 += 32) {
    if (t < 64) {
      int row = t >> 2, gq = t & 3;
      *(bf16x8*)&As[phys16(gq, row)] =
          *(const bf16x8*)&U[(size_t)(m0 + row) * 256 + k0 + gq * 8];
    }
    const unsigned short* brow = u2T + (size_t)t * 256 + k0;
    #pragma unroll
    for (int gq = 0; gq < 4; ++gq)
      *(bf16x8*)&Bs[((gq << 8) | (t ^ gq)) << 3] = *(const bf16x8*)(brow + gq * 8);
    __syncthreads();
    bf16x8 a = *(const bf16x8*)&As[phys16(fg, fr)];
    #pragma unroll
    for (int j = 0; j < 4; ++j) {
      int n = 64 * w + 16 * j + fr;
      bf16x8 b = *(const bf16x8*)&Bs[((fg << 8) | (n ^ fg)) << 3];
      acc[j] = __builtin_amdgcn_mfma_f32_16x16x32_bf16(a, b, acc[j], 0, 0, 0);
    }
    __syncthreads();
  }

  float bcol[4], gv[4], bv[4];
  #pragma unroll
  for (int j = 0; j < 4; ++j) {
    int col = 64 * w + 16 * j + fr;
    bcol[j] = bias[col]; gv[j] = g[col]; bv[j] = bb[col];
  }
  float vsum[4] = {}, vssq[4] = {};
  #pragma unroll
  for (int j = 0; j < 4; ++j) {
    int col = 64 * w + 16 * j + fr;
    #pragma unroll
    for (int r = 0; r < 4; ++r) {
      int row = m0 + 4 * fg + r;
      float v = acc[j][r] + bcol[j] + bf2f(h[(size_t)row * 256 + col]);
      acc[j][r] = v;
      vsum[r] += v;
      vssq[r] += v * v;
    }
  }
  #pragma unroll
  for (int off = 1; off < 16; off <<= 1) {
    #pragma unroll
    for (int r = 0; r < 4; ++r) {
      vsum[r] += __shfl_xor(vsum[r], off, 64);
      vssq[r] += __shfl_xor(vssq[r], off, 64);
    }
  }
  if (fr == 0) {
    #pragma unroll
    for (int r = 0; r < 4; ++r) {
      psum[w][4 * fg + r] = vsum[r];
      pssq[w][4 * fg + r] = vssq[r];
    }
  }
  __syncthreads();

  float rem = 0.f;
  if constexpr (OUTM == 3) rem = 1.0f - hp[m0 >> 9];
  #pragma unroll
  for (int r = 0; r < 4; ++r) {
    int rr = 4 * fg + r;
    float s  = psum[0][rr] + psum[1][rr] + psum[2][rr] + psum[3][rr];
    float q2 = pssq[0][rr] + pssq[1][rr] + pssq[2][rr] + pssq[3][rr];
    float mean = s * (1.0f / 256.0f);
    float var  = q2 * (1.0f / 256.0f) - mean * mean;
    float inv  = rsqrtf(var + 1e-5f);
    int row = m0 + rr;
    #pragma unroll
    for (int j = 0; j < 4; ++j) {
      int col = 64 * w + 16 * j + fr;
      float y = (acc[j][r] - mean) * inv * gv[j] + bv[j];
      h[(size_t)row * 256 + col] = f2bf(y);
      if constexpr (OUTM == 3) outp[(size_t)row * 256 + col] += rem * y;
    }
  }
}

// ---- causal tri-tile scores (bf16 out), XCD-swizzled ----------------------
__global__ __launch_bounds__(256)
void scores_tri(const unsigned short* __restrict__ qkv, unsigned short* __restrict__ sc)
{
  int flat = blockIdx.x;
  int xcd = flat & 7, s = flat >> 3;
  int bhi = s / 36, tile = s - bhi * 36;
  int b = bhi * 8 + xcd;
  int ti = 0;
  while ((ti + 1) * (ti + 2) / 2 <= tile) ++ti;
  int tj = tile - ti * (ti + 1) / 2;
  const int m0 = ti * 64, n0 = tj * 64;
  const unsigned short* Aq = qkv + (size_t)b * N_ * 768;
  const unsigned short* Bk = Aq + 256;

  __shared__ short As[4 * 64 * 8];
  __shared__ short Bs[4 * 64 * 8];
  const int tid  = threadIdx.x;
  const int srow = tid >> 2, sg = tid & 3;
  const int lane = tid & 63, w = tid >> 6;
  const int wr   = w >> 1,  wc = w & 1;
  const int fr   = lane & 15, fg = lane >> 4;

  f32x4 acc[2][2] = {};
  for (int k0 = 0; k0 < 256; k0 += 32) {
    *(bf16x8*)&As[phys(sg, srow)] =
        *(const bf16x8*)&Aq[(size_t)(m0 + srow) * 768 + k0 + sg * 8];
    *(bf16x8*)&Bs[phys(sg, srow)] =
        *(const bf16x8*)&Bk[(size_t)(n0 + srow) * 768 + k0 + sg * 8];
    __syncthreads();
    bf16x8 a0 = *(const bf16x8*)&As[phys(fg, wr * 32 + fr)];
    bf16x8 a1 = *(const bf16x8*)&As[phys(fg, wr * 32 + 16 + fr)];
    bf16x8 b0 = *(const bf16x8*)&Bs[phys(fg, wc * 32 + fr)];
    bf16x8 b1 = *(const bf16x8*)&Bs[phys(fg, wc * 32 + 16 + fr)];
    acc[0][0] = __builtin_amdgcn_mfma_f32_16x16x32_bf16(a0, b0, acc[0][0], 0, 0, 0);
    acc[0][1] = __builtin_amdgcn_mfma_f32_16x16x32_bf16(a0, b1, acc[0][1], 0, 0, 0);
    acc[1][0] = __builtin_amdgcn_mfma_f32_16x16x32_bf16(a1, b0, acc[1][0], 0, 0, 0);
    acc[1][1] = __builtin_amdgcn_mfma_f32_16x16x32_bf16(a1, b1, acc[1][1], 0, 0, 0);
    __syncthreads();
  }
  unsigned short* scb = sc + (size_t)b * N_ * N_;
  #pragma unroll
  for (int i = 0; i < 2; ++i) {
    #pragma unroll
    for (int j = 0; j < 2; ++j) {
      int row0 = m0 + wr * 32 + i * 16 + fg * 4;
      int col  = n0 + wc * 32 + j * 16 + fr;
      #pragma unroll
      for (int r = 0; r < 4; ++r) {
        int row = row0 + r;
        float vv = acc[i][j][r] * 0.0625f;
        if (col > row) vv = -__builtin_inff();
        scb[(size_t)row * N_ + col] = f2bf(vv);
      }
    }
  }
}

// ---- weight prep ----------------------------------------------------------
struct PrepJobs {
  const float* src[12];
  unsigned short* dst[12];
  int rows[12];
  int dstride[12];
  int strt[12];
};
__global__ __launch_bounds__(256)
void prep_w_k(PrepJobs pj)
{
  int jid = blockIdx.y;
  const float* src = pj.src[jid];
  unsigned short* dst = pj.dst[jid];
  int ds = pj.dstride[jid];
  int total = pj.rows[jid] << 8;
  if (pj.strt[jid]) {
    for (int i = blockIdx.x * 256 + threadIdx.x; i < total; i += gridDim.x * 256) {
      int k = i & 255, n = i >> 8;
      dst[(size_t)n * ds + k] = f2bf(src[i]);
    }
  } else {
    for (int i = blockIdx.x * 256 + threadIdx.x; i < total; i += gridDim.x * 256) {
      int k = i & 255, n = i >> 8;
      dst[(size_t)n * ds + k] = f2bf(src[(size_t)k * 256 + n]);
    }
  }
}

// ---- bias prep ------------------------------------------------------------
__global__ __launch_bounds__(256)
void biasprep_k(const float* __restrict__ upd_b1, const float* __restrict__ msg_b2,
                const float* __restrict__ upd_w1, const float* __restrict__ msg_b1,
                const float* __restrict__ o_b, const float* __restrict__ br_w,
                const float* __restrict__ br_b, const float* __restrict__ q_b,
                const float* __restrict__ k_b, const float* __restrict__ v_b,
                float* __restrict__ biasU, float* __restrict__ biasHsn,
                float* __restrict__ biasB2, float* __restrict__ bQKV)
{
  int c = threadIdx.x;
  float s = upd_b1[c];
  for (int k = 0; k < 256; ++k)
    s += msg_b2[k] * upd_w1[(size_t)(256 + k) * 256 + c];
  biasU[c] = s;
  biasHsn[c] = msg_b1[c];
  biasHsn[256 + c] = 0.f;
  float s2 = br_b[c];
  for (int k = 0; k < 256; ++k)
    s2 += o_b[k] * br_w[(size_t)k * 256 + c];
  biasB2[c] = s2;
  bQKV[c] = q_b[c]; bQKV[256 + c] = k_b[c]; bQKV[512 + c] = v_b[c];
}

// ---- GRU pointwise (vectorized, 4 elems/thread, h bf16) -------------------
template<int FIRST>
__global__ __launch_bounds__(256)
void gru_pw_k(const unsigned short* __restrict__ gh, const float* __restrict__ bhh,
              const float* __restrict__ embW, const int* __restrict__ x,
              const float* __restrict__ bih,
              unsigned short* __restrict__ h, unsigned short* __restrict__ local, int t)
{
  int i   = blockIdx.x * 256 + threadIdx.x;   // over BN*64 groups
  int row = i >> 6, d0 = (i & 63) << 2;
  int tok = x[row * 4 + t];
  const float* er = embW + (size_t)tok * 768;
  const float* pr = embW + (size_t)(256 + t) * 768;
  float4 e0 = *(const float4*)(er + d0);
  float4 e1 = *(const float4*)(er + 256 + d0);
  float4 e2 = *(const float4*)(er + 512 + d0);
  float4 p0 = *(const float4*)(pr + d0);
  float4 p1 = *(const float4*)(pr + 256 + d0);
  float4 p2 = *(const float4*)(pr + 512 + d0);
  float4 q0 = *(const float4*)(bih + d0);
  float4 q1 = *(const float4*)(bih + 256 + d0);
  float4 q2 = *(const float4*)(bih + 512 + d0);
  float ir[4]  = {e0.x+p0.x+q0.x, e0.y+p0.y+q0.y, e0.z+p0.z+q0.z, e0.w+p0.w+q0.w};
  float iz[4]  = {e1.x+p1.x+q1.x, e1.y+p1.y+q1.y, e1.z+p1.z+q1.z, e1.w+p1.w+q1.w};
  float inn[4] = {e2.x+p2.x+q2.x, e2.y+p2.y+q2.y, e2.z+p2.z+q2.z, e2.w+p2.w+q2.w};
  float hr[4], hz[4], hn[4];
  if constexpr (FIRST) {
    float4 b0 = *(const float4*)(bhh + d0);
    float4 b1 = *(const float4*)(bhh + 256 + d0);
    float4 b2 = *(const float4*)(bhh + 512 + d0);
    hr[0]=b0.x; hr[1]=b0.y; hr[2]=b0.z; hr[3]=b0.w;
    hz[0]=b1.x; hz[1]=b1.y; hz[2]=b1.z; hz[3]=b1.w;
    hn[0]=b2.x; hn[1]=b2.y; hn[2]=b2.z; hn[3]=b2.w;
  } else {
    const unsigned short* gr = gh + (size_t)row * 768;
    ushort4 u0 = *(const ushort4*)(gr + d0);
    ushort4 u1 = *(const ushort4*)(gr + 256 + d0);
    ushort4 u2 = *(const ushort4*)(gr + 512 + d0);
    hr[0]=bf2f(u0.x); hr[1]=bf2f(u0.y); hr[2]=bf2f(u0.z); hr[3]=bf2f(u0.w);
    hz[0]=bf2f(u1.x); hz[1]=bf2f(u1.y); hz[2]=bf2f(u1.z); hz[3]=bf2f(u1.w);
    hn[0]=bf2f(u2.x); hn[1]=bf2f(u2.y); hn[2]=bf2f(u2.z); hn[3]=bf2f(u2.w);
  }
  ushort4 hprev = {0, 0, 0, 0};
  if constexpr (!FIRST) hprev = *(const ushort4*)&h[(size_t)row * 256 + d0];
  float hp4[4] = {bf2f(hprev.x), bf2f(hprev.y), bf2f(hprev.z), bf2f(hprev.w)};
  ushort4 oh;
  #pragma unroll
  for (int e = 0; e < 4; ++e) {
    float r  = sigm_f(ir[e] + hr[e]);
    float zg = sigm_f(iz[e] + hz[e]);
    float nn = tanhf(inn[e] + r * hn[e]);
    float hnew;
    if constexpr (FIRST) hnew = (1.0f - zg) * nn;
    else                 hnew = (1.0f - zg) * nn + zg * hp4[e];
    ((unsigned short*)&oh)[e] = f2bf(hnew);
  }
  *(ushort4*)&h[(size_t)row * 256 + d0] = oh;
  *(ushort4*)&local[((size_t)row * 4 + t) * 256 + d0] = oh;
}

// ---- S' = rowscale( sum_kk gelu(hs + shift(hn)) ) -> bf16 -----------------
__global__ __launch_bounds__(256)
void smsg_k(const unsigned short* __restrict__ hsn, unsigned short* __restrict__ S)
{
  int i = blockIdx.x * 256 + threadIdx.x;   // BN*64
  int m = i >> 6, d4 = (i & 63) << 2;
  int n = m & (N_ - 1);
  ushort4 hsu = *(const ushort4*)&hsn[(size_t)m * 512 + d4];
  float hs0 = bf2f(hsu.x), hs1 = bf2f(hsu.y), hs2 = bf2f(hsu.z), hs3 = bf2f(hsu.w);
  float a0 = 0.f, a1 = 0.f, a2 = 0.f, a3 = 0.f;
  #pragma unroll
  for (int kk = 0; kk < 5; ++kk) {
    int idx = n + kk - 4;
    if (idx >= 0) {
      ushort4 hv = *(const ushort4*)&hsn[(size_t)(m + kk - 4) * 512 + 256 + d4];
      a0 += gelu_f(hs0 + bf2f(hv.x));
      a1 += gelu_f(hs1 + bf2f(hv.y));
      a2 += gelu_f(hs2 + bf2f(hv.z));
      a3 += gelu_f(hs3 + bf2f(hv.w));
    }
  }
  float sc1 = 1.0f / (float)((n < 4 ? n : 4) + 1);
  ushort4 o = {f2bf(a0 * sc1), f2bf(a1 * sc1), f2bf(a2 * sc1), f2bf(a3 * sc1)};
  *(ushort4*)&S[(size_t)m * 256 + d4] = o;
}

// ---- LayerNorm bf16 in place (pp_ln on local) -----------------------------
__global__ __launch_bounds__(256)
void ln_bf16_k(unsigned short* __restrict__ X, const float* __restrict__ g,
               const float* __restrict__ bb)
{
  int wave = threadIdx.x >> 6, lane = threadIdx.x & 63;
  int row  = blockIdx.x * 4 + wave;
  unsigned short* xr = X + (size_t)row * 256;
  ushort4 u = *(const ushort4*)&xr[lane * 4];
  float x[4] = {bf2f(u.x), bf2f(u.y), bf2f(u.z), bf2f(u.w)};
  float s = x[0] + x[1] + x[2] + x[3];
  #pragma unroll
  for (int off = 1; off < 64; off <<= 1) s += __shfl_xor(s, off, 64);
  float mean = s * (1.0f / 256.0f);
  float ss = 0.f;
  #pragma unroll
  for (int j = 0; j < 4; ++j) { float d = x[j] - mean; ss += d * d; }
  #pragma unroll
  for (int off = 1; off < 64; off <<= 1) ss += __shfl_xor(ss, off, 64);
  float inv = rsqrtf(ss * (1.0f / 256.0f) + 1e-5f);
  ushort4 o;
  o.x = f2bf((x[0] - mean) * inv * g[lane*4+0] + bb[lane*4+0]);
  o.y = f2bf((x[1] - mean) * inv * g[lane*4+1] + bb[lane*4+1]);
  o.z = f2bf((x[2] - mean) * inv * g[lane*4+2] + bb[lane*4+2]);
  o.w = f2bf((x[3] - mean) * inv * g[lane*4+3] + bb[lane*4+3]);
  *(ushort4*)&xr[lane * 4] = o;
}

// ---- final LN: local bf16 + broad bf16 -> Abuf bf16 -----------------------
__global__ __launch_bounds__(256)
void ln_cvt_k(const unsigned short* __restrict__ X, const unsigned short* __restrict__ Add,
              const float* __restrict__ g, const float* __restrict__ bb,
              unsigned short* __restrict__ Out)
{
  int wave = threadIdx.x >> 6, lane = threadIdx.x & 63;
  int row  = blockIdx.x * 4 + wave;
  ushort4 u = *(const ushort4*)&X[(size_t)row * 256 + lane * 4];
  ushort4 a = *(const ushort4*)&Add[(size_t)(row >> 2) * 256 + lane * 4];
  float x[4] = {bf2f(u.x) + bf2f(a.x), bf2f(u.y) + bf2f(a.y),
                bf2f(u.z) + bf2f(a.z), bf2f(u.w) + bf2f(a.w)};
  float s = x[0] + x[1] + x[2] + x[3];
  #pragma unroll
  for (int off = 1; off < 64; off <<= 1) s += __shfl_xor(s, off, 64);
  float mean = s * (1.0f / 256.0f);
  float ss = 0.f;
  #pragma unroll
  for (int j = 0; j < 4; ++j) { float d = x[j] - mean; ss += d * d; }
  #pragma unroll
  for (int off = 1; off < 64; off <<= 1) ss += __shfl_xor(ss, off, 64);
  float inv = rsqrtf(ss * (1.0f / 256.0f) + 1e-5f);
  ushort4 o;
  o.x = f2bf((x[0] - mean) * inv * g[lane*4+0] + bb[lane*4+0]);
  o.y = f2bf((x[1] - mean) * inv * g[lane*4+1] + bb[lane*4+1]);
  o.z = f2bf((x[2] - mean) * inv * g[lane*4+2] + bb[lane*4+2]);
  o.w = f2bf((x[3] - mean) * inv * g[lane*4+3] + bb[lane*4+3]);
  *(ushort4*)&Out[(size_t)row * 256 + lane * 4] = o;
}

// ---- halting (h bf16) ------------------------------------------------------
__global__ __launch_bounds__(256)
void halt1_k(const unsigned short* __restrict__ h, const float* __restrict__ hw,
             float* __restrict__ part)
{
  int b = blockIdx.x, s = blockIdx.y, tid = threadIdx.x;
  const unsigned short* p = h + ((size_t)b * N_ + s * 32) * 256;
  float acc = 0.f;
  for (int i = tid * 4; i < 32 * 256; i += 1024) {
    ushort4 u = *(const ushort4*)&p[i];
    const float4 w4 = *(const float4*)&hw[i & 255];
    acc += bf2f(u.x) * w4.x + bf2f(u.y) * w4.y + bf2f(u.z) * w4.z + bf2f(u.w) * w4.w;
  }
  __shared__ float red[256];
  red[tid] = acc; __syncthreads();
  for (int off = 128; off > 0; off >>= 1) {
    if (tid < off) red[tid] += red[tid + off];
    __syncthreads();
  }
  if (tid == 0) part[b * 16 + s] = red[0];
}
__global__ __launch_bounds__(64)
void halt2_k(const float* __restrict__ part, const float* __restrict__ hb,
             float* __restrict__ hp)
{
  int b = threadIdx.x;
  if (b < 32) {
    float s = 0.f;
    for (int i = 0; i < 16; ++i) s += part[b * 16 + i];
    hp[b] = sigm_f(s * (1.0f / (float)N_) + hb[0]);
  }
}
__global__ __launch_bounds__(256)
void out2_k(const unsigned short* __restrict__ h, const float* __restrict__ hp,
            float* __restrict__ outp)
{
  int i = blockIdx.x * 256 + threadIdx.x;   // groups of 4
  float hpv = hp[i >> 15];
  ushort4 u = *(const ushort4*)&h[(size_t)i * 4];
  float4 o = {hpv * bf2f(u.x), hpv * bf2f(u.y), hpv * bf2f(u.z), hpv * bf2f(u.w)};
  *(float4*)&outp[(size_t)i * 4] = o;
}

// ---- wave-per-row top-8 + softmax + V gather (sc bf16, qkv stride 768) ----
__global__ __launch_bounds__(256)
void topk_k(const unsigned short* __restrict__ sc, const unsigned short* __restrict__ qkv,
            unsigned short* __restrict__ rpre)
{
  const float NEG = -__builtin_inff();
  int wave = threadIdx.x >> 6, lane = threadIdx.x & 63;
  int rowg = blockIdx.x * 4 + wave;
  int b = rowg >> 9, n = rowg & (N_ - 1);
  const unsigned short* srow = sc + (size_t)rowg * N_;
  float v[8];
  #pragma unroll
  for (int j = 0; j < 8; ++j) {
    int col = lane + j * 64;
    v[j] = (col <= n) ? bf2f(srow[col]) : NEG;
  }
  float tv[8]; int ti[8];
  #pragma unroll
  for (int it = 0; it < 8; ++it) {
    float bv = v[0]; int bi = lane;
    #pragma unroll
    for (int j = 1; j < 8; ++j)
      if (v[j] > bv) { bv = v[j]; bi = lane + j * 64; }
    #pragma unroll
    for (int off = 1; off < 64; off <<= 1) {
      float ov = __shfl_xor(bv, off, 64);
      int   oi = __shfl_xor(bi, off, 64);
      if (ov > bv || (ov == bv && oi < bi)) { bv = ov; bi = oi; }
    }
    tv[it] = bv; ti[it] = bi;
    if ((bi & 63) == lane) v[bi >> 6] = NEG;
  }
  float mx = tv[0];
  float wsum = 0.f, wj[8];
  #pragma unroll
  for (int j = 0; j < 8; ++j) { wj[j] = expf(tv[j] - mx); wsum += wj[j]; }
  float inv = 1.0f / wsum;
  const unsigned short* vb = qkv + 512;
  int d0 = lane * 4;
  float a0 = 0.f, a1 = 0.f, a2 = 0.f, a3 = 0.f;
  #pragma unroll
  for (int j = 0; j < 8; ++j) {
    float wgt = wj[j] * inv;
    ushort4 vv = *(const ushort4*)&vb[((size_t)(b * N_ + ti[j])) * 768 + d0];
    a0 += wgt * bf2f(vv.x); a1 += wgt * bf2f(vv.y);
    a2 += wgt * bf2f(vv.z); a3 += wgt * bf2f(vv.w);
  }
  ushort4 o = {f2bf(a0), f2bf(a1), f2bf(a2), f2bf(a3)};
  *(ushort4*)&rpre[(size_t)rowg * 256 + d0] = o;
}

// ---- KL scalar ------------------------------------------------------------
__global__ void kl_k(const float* __restrict__ hp, float* __restrict__ out)
{
  if (threadIdx.x == 0 && blockIdx.x == 0) {
    float hm = 0.f;
    for (int b = 0; b < 32; ++b) hm += hp[b];
    hm *= (1.0f / 32.0f);
    const float l1e8 = logf(1e-8f);
    float kl = 0.f;
    kl += 0.2f    * (logf(0.2f)    - l1e8);
    kl += 0.16f   * (logf(0.16f)   - l1e8);
    kl += 0.128f  * (logf(0.128f)  - logf(hm + 1e-8f));
    kl += 0.1024f * (logf(0.1024f) - logf(1.0f + 1e-8f));
    out[0] = kl * 0.25f;
  }
}

// ---------------------------------------------------------------------------
extern "C" void kernel_launch(void* const* d_in, const int* in_sizes, int n_in,
                              void* d_out, int out_size, void* d_ws, size_t ws_size,
                              hipStream_t stream)
{
  const int*   x       = (const int*)  d_in[0];
  const float* emb     = (const float*)d_in[1];
  const float* pos     = (const float*)d_in[2];
  const float* gru_wih = (const float*)d_in[3];
  const float* gru_whh = (const float*)d_in[4];
  const float* gru_bih = (const float*)d_in[5];
  const float* gru_bhh = (const float*)d_in[6];
  const float* pp_ln_g = (const float*)d_in[7];
  const float* pp_ln_b = (const float*)d_in[8];
  const float* sum_w   = (const float*)d_in[9];
  const float* sum_b   = (const float*)d_in[10];
  const float* msg_w1  = (const float*)d_in[11];
  const float* msg_b1  = (const float*)d_in[12];
  const float* msg_w2  = (const float*)d_in[13];
  const float* msg_b2  = (const float*)d_in[14];
  const float* upd_w1  = (const float*)d_in[15];
  const float* upd_b1  = (const float*)d_in[16];
  const float* upd_w2  = (const float*)d_in[17];
  const float* upd_b2  = (const float*)d_in[18];
  const float* halt_w  = (const float*)d_in[19];
  const float* halt_b  = (const float*)d_in[20];
  const float* mp_ln_g = (const float*)d_in[21];
  const float* mp_ln_b = (const float*)d_in[22];
  const float* q_w     = (const float*)d_in[23];
  const float* q_b     = (const float*)d_in[24];
  const float* k_w     = (const float*)d_in[25];
  const float* k_b     = (const float*)d_in[26];
  const float* v_w     = (const float*)d_in[27];
  const float* v_b     = (const float*)d_in[28];
  const float* o_w     = (const float*)d_in[29];
  const float* o_b     = (const float*)d_in[30];
  const float* br_w    = (const float*)d_in[31];
  const float* br_b    = (const float*)d_in[32];
  const float* f_ln_g  = (const float*)d_in[33];
  const float* f_ln_b  = (const float*)d_in[34];
  const float* head_w  = (const float*)d_in[35];

  // ---- workspace ----
  constexpr size_t SZ_Q = (size_t)BN_ * 256;
  float* ws     = (float*)d_ws;
  float* R_h    = ws;                  // broad bf16 lives here late
  float* R_outp = R_h    + SZ_Q;
  float* R_b1   = R_outp + SZ_Q;       // gh lo / hsn bf16 / sc bf16 / Abuf
  float* R_b2   = R_b1   + SZ_Q;       // gh hi / U bf16 / sc hi
  float* R_b3   = R_b2   + SZ_Q;       // S' bf16 + h bf16 / qkv lo
  float* R_rp   = R_b3   + SZ_Q;       // qkv hi + rpre bf16
  unsigned short* R_loc = (unsigned short*)(R_rp + SZ_Q);   // local bf16 (4*SZ_Q shorts)
  unsigned short* wb = R_loc + 4 * SZ_Q;
  unsigned short* sumT  = wb;                  // [256][256]
  unsigned short* W1cT  = sumT  + 65536;       // [512][256]
  unsigned short* u1cT  = W1cT  + 131072;      // [256][512] = [U1a | Wc]
  unsigned short* u2T   = u1cT  + 131072;      // [256][256]
  unsigned short* qkvT  = u2T   + 65536;       // [768][256]
  unsigned short* brWT  = qkvT  + 196608;      // [256][512] = [brW | WobT]
  unsigned short* headT = brWT  + 131072;      // [256][256]
  unsigned short* whhT  = headT + 65536;       // [768][256]
  float* R_embW = (float*)(whhT + 196608);     // [320][768]
  float* R_bU   = R_embW + 320 * 768;
  float* R_bH   = R_bU + 256;
  float* R_bB2  = R_bH + 512;
  float* R_bQKV = R_bB2 + 256;
  float* R_part = R_bQKV + 768;
  float* R_hp   = R_part + 512;

  // bf16 h (GRU recurrence + msg phase): upper half of b3
  unsigned short* R_hb = ((unsigned short*)R_b3) + SZ_Q;

  float* logits = (float*)d_out;
  dim3 blk(256);

  // ---- weight prep ----
  PrepJobs pj;
  const float* srcs[11] = {sum_w, msg_w1, msg_w1 + 65536, upd_w1, upd_w2,
                           q_w, k_w, v_w, br_w, head_w, gru_whh};
  unsigned short* dsts[11] = {sumT, W1cT, W1cT + 65536, u1cT, u2T,
                              qkvT, qkvT + 65536, qkvT + 131072, brWT, headT, whhT};
  int rows[11] = {256,256,256,256,256,256,256,256,256,256,768};
  int dstd[11] = {256,256,256,512,256,256,256,256,512,256,256};
  int strt[11] = {0,0,0,0,0,0,0,0,0,0,1};
  for (int i = 0; i < 11; ++i) {
    pj.src[i]=srcs[i]; pj.dst[i]=dsts[i]; pj.rows[i]=rows[i];
    pj.dstride[i]=dstd[i]; pj.strt[i]=strt[i];
  }
  prep_w_k<<<dim3(64, 11), blk, 0, stream>>>(pj);
  biasprep_k<<<dim3(1), blk, 0, stream>>>(upd_b1, msg_b2, upd_w1, msg_b1,
                                          o_b, br_w, br_b, q_b, k_b, v_b,
                                          R_bU, R_bH, R_bB2, R_bQKV);
  // Wc^T = (msg_w2 @ U1b)^T -> u1cT cols 256..511
  gemm_mfma<8, 1, 0, 1><<<dim3(4, 4), blk, 0, stream>>>(
      nullptr, msg_w2, nullptr, u1cT + 256, 256, 256, 256, 256, 512,
      upd_w1 + 65536, nullptr, nullptr);
  // Wob^T = (o_w @ br_w)^T -> brWT cols 256..511
  gemm_mfma<8, 1, 0, 1><<<dim3(4, 4), blk, 0, stream>>>(
      nullptr, o_w, nullptr, brWT + 256, 256, 256, 256, 256, 512,
      br_w, nullptr, nullptr);
  // embW = [emb; pos] @ wih^T  (nby=5: identity mapping path)
  gemm_mfma<6, 1, 0, 0><<<dim3(12, 5), blk, 0, stream>>>(
      nullptr, gru_wih, nullptr, R_embW, 320, 768, 256, 256, 768,
      nullptr, emb, pos);

  // ---- patch GRU (h bf16 recurrence) ----
  unsigned short* ghB = (unsigned short*)R_b1;
  gru_pw_k<1><<<dim3(BN_ / 4), blk, 0, stream>>>(
      nullptr, gru_bhh, R_embW, x, gru_bih, R_hb, R_loc, 0);
  for (int t = 1; t < 4; ++t) {
    gemm_big<1, 0, 1><<<dim3(6, 128), blk, 0, stream>>>(
        R_hb, whhT, gru_bhh, ghB, BN_, 768, 256, 256, 768);
    gru_pw_k<0><<<dim3(BN_ / 4), blk, 0, stream>>>(
        ghB, gru_bhh, R_embW, x, gru_bih, R_hb, R_loc, t);
  }
  ln_bf16_k<<<dim3(M1_ / 4), blk, 0, stream>>>(R_loc, pp_ln_g, pp_ln_b);

  // summaries -> h (bf16)
  gemm_mfma<9, 0, 0, 1><<<dim3(4, 256), blk, 0, stream>>>(
      (const float*)R_loc, sumT, sum_b, R_hb, BN_, 256, 256, 256, 256,
      nullptr, nullptr, nullptr);

  // ---- message-passing rounds ----
  unsigned short* hsnB = (unsigned short*)R_b1;
  unsigned short* UB   = (unsigned short*)R_b2;
  unsigned short* Sb   = (unsigned short*)R_b3;
  for (int step = 0; step < 4; ++step) {
    gemm_big<1, 0, 1><<<dim3(4, 128), blk, 0, stream>>>(
        R_hb, W1cT, R_bH, hsnB, BN_, 512, 256, 256, 512);
    smsg_k<<<dim3(BN_ / 4), blk, 0, stream>>>(hsnB, Sb);
    gemm_mfma<10, 0, 1, 1><<<dim3(4, 256), blk, 0, stream>>>(
        (const float*)R_hb, u1cT, R_bU, UB, BN_, 256, 512, 512, 256,
        (const float*)Sb, nullptr, nullptr);
    if (step == 3) {
      gemm_ln<3><<<dim3(BN_ / 16), blk, 0, stream>>>(
          UB, u2T, upd_b2, R_hb, mp_ln_g, mp_ln_b, R_hp, R_outp);
    } else {
      gemm_ln<0><<<dim3(BN_ / 16), blk, 0, stream>>>(
          UB, u2T, upd_b2, R_hb, mp_ln_g, mp_ln_b, nullptr, nullptr);
      if (step == 2) {
        halt1_k<<<dim3(32, 16), blk, 0, stream>>>(R_hb, halt_w, R_part);
        halt2_k<<<dim3(1), dim3(64), 0, stream>>>(R_part, halt_b, R_hp);
        out2_k<<<dim3(BN_ / 4), blk, 0, stream>>>(R_hb, R_hp, R_outp);
      }
    }
  }

  // ---- sparse retrieval attention ----
  unsigned short* qkv  = (unsigned short*)R_b3;           // [BN][768] bf16 (h dead)
  unsigned short* rpre = ((unsigned short*)R_rp) + SZ_Q;  // [BN][256] bf16
  unsigned short* sc   = (unsigned short*)R_b1;           // 32x512x512 bf16
  gemm_big<0, 0, 1><<<dim3(6, 128), blk, 0, stream>>>(
      R_outp, qkvT, R_bQKV, qkv, BN_, 768, 256, 256, 768);
  scores_tri<<<dim3(1152), blk, 0, stream>>>(qkv, sc);
  topk_k<<<dim3(BN_ / 4), blk, 0, stream>>>(sc, qkv, rpre);

  // broad = [outp | rpre] @ brWT^T + biasB2  -> bf16 in R_h region
  unsigned short* broadB = (unsigned short*)R_h;
  gemm_mfma<11, 0, 0, 1><<<dim3(4, 256), blk, 0, stream>>>(
      R_outp, brWT, R_bB2, broadB, BN_, 256, 512, 512, 256,
      (const float*)rpre, nullptr, nullptr);

  // final LN + convert -> Abuf (in b1, sc dead), head GEMM (128-tile) -> logits
  unsigned short* Abuf = (unsigned short*)R_b1;
  ln_cvt_k<<<dim3(M1_ / 4), blk, 0, stream>>>(R_loc, broadB, f_ln_g, f_ln_b, Abuf);
  gemm_big<1, 0, 0><<<dim3(2, 512), blk, 0, stream>>>(
      Abuf, headT, nullptr, logits, M1_, 256, 256, 256, 256);

  kl_k<<<dim3(1), dim3(64), 0, stream>>>(R_hp, logits + (size_t)M1_ * 256);
}

// Round 18
// 560.504 us; speedup vs baseline: 1.1424x; 1.0275x over previous
//
#include <hip/hip_runtime.h>
#include <cmath>

// ---------------------------------------------------------------------------
// SutraV04 round 17 = round 16 (best, 569-576 us) + pp-LN fused into gru_pw
// (each 64-lane wave owns exactly one local row; LN via __shfl_xor on f32
// hnew before the bf16 local store; h keeps raw hnew for the recurrence).
// Removes ln_bf16_k: 67 MB round-trip + 1 launch. Pointwise-into-pointwise
// fusion — NOT the GEMM-staging anti-pattern.
// ---------------------------------------------------------------------------

constexpr int N_   = 512;
constexpr int B_   = 32;
constexpr int BN_  = B_ * N_;   // 16384
constexpr int M1_  = BN_ * 4;   // 65536

typedef short bf16x8 __attribute__((ext_vector_type(8)));
typedef float f32x4  __attribute__((ext_vector_type(4)));

__device__ __forceinline__ float gelu_f(float x) {
  return 0.5f * x * (1.0f + erff(x * 0.70710678118654752440f));
}
__device__ __forceinline__ float sigm_f(float x) {
  return 1.0f / (1.0f + expf(-x));
}
__device__ __forceinline__ unsigned short f2bf(float f) {
  union { float f; unsigned int u; } c; c.f = f;
  unsigned int u = c.u;
  u += 0x7FFFu + ((u >> 16) & 1u);
  return (unsigned short)(u >> 16);
}
__device__ __forceinline__ float bf2f(unsigned short u) {
  union { unsigned int u; float f; } c; c.u = ((unsigned int)u) << 16;
  return c.f;
}
__device__ __forceinline__ int phys(int g, int r) {      // 64-row tiles
  return ((g << 6) | (r ^ g)) << 3;
}
__device__ __forceinline__ int phys128(int g, int r) {   // 128-row tiles
  return ((g << 7) | (r ^ g)) << 3;
}
__device__ __forceinline__ int phys16(int g, int r) {    // 16-row tiles
  return ((g << 4) | (r ^ g)) << 3;
}

// XCD-aware block remap: same-A-panel blocks (all nB of a chunk of mB) land
// on one XCD (flat % 8). Bijective; falls back to identity if nby % 8 != 0.
__device__ __forceinline__ void xcd_map(int& mB, int& nB) {
  int nbx = gridDim.x, nby = gridDim.y;
  if ((nby & 7) == 0) {
    int flat = blockIdx.y * nbx + blockIdx.x;
    int chunk = nby >> 3;
    int xcd = flat & 7, s2 = flat >> 3;
    int q = s2 / nbx;
    mB = xcd * chunk + q;
    nB = s2 - q * nbx;
  } else {
    mB = blockIdx.y; nB = blockIdx.x;
  }
}

// ---- 128x128-tile MFMA GEMM ----------------------------------------------
// AMODE: 0 f32 [m][K]; 1 bf16 [m][K].  EPI: 0 none, 1 gelu. COUT: 0 f32, 1 bf16.
template<int AMODE, int EPI, int COUT>
__global__ __launch_bounds__(256)
void gemm_big(const void* __restrict__ A, const unsigned short* __restrict__ Bt,
              const float* __restrict__ bias, void* __restrict__ C,
              int M, int Nn, int K, int bstride, int ldC)
{
  __shared__ short As[4 * 128 * 8];
  __shared__ short Bs[4 * 128 * 8];
  const int t  = threadIdx.x;
  int mB, nB;
  xcd_map(mB, nB);
  const int m0 = mB * 128, n0 = nB * 128;
  const int lane = t & 63, w = t >> 6;
  const int wr = w >> 1, wc = w & 1;
  const int fr = lane & 15, fg = lane >> 4;

  f32x4 acc[4][4] = {};

  for (int k0 = 0; k0 < K; k0 += 32) {
    #pragma unroll
    for (int c = 0; c < 2; ++c) {
      int idx = t + c * 256;
      int row = idx >> 2, g = idx & 3;
      int kk = k0 + g * 8;
      bf16x8 av;
      if constexpr (AMODE == 1) {
        av = *(const bf16x8*)&((const unsigned short*)A)[(size_t)(m0 + row) * K + kk];
      } else {
        const float4* p = (const float4*)&((const float*)A)[(size_t)(m0 + row) * K + kk];
        float4 a = p[0], b = p[1];
        av[0]=(short)f2bf(a.x); av[1]=(short)f2bf(a.y); av[2]=(short)f2bf(a.z); av[3]=(short)f2bf(a.w);
        av[4]=(short)f2bf(b.x); av[5]=(short)f2bf(b.y); av[6]=(short)f2bf(b.z); av[7]=(short)f2bf(b.w);
      }
      *(bf16x8*)&As[phys128(g, row)] = av;
      *(bf16x8*)&Bs[phys128(g, row)] =
          *(const bf16x8*)&Bt[(size_t)(n0 + row) * bstride + kk];
    }
    __syncthreads();

    bf16x8 a[4], b[4];
    #pragma unroll
    for (int i = 0; i < 4; ++i)
      a[i] = *(const bf16x8*)&As[phys128(fg, wr * 64 + i * 16 + fr)];
    #pragma unroll
    for (int j = 0; j < 4; ++j)
      b[j] = *(const bf16x8*)&Bs[phys128(fg, wc * 64 + j * 16 + fr)];
    #pragma unroll
    for (int i = 0; i < 4; ++i)
      #pragma unroll
      for (int j = 0; j < 4; ++j)
        acc[i][j] = __builtin_amdgcn_mfma_f32_16x16x32_bf16(a[i], b[j], acc[i][j], 0, 0, 0);
    __syncthreads();
  }

  #pragma unroll
  for (int i = 0; i < 4; ++i)
    #pragma unroll
    for (int j = 0; j < 4; ++j) {
      int col = n0 + wc * 64 + j * 16 + fr;
      float bcol = bias ? bias[col] : 0.0f;
      #pragma unroll
      for (int r = 0; r < 4; ++r) {
        int row = m0 + wr * 64 + i * 16 + fg * 4 + r;
        float vv = acc[i][j][r] + bcol;
        if constexpr (EPI == 1) vv = gelu_f(vv);
        if constexpr (COUT == 0)
          ((float*)C)[(size_t)row * ldC + col] = vv;
        else
          ((unsigned short*)C)[(size_t)row * ldC + col] = f2bf(vv);
      }
    }
}

// ---- 64-tile gather GEMM --------------------------------------------------
// MODE: 6 emb/pos rows; 8 transposed f32 gather P2[k*256+m]; 9 bf16 patch-mean;
//       10 concat(bf16 A | bf16 P2); 11 concat(f32 A | bf16 P2)
// BSRC: 0 bf16 Bt; 1 fp32.  EPI: 0 none, 1 gelu.  COUT: 0 f32, 1 bf16.
template<int MODE, int BSRC, int EPI, int COUT>
__global__ __launch_bounds__(256)
void gemm_mfma(const float* __restrict__ A, const void* __restrict__ Bsrc,
               const float* __restrict__ bias, void* __restrict__ C,
               int M, int Nn, int K, int bstride, int ldC,
               const float* __restrict__ P2,
               const float* __restrict__ emb, const float* __restrict__ pos)
{
  __shared__ short As[4 * 64 * 8];
  __shared__ short Bs[4 * 64 * 8];
  const int tid  = threadIdx.x;
  int mB, nB;
  xcd_map(mB, nB);
  const int m0 = mB * 64, n0 = nB * 64;
  const int srow = tid >> 2, sg = tid & 3;
  const int lane = tid & 63, w = tid >> 6;
  const int wr   = w >> 1,  wc = w & 1;
  const int fr   = lane & 15, fg = lane >> 4;

  f32x4 acc[2][2] = {};

  for (int k0 = 0; k0 < K; k0 += 32) {
    {
      int m = m0 + srow, k = k0 + sg * 8;
      bf16x8 tv;
      if constexpr (MODE == 10) {
        if (k < 256)
          tv = *(const bf16x8*)&((const unsigned short*)A)[(size_t)m * 256 + k];
        else
          tv = *(const bf16x8*)&((const unsigned short*)P2)[(size_t)m * 256 + (k - 256)];
      } else if constexpr (MODE == 11) {
        if (k < 256) {
          const float4* p = (const float4*)(A + (size_t)m * 256 + k);
          float4 a = p[0], b = p[1];
          tv[0]=(short)f2bf(a.x); tv[1]=(short)f2bf(a.y); tv[2]=(short)f2bf(a.z); tv[3]=(short)f2bf(a.w);
          tv[4]=(short)f2bf(b.x); tv[5]=(short)f2bf(b.y); tv[6]=(short)f2bf(b.z); tv[7]=(short)f2bf(b.w);
        } else {
          tv = *(const bf16x8*)&((const unsigned short*)P2)[(size_t)m * 256 + (k - 256)];
        }
      } else {
        float v[8];
        if constexpr (MODE == 6) {
          const float* src = nullptr;
          if (m < 256) src = emb + (size_t)m * 256 + k;
          else if (m < 260) src = pos + (size_t)(m - 256) * 256 + k;
          if (src) {
            const float4* p = (const float4*)src;
            float4 a = p[0], b = p[1];
            v[0]=a.x; v[1]=a.y; v[2]=a.z; v[3]=a.w; v[4]=b.x; v[5]=b.y; v[6]=b.z; v[7]=b.w;
          } else {
            #pragma unroll
            for (int j = 0; j < 8; ++j) v[j] = 0.f;
          }
        } else if constexpr (MODE == 8) {
          #pragma unroll
          for (int j = 0; j < 8; ++j) v[j] = P2[(size_t)(k + j) * 256 + m];
        } else { // 9
          const unsigned short* Ab = (const unsigned short*)A;
          const unsigned short* base = Ab + (size_t)m * 1024 + k;
          bf16x8 r0 = *(const bf16x8*)(base);
          bf16x8 r1 = *(const bf16x8*)(base + 256);
          bf16x8 r2 = *(const bf16x8*)(base + 512);
          bf16x8 r3 = *(const bf16x8*)(base + 768);
          #pragma unroll
          for (int j = 0; j < 8; ++j)
            v[j] = 0.25f * (bf2f((unsigned short)r0[j]) + bf2f((unsigned short)r1[j]) +
                            bf2f((unsigned short)r2[j]) + bf2f((unsigned short)r3[j]));
        }
        #pragma unroll
        for (int j = 0; j < 8; ++j) tv[j] = (short)f2bf(v[j]);
      }
      *(bf16x8*)&As[phys(sg, srow)] = tv;
    }
    if constexpr (BSRC == 0) {
      const unsigned short* Bt = (const unsigned short*)Bsrc;
      *(bf16x8*)&Bs[phys(sg, srow)] =
          *(const bf16x8*)&Bt[(size_t)(n0 + srow) * bstride + k0 + sg * 8];
    } else {
      const float* Bf = (const float*)Bsrc;
      const float4* p = (const float4*)(Bf + (size_t)(n0 + srow) * bstride + k0 + sg * 8);
      float4 a = p[0], b = p[1];
      bf16x8 tv;
      tv[0]=(short)f2bf(a.x); tv[1]=(short)f2bf(a.y); tv[2]=(short)f2bf(a.z); tv[3]=(short)f2bf(a.w);
      tv[4]=(short)f2bf(b.x); tv[5]=(short)f2bf(b.y); tv[6]=(short)f2bf(b.z); tv[7]=(short)f2bf(b.w);
      *(bf16x8*)&Bs[phys(sg, srow)] = tv;
    }
    __syncthreads();

    bf16x8 a0 = *(const bf16x8*)&As[phys(fg, wr * 32 + fr)];
    bf16x8 a1 = *(const bf16x8*)&As[phys(fg, wr * 32 + 16 + fr)];
    bf16x8 b0 = *(const bf16x8*)&Bs[phys(fg, wc * 32 + fr)];
    bf16x8 b1 = *(const bf16x8*)&Bs[phys(fg, wc * 32 + 16 + fr)];
    acc[0][0] = __builtin_amdgcn_mfma_f32_16x16x32_bf16(a0, b0, acc[0][0], 0, 0, 0);
    acc[0][1] = __builtin_amdgcn_mfma_f32_16x16x32_bf16(a0, b1, acc[0][1], 0, 0, 0);
    acc[1][0] = __builtin_amdgcn_mfma_f32_16x16x32_bf16(a1, b0, acc[1][0], 0, 0, 0);
    acc[1][1] = __builtin_amdgcn_mfma_f32_16x16x32_bf16(a1, b1, acc[1][1], 0, 0, 0);
    __syncthreads();
  }

  #pragma unroll
  for (int i = 0; i < 2; ++i) {
    #pragma unroll
    for (int j = 0; j < 2; ++j) {
      int row0 = m0 + wr * 32 + i * 16 + fg * 4;
      int col  = n0 + wc * 32 + j * 16 + fr;
      float bcol = bias ? bias[col] : 0.0f;
      #pragma unroll
      for (int r = 0; r < 4; ++r) {
        float vv = acc[i][j][r] + bcol;
        if constexpr (EPI == 1) vv = gelu_f(vv);
        int row = row0 + r;
        if constexpr (COUT == 0)
          ((float*)C)[(size_t)row * ldC + col] = vv;
        else
          ((unsigned short*)C)[(size_t)row * ldC + col] = f2bf(vv);
      }
    }
  }
}

// ---- fused upd-GEMM + residual + LN; 16-row full-width tile ---------------
template<int OUTM>
__global__ __launch_bounds__(256)
void gemm_ln(const unsigned short* __restrict__ U, const unsigned short* __restrict__ u2T,
             const float* __restrict__ bias, unsigned short* __restrict__ h,
             const float* __restrict__ g, const float* __restrict__ bb,
             const float* __restrict__ hp, float* __restrict__ outp)
{
  __shared__ short As[4 * 16 * 8];
  __shared__ short Bs[4 * 256 * 8];
  __shared__ float psum[4][16], pssq[4][16];
  const int m0 = blockIdx.x * 16;
  const int t  = threadIdx.x;
  const int lane = t & 63, w = t >> 6;
  const int fr = lane & 15, fg = lane >> 4;

  f32x4 acc[4] = {};
  for (int k0 = 0; k0 < 256; k0 += 32) {
    if (t < 64) {
      int row = t >> 2, gq = t & 3;
      *(bf16x8*)&As[phys16(gq, row)] =
          *(const bf16x8*)&U[(size_t)(m0 + row) * 256 + k0 + gq * 8];
    }
    const unsigned short* brow = u2T + (size_t)t * 256 + k0;
    #pragma unroll
    for (int gq = 0; gq < 4; ++gq)
      *(bf16x8*)&Bs[((gq << 8) | (t ^ gq)) << 3] = *(const bf16x8*)(brow + gq * 8);
    __syncthreads();
    bf16x8 a = *(const bf16x8*)&As[phys16(fg, fr)];
    #pragma unroll
    for (int j = 0; j < 4; ++j) {
      int n = 64 * w + 16 * j + fr;
      bf16x8 b = *(const bf16x8*)&Bs[((fg << 8) | (n ^ fg)) << 3];
      acc[j] = __builtin_amdgcn_mfma_f32_16x16x32_bf16(a, b, acc[j], 0, 0, 0);
    }
    __syncthreads();
  }

  float bcol[4], gv[4], bv[4];
  #pragma unroll
  for (int j = 0; j < 4; ++j) {
    int col = 64 * w + 16 * j + fr;
    bcol[j] = bias[col]; gv[j] = g[col]; bv[j] = bb[col];
  }
  float vsum[4] = {}, vssq[4] = {};
  #pragma unroll
  for (int j = 0; j < 4; ++j) {
    int col = 64 * w + 16 * j + fr;
    #pragma unroll
    for (int r = 0; r < 4; ++r) {
      int row = m0 + 4 * fg + r;
      float v = acc[j][r] + bcol[j] + bf2f(h[(size_t)row * 256 + col]);
      acc[j][r] = v;
      vsum[r] += v;
      vssq[r] += v * v;
    }
  }
  #pragma unroll
  for (int off = 1; off < 16; off <<= 1) {
    #pragma unroll
    for (int r = 0; r < 4; ++r) {
      vsum[r] += __shfl_xor(vsum[r], off, 64);
      vssq[r] += __shfl_xor(vssq[r], off, 64);
    }
  }
  if (fr == 0) {
    #pragma unroll
    for (int r = 0; r < 4; ++r) {
      psum[w][4 * fg + r] = vsum[r];
      pssq[w][4 * fg + r] = vssq[r];
    }
  }
  __syncthreads();

  float rem = 0.f;
  if constexpr (OUTM == 3) rem = 1.0f - hp[m0 >> 9];
  #pragma unroll
  for (int r = 0; r < 4; ++r) {
    int rr = 4 * fg + r;
    float s  = psum[0][rr] + psum[1][rr] + psum[2][rr] + psum[3][rr];
    float q2 = pssq[0][rr] + pssq[1][rr] + pssq[2][rr] + pssq[3][rr];
    float mean = s * (1.0f / 256.0f);
    float var  = q2 * (1.0f / 256.0f) - mean * mean;
    float inv  = rsqrtf(var + 1e-5f);
    int row = m0 + rr;
    #pragma unroll
    for (int j = 0; j < 4; ++j) {
      int col = 64 * w + 16 * j + fr;
      float y = (acc[j][r] - mean) * inv * gv[j] + bv[j];
      h[(size_t)row * 256 + col] = f2bf(y);
      if constexpr (OUTM == 3) outp[(size_t)row * 256 + col] += rem * y;
    }
  }
}

// ---- causal tri-tile scores (bf16 out), XCD-swizzled ----------------------
__global__ __launch_bounds__(256)
void scores_tri(const unsigned short* __restrict__ qkv, unsigned short* __restrict__ sc)
{
  int flat = blockIdx.x;
  int xcd = flat & 7, s = flat >> 3;
  int bhi = s / 36, tile = s - bhi * 36;
  int b = bhi * 8 + xcd;
  int ti = 0;
  while ((ti + 1) * (ti + 2) / 2 <= tile) ++ti;
  int tj = tile - ti * (ti + 1) / 2;
  const int m0 = ti * 64, n0 = tj * 64;
  const unsigned short* Aq = qkv + (size_t)b * N_ * 768;
  const unsigned short* Bk = Aq + 256;

  __shared__ short As[4 * 64 * 8];
  __shared__ short Bs[4 * 64 * 8];
  const int tid  = threadIdx.x;
  const int srow = tid >> 2, sg = tid & 3;
  const int lane = tid & 63, w = tid >> 6;
  const int wr   = w >> 1,  wc = w & 1;
  const int fr   = lane & 15, fg = lane >> 4;

  f32x4 acc[2][2] = {};
  for (int k0 = 0; k0 < 256; k0 += 32) {
    *(bf16x8*)&As[phys(sg, srow)] =
        *(const bf16x8*)&Aq[(size_t)(m0 + srow) * 768 + k0 + sg * 8];
    *(bf16x8*)&Bs[phys(sg, srow)] =
        *(const bf16x8*)&Bk[(size_t)(n0 + srow) * 768 + k0 + sg * 8];
    __syncthreads();
    bf16x8 a0 = *(const bf16x8*)&As[phys(fg, wr * 32 + fr)];
    bf16x8 a1 = *(const bf16x8*)&As[phys(fg, wr * 32 + 16 + fr)];
    bf16x8 b0 = *(const bf16x8*)&Bs[phys(fg, wc * 32 + fr)];
    bf16x8 b1 = *(const bf16x8*)&Bs[phys(fg, wc * 32 + 16 + fr)];
    acc[0][0] = __builtin_amdgcn_mfma_f32_16x16x32_bf16(a0, b0, acc[0][0], 0, 0, 0);
    acc[0][1] = __builtin_amdgcn_mfma_f32_16x16x32_bf16(a0, b1, acc[0][1], 0, 0, 0);
    acc[1][0] = __builtin_amdgcn_mfma_f32_16x16x32_bf16(a1, b0, acc[1][0], 0, 0, 0);
    acc[1][1] = __builtin_amdgcn_mfma_f32_16x16x32_bf16(a1, b1, acc[1][1], 0, 0, 0);
    __syncthreads();
  }
  unsigned short* scb = sc + (size_t)b * N_ * N_;
  #pragma unroll
  for (int i = 0; i < 2; ++i) {
    #pragma unroll
    for (int j = 0; j < 2; ++j) {
      int row0 = m0 + wr * 32 + i * 16 + fg * 4;
      int col  = n0 + wc * 32 + j * 16 + fr;
      #pragma unroll
      for (int r = 0; r < 4; ++r) {
        int row = row0 + r;
        float vv = acc[i][j][r] * 0.0625f;
        if (col > row) vv = -__builtin_inff();
        scb[(size_t)row * N_ + col] = f2bf(vv);
      }
    }
  }
}

// ---- weight prep ----------------------------------------------------------
struct PrepJobs {
  const float* src[12];
  unsigned short* dst[12];
  int rows[12];
  int dstride[12];
  int strt[12];
};
__global__ __launch_bounds__(256)
void prep_w_k(PrepJobs pj)
{
  int jid = blockIdx.y;
  const float* src = pj.src[jid];
  unsigned short* dst = pj.dst[jid];
  int ds = pj.dstride[jid];
  int total = pj.rows[jid] << 8;
  if (pj.strt[jid]) {
    for (int i = blockIdx.x * 256 + threadIdx.x; i < total; i += gridDim.x * 256) {
      int k = i & 255, n = i >> 8;
      dst[(size_t)n * ds + k] = f2bf(src[i]);
    }
  } else {
    for (int i = blockIdx.x * 256 + threadIdx.x; i < total; i += gridDim.x * 256) {
      int k = i & 255, n = i >> 8;
      dst[(size_t)n * ds + k] = f2bf(src[(size_t)k * 256 + n]);
    }
  }
}

// ---- bias prep ------------------------------------------------------------
__global__ __launch_bounds__(256)
void biasprep_k(const float* __restrict__ upd_b1, const float* __restrict__ msg_b2,
                const float* __restrict__ upd_w1, const float* __restrict__ msg_b1,
                const float* __restrict__ o_b, const float* __restrict__ br_w,
                const float* __restrict__ br_b, const float* __restrict__ q_b,
                const float* __restrict__ k_b, const float* __restrict__ v_b,
                float* __restrict__ biasU, float* __restrict__ biasHsn,
                float* __restrict__ biasB2, float* __restrict__ bQKV)
{
  int c = threadIdx.x;
  float s = upd_b1[c];
  for (int k = 0; k < 256; ++k)
    s += msg_b2[k] * upd_w1[(size_t)(256 + k) * 256 + c];
  biasU[c] = s;
  biasHsn[c] = msg_b1[c];
  biasHsn[256 + c] = 0.f;
  float s2 = br_b[c];
  for (int k = 0; k < 256; ++k)
    s2 += o_b[k] * br_w[(size_t)k * 256 + c];
  biasB2[c] = s2;
  bQKV[c] = q_b[c]; bQKV[256 + c] = k_b[c]; bQKV[512 + c] = v_b[c];
}

// ---- GRU pointwise + fused pp-LN (one wave per local row) -----------------
template<int FIRST>
__global__ __launch_bounds__(256)
void gru_pw_k(const unsigned short* __restrict__ gh, const float* __restrict__ bhh,
              const float* __restrict__ embW, const int* __restrict__ x,
              const float* __restrict__ bih,
              const float* __restrict__ lng, const float* __restrict__ lnb,
              unsigned short* __restrict__ h, unsigned short* __restrict__ local, int t)
{
  int i   = blockIdx.x * 256 + threadIdx.x;   // over BN*64 groups
  int row = i >> 6, d0 = (i & 63) << 2;
  int tok = x[row * 4 + t];
  const float* er = embW + (size_t)tok * 768;
  const float* pr = embW + (size_t)(256 + t) * 768;
  float4 e0 = *(const float4*)(er + d0);
  float4 e1 = *(const float4*)(er + 256 + d0);
  float4 e2 = *(const float4*)(er + 512 + d0);
  float4 p0 = *(const float4*)(pr + d0);
  float4 p1 = *(const float4*)(pr + 256 + d0);
  float4 p2 = *(const float4*)(pr + 512 + d0);
  float4 q0 = *(const float4*)(bih + d0);
  float4 q1 = *(const float4*)(bih + 256 + d0);
  float4 q2 = *(const float4*)(bih + 512 + d0);
  float ir[4]  = {e0.x+p0.x+q0.x, e0.y+p0.y+q0.y, e0.z+p0.z+q0.z, e0.w+p0.w+q0.w};
  float iz[4]  = {e1.x+p1.x+q1.x, e1.y+p1.y+q1.y, e1.z+p1.z+q1.z, e1.w+p1.w+q1.w};
  float inn[4] = {e2.x+p2.x+q2.x, e2.y+p2.y+q2.y, e2.z+p2.z+q2.z, e2.w+p2.w+q2.w};
  float hr[4], hz[4], hn[4];
  if constexpr (FIRST) {
    float4 b0 = *(const float4*)(bhh + d0);
    float4 b1 = *(const float4*)(bhh + 256 + d0);
    float4 b2 = *(const float4*)(bhh + 512 + d0);
    hr[0]=b0.x; hr[1]=b0.y; hr[2]=b0.z; hr[3]=b0.w;
    hz[0]=b1.x; hz[1]=b1.y; hz[2]=b1.z; hz[3]=b1.w;
    hn[0]=b2.x; hn[1]=b2.y; hn[2]=b2.z; hn[3]=b2.w;
  } else {
    const unsigned short* gr = gh + (size_t)row * 768;
    ushort4 u0 = *(const ushort4*)(gr + d0);
    ushort4 u1 = *(const ushort4*)(gr + 256 + d0);
    ushort4 u2 = *(const ushort4*)(gr + 512 + d0);
    hr[0]=bf2f(u0.x); hr[1]=bf2f(u0.y); hr[2]=bf2f(u0.z); hr[3]=bf2f(u0.w);
    hz[0]=bf2f(u1.x); hz[1]=bf2f(u1.y); hz[2]=bf2f(u1.z); hz[3]=bf2f(u1.w);
    hn[0]=bf2f(u2.x); hn[1]=bf2f(u2.y); hn[2]=bf2f(u2.z); hn[3]=bf2f(u2.w);
  }
  ushort4 hprev = {0, 0, 0, 0};
  if constexpr (!FIRST) hprev = *(const ushort4*)&h[(size_t)row * 256 + d0];
  float hp4[4] = {bf2f(hprev.x), bf2f(hprev.y), bf2f(hprev.z), bf2f(hprev.w)};
  float hv[4];
  ushort4 oh;
  #pragma unroll
  for (int e = 0; e < 4; ++e) {
    float r  = sigm_f(ir[e] + hr[e]);
    float zg = sigm_f(iz[e] + hz[e]);
    float nn = tanhf(inn[e] + r * hn[e]);
    float hnew;
    if constexpr (FIRST) hnew = (1.0f - zg) * nn;
    else                 hnew = (1.0f - zg) * nn + zg * hp4[e];
    hv[e] = hnew;
    ((unsigned short*)&oh)[e] = f2bf(hnew);
  }
  *(ushort4*)&h[(size_t)row * 256 + d0] = oh;

  // fused pp-LN over this wave's row (64 lanes x 4 elems = 256)
  float s = hv[0] + hv[1] + hv[2] + hv[3];
  #pragma unroll
  for (int off = 1; off < 64; off <<= 1) s += __shfl_xor(s, off, 64);
  float mean = s * (1.0f / 256.0f);
  float ss = 0.f;
  #pragma unroll
  for (int e = 0; e < 4; ++e) { float d = hv[e] - mean; ss += d * d; }
  #pragma unroll
  for (int off = 1; off < 64; off <<= 1) ss += __shfl_xor(ss, off, 64);
  float inv = rsqrtf(ss * (1.0f / 256.0f) + 1e-5f);
  const float4 g4 = *(const float4*)(lng + d0);
  const float4 b4 = *(const float4*)(lnb + d0);
  ushort4 ol;
  ol.x = f2bf((hv[0] - mean) * inv * g4.x + b4.x);
  ol.y = f2bf((hv[1] - mean) * inv * g4.y + b4.y);
  ol.z = f2bf((hv[2] - mean) * inv * g4.z + b4.z);
  ol.w = f2bf((hv[3] - mean) * inv * g4.w + b4.w);
  *(ushort4*)&local[((size_t)row * 4 + t) * 256 + d0] = ol;
}

// ---- S' = rowscale( sum_kk gelu(hs + shift(hn)) ) -> bf16 -----------------
__global__ __launch_bounds__(256)
void smsg_k(const unsigned short* __restrict__ hsn, unsigned short* __restrict__ S)
{
  int i = blockIdx.x * 256 + threadIdx.x;   // BN*64
  int m = i >> 6, d4 = (i & 63) << 2;
  int n = m & (N_ - 1);
  ushort4 hsu = *(const ushort4*)&hsn[(size_t)m * 512 + d4];
  float hs0 = bf2f(hsu.x), hs1 = bf2f(hsu.y), hs2 = bf2f(hsu.z), hs3 = bf2f(hsu.w);
  float a0 = 0.f, a1 = 0.f, a2 = 0.f, a3 = 0.f;
  #pragma unroll
  for (int kk = 0; kk < 5; ++kk) {
    int idx = n + kk - 4;
    if (idx >= 0) {
      ushort4 hv = *(const ushort4*)&hsn[(size_t)(m + kk - 4) * 512 + 256 + d4];
      a0 += gelu_f(hs0 + bf2f(hv.x));
      a1 += gelu_f(hs1 + bf2f(hv.y));
      a2 += gelu_f(hs2 + bf2f(hv.z));
      a3 += gelu_f(hs3 + bf2f(hv.w));
    }
  }
  float sc1 = 1.0f / (float)((n < 4 ? n : 4) + 1);
  ushort4 o = {f2bf(a0 * sc1), f2bf(a1 * sc1), f2bf(a2 * sc1), f2bf(a3 * sc1)};
  *(ushort4*)&S[(size_t)m * 256 + d4] = o;
}

// ---- final LN: local bf16 + broad bf16 -> Abuf bf16 -----------------------
__global__ __launch_bounds__(256)
void ln_cvt_k(const unsigned short* __restrict__ X, const unsigned short* __restrict__ Add,
              const float* __restrict__ g, const float* __restrict__ bb,
              unsigned short* __restrict__ Out)
{
  int wave = threadIdx.x >> 6, lane = threadIdx.x & 63;
  int row  = blockIdx.x * 4 + wave;
  ushort4 u = *(const ushort4*)&X[(size_t)row * 256 + lane * 4];
  ushort4 a = *(const ushort4*)&Add[(size_t)(row >> 2) * 256 + lane * 4];
  float x[4] = {bf2f(u.x) + bf2f(a.x), bf2f(u.y) + bf2f(a.y),
                bf2f(u.z) + bf2f(a.z), bf2f(u.w) + bf2f(a.w)};
  float s = x[0] + x[1] + x[2] + x[3];
  #pragma unroll
  for (int off = 1; off < 64; off <<= 1) s += __shfl_xor(s, off, 64);
  float mean = s * (1.0f / 256.0f);
  float ss = 0.f;
  #pragma unroll
  for (int j = 0; j < 4; ++j) { float d = x[j] - mean; ss += d * d; }
  #pragma unroll
  for (int off = 1; off < 64; off <<= 1) ss += __shfl_xor(ss, off, 64);
  float inv = rsqrtf(ss * (1.0f / 256.0f) + 1e-5f);
  ushort4 o;
  o.x = f2bf((x[0] - mean) * inv * g[lane*4+0] + bb[lane*4+0]);
  o.y = f2bf((x[1] - mean) * inv * g[lane*4+1] + bb[lane*4+1]);
  o.z = f2bf((x[2] - mean) * inv * g[lane*4+2] + bb[lane*4+2]);
  o.w = f2bf((x[3] - mean) * inv * g[lane*4+3] + bb[lane*4+3]);
  *(ushort4*)&Out[(size_t)row * 256 + lane * 4] = o;
}

// ---- halting (h bf16) ------------------------------------------------------
__global__ __launch_bounds__(256)
void halt1_k(const unsigned short* __restrict__ h, const float* __restrict__ hw,
             float* __restrict__ part)
{
  int b = blockIdx.x, s = blockIdx.y, tid = threadIdx.x;
  const unsigned short* p = h + ((size_t)b * N_ + s * 32) * 256;
  float acc = 0.f;
  for (int i = tid * 4; i < 32 * 256; i += 1024) {
    ushort4 u = *(const ushort4*)&p[i];
    const float4 w4 = *(const float4*)&hw[i & 255];
    acc += bf2f(u.x) * w4.x + bf2f(u.y) * w4.y + bf2f(u.z) * w4.z + bf2f(u.w) * w4.w;
  }
  __shared__ float red[256];
  red[tid] = acc; __syncthreads();
  for (int off = 128; off > 0; off >>= 1) {
    if (tid < off) red[tid] += red[tid + off];
    __syncthreads();
  }
  if (tid == 0) part[b * 16 + s] = red[0];
}
__global__ __launch_bounds__(64)
void halt2_k(const float* __restrict__ part, const float* __restrict__ hb,
             float* __restrict__ hp)
{
  int b = threadIdx.x;
  if (b < 32) {
    float s = 0.f;
    for (int i = 0; i < 16; ++i) s += part[b * 16 + i];
    hp[b] = sigm_f(s * (1.0f / (float)N_) + hb[0]);
  }
}
__global__ __launch_bounds__(256)
void out2_k(const unsigned short* __restrict__ h, const float* __restrict__ hp,
            float* __restrict__ outp)
{
  int i = blockIdx.x * 256 + threadIdx.x;   // groups of 4
  float hpv = hp[i >> 15];
  ushort4 u = *(const ushort4*)&h[(size_t)i * 4];
  float4 o = {hpv * bf2f(u.x), hpv * bf2f(u.y), hpv * bf2f(u.z), hpv * bf2f(u.w)};
  *(float4*)&outp[(size_t)i * 4] = o;
}

// ---- wave-per-row top-8 + softmax + V gather (sc bf16, qkv stride 768) ----
__global__ __launch_bounds__(256)
void topk_k(const unsigned short* __restrict__ sc, const unsigned short* __restrict__ qkv,
            unsigned short* __restrict__ rpre)
{
  const float NEG = -__builtin_inff();
  int wave = threadIdx.x >> 6, lane = threadIdx.x & 63;
  int rowg = blockIdx.x * 4 + wave;
  int b = rowg >> 9, n = rowg & (N_ - 1);
  const unsigned short* srow = sc + (size_t)rowg * N_;
  float v[8];
  #pragma unroll
  for (int j = 0; j < 8; ++j) {
    int col = lane + j * 64;
    v[j] = (col <= n) ? bf2f(srow[col]) : NEG;
  }
  float tv[8]; int ti[8];
  #pragma unroll
  for (int it = 0; it < 8; ++it) {
    float bv = v[0]; int bi = lane;
    #pragma unroll
    for (int j = 1; j < 8; ++j)
      if (v[j] > bv) { bv = v[j]; bi = lane + j * 64; }
    #pragma unroll
    for (int off = 1; off < 64; off <<= 1) {
      float ov = __shfl_xor(bv, off, 64);
      int   oi = __shfl_xor(bi, off, 64);
      if (ov > bv || (ov == bv && oi < bi)) { bv = ov; bi = oi; }
    }
    tv[it] = bv; ti[it] = bi;
    if ((bi & 63) == lane) v[bi >> 6] = NEG;
  }
  float mx = tv[0];
  float wsum = 0.f, wj[8];
  #pragma unroll
  for (int j = 0; j < 8; ++j) { wj[j] = expf(tv[j] - mx); wsum += wj[j]; }
  float inv = 1.0f / wsum;
  const unsigned short* vb = qkv + 512;
  int d0 = lane * 4;
  float a0 = 0.f, a1 = 0.f, a2 = 0.f, a3 = 0.f;
  #pragma unroll
  for (int j = 0; j < 8; ++j) {
    float wgt = wj[j] * inv;
    ushort4 vv = *(const ushort4*)&vb[((size_t)(b * N_ + ti[j])) * 768 + d0];
    a0 += wgt * bf2f(vv.x); a1 += wgt * bf2f(vv.y);
    a2 += wgt * bf2f(vv.z); a3 += wgt * bf2f(vv.w);
  }
  ushort4 o = {f2bf(a0), f2bf(a1), f2bf(a2), f2bf(a3)};
  *(ushort4*)&rpre[(size_t)rowg * 256 + d0] = o;
}

// ---- KL scalar ------------------------------------------------------------
__global__ void kl_k(const float* __restrict__ hp, float* __restrict__ out)
{
  if (threadIdx.x == 0 && blockIdx.x == 0) {
    float hm = 0.f;
    for (int b = 0; b < 32; ++b) hm += hp[b];
    hm *= (1.0f / 32.0f);
    const float l1e8 = logf(1e-8f);
    float kl = 0.f;
    kl += 0.2f    * (logf(0.2f)    - l1e8);
    kl += 0.16f   * (logf(0.16f)   - l1e8);
    kl += 0.128f  * (logf(0.128f)  - logf(hm + 1e-8f));
    kl += 0.1024f * (logf(0.1024f) - logf(1.0f + 1e-8f));
    out[0] = kl * 0.25f;
  }
}

// ---------------------------------------------------------------------------
extern "C" void kernel_launch(void* const* d_in, const int* in_sizes, int n_in,
                              void* d_out, int out_size, void* d_ws, size_t ws_size,
                              hipStream_t stream)
{
  const int*   x       = (const int*)  d_in[0];
  const float* emb     = (const float*)d_in[1];
  const float* pos     = (const float*)d_in[2];
  const float* gru_wih = (const float*)d_in[3];
  const float* gru_whh = (const float*)d_in[4];
  const float* gru_bih = (const float*)d_in[5];
  const float* gru_bhh = (const float*)d_in[6];
  const float* pp_ln_g = (const float*)d_in[7];
  const float* pp_ln_b = (const float*)d_in[8];
  const float* sum_w   = (const float*)d_in[9];
  const float* sum_b   = (const float*)d_in[10];
  const float* msg_w1  = (const float*)d_in[11];
  const float* msg_b1  = (const float*)d_in[12];
  const float* msg_w2  = (const float*)d_in[13];
  const float* msg_b2  = (const float*)d_in[14];
  const float* upd_w1  = (const float*)d_in[15];
  const float* upd_b1  = (const float*)d_in[16];
  const float* upd_w2  = (const float*)d_in[17];
  const float* upd_b2  = (const float*)d_in[18];
  const float* halt_w  = (const float*)d_in[19];
  const float* halt_b  = (const float*)d_in[20];
  const float* mp_ln_g = (const float*)d_in[21];
  const float* mp_ln_b = (const float*)d_in[22];
  const float* q_w     = (const float*)d_in[23];
  const float* q_b     = (const float*)d_in[24];
  const float* k_w     = (const float*)d_in[25];
  const float* k_b     = (const float*)d_in[26];
  const float* v_w     = (const float*)d_in[27];
  const float* v_b     = (const float*)d_in[28];
  const float* o_w     = (const float*)d_in[29];
  const float* o_b     = (const float*)d_in[30];
  const float* br_w    = (const float*)d_in[31];
  const float* br_b    = (const float*)d_in[32];
  const float* f_ln_g  = (const float*)d_in[33];
  const float* f_ln_b  = (const float*)d_in[34];
  const float* head_w  = (const float*)d_in[35];

  // ---- workspace ----
  constexpr size_t SZ_Q = (size_t)BN_ * 256;
  float* ws     = (float*)d_ws;
  float* R_h    = ws;                  // broad bf16 lives here late
  float* R_outp = R_h    + SZ_Q;
  float* R_b1   = R_outp + SZ_Q;       // gh lo / hsn bf16 / sc bf16 / Abuf
  float* R_b2   = R_b1   + SZ_Q;       // gh hi / U bf16 / sc hi
  float* R_b3   = R_b2   + SZ_Q;       // S' bf16 + h bf16 / qkv lo
  float* R_rp   = R_b3   + SZ_Q;       // qkv hi + rpre bf16
  unsigned short* R_loc = (unsigned short*)(R_rp + SZ_Q);   // local bf16 (4*SZ_Q shorts)
  unsigned short* wb = R_loc + 4 * SZ_Q;
  unsigned short* sumT  = wb;                  // [256][256]
  unsigned short* W1cT  = sumT  + 65536;       // [512][256]
  unsigned short* u1cT  = W1cT  + 131072;      // [256][512] = [U1a | Wc]
  unsigned short* u2T   = u1cT  + 131072;      // [256][256]
  unsigned short* qkvT  = u2T   + 65536;       // [768][256]
  unsigned short* brWT  = qkvT  + 196608;      // [256][512] = [brW | WobT]
  unsigned short* headT = brWT  + 131072;      // [256][256]
  unsigned short* whhT  = headT + 65536;       // [768][256]
  float* R_embW = (float*)(whhT + 196608);     // [320][768]
  float* R_bU   = R_embW + 320 * 768;
  float* R_bH   = R_bU + 256;
  float* R_bB2  = R_bH + 512;
  float* R_bQKV = R_bB2 + 256;
  float* R_part = R_bQKV + 768;
  float* R_hp   = R_part + 512;

  // bf16 h (GRU recurrence + msg phase): upper half of b3
  unsigned short* R_hb = ((unsigned short*)R_b3) + SZ_Q;

  float* logits = (float*)d_out;
  dim3 blk(256);

  // ---- weight prep ----
  PrepJobs pj;
  const float* srcs[11] = {sum_w, msg_w1, msg_w1 + 65536, upd_w1, upd_w2,
                           q_w, k_w, v_w, br_w, head_w, gru_whh};
  unsigned short* dsts[11] = {sumT, W1cT, W1cT + 65536, u1cT, u2T,
                              qkvT, qkvT + 65536, qkvT + 131072, brWT, headT, whhT};
  int rows[11] = {256,256,256,256,256,256,256,256,256,256,768};
  int dstd[11] = {256,256,256,512,256,256,256,256,512,256,256};
  int strt[11] = {0,0,0,0,0,0,0,0,0,0,1};
  for (int i = 0; i < 11; ++i) {
    pj.src[i]=srcs[i]; pj.dst[i]=dsts[i]; pj.rows[i]=rows[i];
    pj.dstride[i]=dstd[i]; pj.strt[i]=strt[i];
  }
  prep_w_k<<<dim3(64, 11), blk, 0, stream>>>(pj);
  biasprep_k<<<dim3(1), blk, 0, stream>>>(upd_b1, msg_b2, upd_w1, msg_b1,
                                          o_b, br_w, br_b, q_b, k_b, v_b,
                                          R_bU, R_bH, R_bB2, R_bQKV);
  // Wc^T = (msg_w2 @ U1b)^T -> u1cT cols 256..511
  gemm_mfma<8, 1, 0, 1><<<dim3(4, 4), blk, 0, stream>>>(
      nullptr, msg_w2, nullptr, u1cT + 256, 256, 256, 256, 256, 512,
      upd_w1 + 65536, nullptr, nullptr);
  // Wob^T = (o_w @ br_w)^T -> brWT cols 256..511
  gemm_mfma<8, 1, 0, 1><<<dim3(4, 4), blk, 0, stream>>>(
      nullptr, o_w, nullptr, brWT + 256, 256, 256, 256, 256, 512,
      br_w, nullptr, nullptr);
  // embW = [emb; pos] @ wih^T  (nby=5: identity mapping path)
  gemm_mfma<6, 1, 0, 0><<<dim3(12, 5), blk, 0, stream>>>(
      nullptr, gru_wih, nullptr, R_embW, 320, 768, 256, 256, 768,
      nullptr, emb, pos);

  // ---- patch GRU (h bf16 recurrence; pp-LN fused into local store) ----
  unsigned short* ghB = (unsigned short*)R_b1;
  gru_pw_k<1><<<dim3(BN_ / 4), blk, 0, stream>>>(
      nullptr, gru_bhh, R_embW, x, gru_bih, pp_ln_g, pp_ln_b, R_hb, R_loc, 0);
  for (int t = 1; t < 4; ++t) {
    gemm_big<1, 0, 1><<<dim3(6, 128), blk, 0, stream>>>(
        R_hb, whhT, gru_bhh, ghB, BN_, 768, 256, 256, 768);
    gru_pw_k<0><<<dim3(BN_ / 4), blk, 0, stream>>>(
        ghB, gru_bhh, R_embW, x, gru_bih, pp_ln_g, pp_ln_b, R_hb, R_loc, t);
  }

  // summaries -> h (bf16)
  gemm_mfma<9, 0, 0, 1><<<dim3(4, 256), blk, 0, stream>>>(
      (const float*)R_loc, sumT, sum_b, R_hb, BN_, 256, 256, 256, 256,
      nullptr, nullptr, nullptr);

  // ---- message-passing rounds ----
  unsigned short* hsnB = (unsigned short*)R_b1;
  unsigned short* UB   = (unsigned short*)R_b2;
  unsigned short* Sb   = (unsigned short*)R_b3;
  for (int step = 0; step < 4; ++step) {
    gemm_big<1, 0, 1><<<dim3(4, 128), blk, 0, stream>>>(
        R_hb, W1cT, R_bH, hsnB, BN_, 512, 256, 256, 512);
    smsg_k<<<dim3(BN_ / 4), blk, 0, stream>>>(hsnB, Sb);
    gemm_mfma<10, 0, 1, 1><<<dim3(4, 256), blk, 0, stream>>>(
        (const float*)R_hb, u1cT, R_bU, UB, BN_, 256, 512, 512, 256,
        (const float*)Sb, nullptr, nullptr);
    if (step == 3) {
      gemm_ln<3><<<dim3(BN_ / 16), blk, 0, stream>>>(
          UB, u2T, upd_b2, R_hb, mp_ln_g, mp_ln_b, R_hp, R_outp);
    } else {
      gemm_ln<0><<<dim3(BN_ / 16), blk, 0, stream>>>(
          UB, u2T, upd_b2, R_hb, mp_ln_g, mp_ln_b, nullptr, nullptr);
      if (step == 2) {
        halt1_k<<<dim3(32, 16), blk, 0, stream>>>(R_hb, halt_w, R_part);
        halt2_k<<<dim3(1), dim3(64), 0, stream>>>(R_part, halt_b, R_hp);
        out2_k<<<dim3(BN_ / 4), blk, 0, stream>>>(R_hb, R_hp, R_outp);
      }
    }
  }

  // ---- sparse retrieval attention ----
  unsigned short* qkv  = (unsigned short*)R_b3;           // [BN][768] bf16 (h dead)
  unsigned short* rpre = ((unsigned short*)R_rp) + SZ_Q;  // [BN][256] bf16
  unsigned short* sc   = (unsigned short*)R_b1;           // 32x512x512 bf16
  gemm_big<0, 0, 1><<<dim3(6, 128), blk, 0, stream>>>(
      R_outp, qkvT, R_bQKV, qkv, BN_, 768, 256, 256, 768);
  scores_tri<<<dim3(1152), blk, 0, stream>>>(qkv, sc);
  topk_k<<<dim3(BN_ / 4), blk, 0, stream>>>(sc, qkv, rpre);

  // broad = [outp | rpre] @ brWT^T + biasB2  -> bf16 in R_h region
  unsigned short* broadB = (unsigned short*)R_h;
  gemm_mfma<11, 0, 0, 1><<<dim3(4, 256), blk, 0, stream>>>(
      R_outp, brWT, R_bB2, broadB, BN_, 256, 512, 512, 256,
      (const float*)rpre, nullptr, nullptr);

  // final LN + convert -> Abuf (in b1, sc dead), head GEMM (128-tile) -> logits
  unsigned short* Abuf = (unsigned short*)R_b1;
  ln_cvt_k<<<dim3(M1_ / 4), blk, 0, stream>>>(R_loc, broadB, f_ln_g, f_ln_b, Abuf);
  gemm_big<1, 0, 0><<<dim3(2, 512), blk, 0, stream>>>(
      Abuf, headT, nullptr, logits, M1_, 256, 256, 256, 256);

  kl_k<<<dim3(1), dim3(64), 0, stream>>>(R_hp, logits + (size_t)M1_ * 256);
}

// Round 19
// 548.387 us; speedup vs baseline: 1.1676x; 1.0221x over previous
//
#include <hip/hip_runtime.h>
#include <cmath>

// ---------------------------------------------------------------------------
// SutraV04 round 18 = round 17 (560 us, best) + outp stored bf16 end-to-end:
// out2_k write, gemm_ln<3> RMW, qkv A-read (AMODE 1), broad A-read (MODE 10).
// Saves ~42 MB HBM; only new rounding is the hp*h partial (O(1) values).
// ---------------------------------------------------------------------------

constexpr int N_   = 512;
constexpr int B_   = 32;
constexpr int BN_  = B_ * N_;   // 16384
constexpr int M1_  = BN_ * 4;   // 65536

typedef short bf16x8 __attribute__((ext_vector_type(8)));
typedef float f32x4  __attribute__((ext_vector_type(4)));

__device__ __forceinline__ float gelu_f(float x) {
  return 0.5f * x * (1.0f + erff(x * 0.70710678118654752440f));
}
__device__ __forceinline__ float sigm_f(float x) {
  return 1.0f / (1.0f + expf(-x));
}
__device__ __forceinline__ unsigned short f2bf(float f) {
  union { float f; unsigned int u; } c; c.f = f;
  unsigned int u = c.u;
  u += 0x7FFFu + ((u >> 16) & 1u);
  return (unsigned short)(u >> 16);
}
__device__ __forceinline__ float bf2f(unsigned short u) {
  union { unsigned int u; float f; } c; c.u = ((unsigned int)u) << 16;
  return c.f;
}
__device__ __forceinline__ int phys(int g, int r) {      // 64-row tiles
  return ((g << 6) | (r ^ g)) << 3;
}
__device__ __forceinline__ int phys128(int g, int r) {   // 128-row tiles
  return ((g << 7) | (r ^ g)) << 3;
}
__device__ __forceinline__ int phys16(int g, int r) {    // 16-row tiles
  return ((g << 4) | (r ^ g)) << 3;
}

// XCD-aware block remap: same-A-panel blocks (all nB of a chunk of mB) land
// on one XCD (flat % 8). Bijective; falls back to identity if nby % 8 != 0.
__device__ __forceinline__ void xcd_map(int& mB, int& nB) {
  int nbx = gridDim.x, nby = gridDim.y;
  if ((nby & 7) == 0) {
    int flat = blockIdx.y * nbx + blockIdx.x;
    int chunk = nby >> 3;
    int xcd = flat & 7, s2 = flat >> 3;
    int q = s2 / nbx;
    mB = xcd * chunk + q;
    nB = s2 - q * nbx;
  } else {
    mB = blockIdx.y; nB = blockIdx.x;
  }
}

// ---- 128x128-tile MFMA GEMM ----------------------------------------------
// AMODE: 0 f32 [m][K]; 1 bf16 [m][K].  EPI: 0 none, 1 gelu. COUT: 0 f32, 1 bf16.
template<int AMODE, int EPI, int COUT>
__global__ __launch_bounds__(256)
void gemm_big(const void* __restrict__ A, const unsigned short* __restrict__ Bt,
              const float* __restrict__ bias, void* __restrict__ C,
              int M, int Nn, int K, int bstride, int ldC)
{
  __shared__ short As[4 * 128 * 8];
  __shared__ short Bs[4 * 128 * 8];
  const int t  = threadIdx.x;
  int mB, nB;
  xcd_map(mB, nB);
  const int m0 = mB * 128, n0 = nB * 128;
  const int lane = t & 63, w = t >> 6;
  const int wr = w >> 1, wc = w & 1;
  const int fr = lane & 15, fg = lane >> 4;

  f32x4 acc[4][4] = {};

  for (int k0 = 0; k0 < K; k0 += 32) {
    #pragma unroll
    for (int c = 0; c < 2; ++c) {
      int idx = t + c * 256;
      int row = idx >> 2, g = idx & 3;
      int kk = k0 + g * 8;
      bf16x8 av;
      if constexpr (AMODE == 1) {
        av = *(const bf16x8*)&((const unsigned short*)A)[(size_t)(m0 + row) * K + kk];
      } else {
        const float4* p = (const float4*)&((const float*)A)[(size_t)(m0 + row) * K + kk];
        float4 a = p[0], b = p[1];
        av[0]=(short)f2bf(a.x); av[1]=(short)f2bf(a.y); av[2]=(short)f2bf(a.z); av[3]=(short)f2bf(a.w);
        av[4]=(short)f2bf(b.x); av[5]=(short)f2bf(b.y); av[6]=(short)f2bf(b.z); av[7]=(short)f2bf(b.w);
      }
      *(bf16x8*)&As[phys128(g, row)] = av;
      *(bf16x8*)&Bs[phys128(g, row)] =
          *(const bf16x8*)&Bt[(size_t)(n0 + row) * bstride + kk];
    }
    __syncthreads();

    bf16x8 a[4], b[4];
    #pragma unroll
    for (int i = 0; i < 4; ++i)
      a[i] = *(const bf16x8*)&As[phys128(fg, wr * 64 + i * 16 + fr)];
    #pragma unroll
    for (int j = 0; j < 4; ++j)
      b[j] = *(const bf16x8*)&Bs[phys128(fg, wc * 64 + j * 16 + fr)];
    #pragma unroll
    for (int i = 0; i < 4; ++i)
      #pragma unroll
      for (int j = 0; j < 4; ++j)
        acc[i][j] = __builtin_amdgcn_mfma_f32_16x16x32_bf16(a[i], b[j], acc[i][j], 0, 0, 0);
    __syncthreads();
  }

  #pragma unroll
  for (int i = 0; i < 4; ++i)
    #pragma unroll
    for (int j = 0; j < 4; ++j) {
      int col = n0 + wc * 64 + j * 16 + fr;
      float bcol = bias ? bias[col] : 0.0f;
      #pragma unroll
      for (int r = 0; r < 4; ++r) {
        int row = m0 + wr * 64 + i * 16 + fg * 4 + r;
        float vv = acc[i][j][r] + bcol;
        if constexpr (EPI == 1) vv = gelu_f(vv);
        if constexpr (COUT == 0)
          ((float*)C)[(size_t)row * ldC + col] = vv;
        else
          ((unsigned short*)C)[(size_t)row * ldC + col] = f2bf(vv);
      }
    }
}

// ---- 64-tile gather GEMM --------------------------------------------------
// MODE: 6 emb/pos rows; 8 transposed f32 gather P2[k*256+m]; 9 bf16 patch-mean;
//       10 concat(bf16 A | bf16 P2); 11 concat(f32 A | bf16 P2)
// BSRC: 0 bf16 Bt; 1 fp32.  EPI: 0 none, 1 gelu.  COUT: 0 f32, 1 bf16.
template<int MODE, int BSRC, int EPI, int COUT>
__global__ __launch_bounds__(256)
void gemm_mfma(const float* __restrict__ A, const void* __restrict__ Bsrc,
               const float* __restrict__ bias, void* __restrict__ C,
               int M, int Nn, int K, int bstride, int ldC,
               const float* __restrict__ P2,
               const float* __restrict__ emb, const float* __restrict__ pos)
{
  __shared__ short As[4 * 64 * 8];
  __shared__ short Bs[4 * 64 * 8];
  const int tid  = threadIdx.x;
  int mB, nB;
  xcd_map(mB, nB);
  const int m0 = mB * 64, n0 = nB * 64;
  const int srow = tid >> 2, sg = tid & 3;
  const int lane = tid & 63, w = tid >> 6;
  const int wr   = w >> 1,  wc = w & 1;
  const int fr   = lane & 15, fg = lane >> 4;

  f32x4 acc[2][2] = {};

  for (int k0 = 0; k0 < K; k0 += 32) {
    {
      int m = m0 + srow, k = k0 + sg * 8;
      bf16x8 tv;
      if constexpr (MODE == 10) {
        if (k < 256)
          tv = *(const bf16x8*)&((const unsigned short*)A)[(size_t)m * 256 + k];
        else
          tv = *(const bf16x8*)&((const unsigned short*)P2)[(size_t)m * 256 + (k - 256)];
      } else if constexpr (MODE == 11) {
        if (k < 256) {
          const float4* p = (const float4*)(A + (size_t)m * 256 + k);
          float4 a = p[0], b = p[1];
          tv[0]=(short)f2bf(a.x); tv[1]=(short)f2bf(a.y); tv[2]=(short)f2bf(a.z); tv[3]=(short)f2bf(a.w);
          tv[4]=(short)f2bf(b.x); tv[5]=(short)f2bf(b.y); tv[6]=(short)f2bf(b.z); tv[7]=(short)f2bf(b.w);
        } else {
          tv = *(const bf16x8*)&((const unsigned short*)P2)[(size_t)m * 256 + (k - 256)];
        }
      } else {
        float v[8];
        if constexpr (MODE == 6) {
          const float* src = nullptr;
          if (m < 256) src = emb + (size_t)m * 256 + k;
          else if (m < 260) src = pos + (size_t)(m - 256) * 256 + k;
          if (src) {
            const float4* p = (const float4*)src;
            float4 a = p[0], b = p[1];
            v[0]=a.x; v[1]=a.y; v[2]=a.z; v[3]=a.w; v[4]=b.x; v[5]=b.y; v[6]=b.z; v[7]=b.w;
          } else {
            #pragma unroll
            for (int j = 0; j < 8; ++j) v[j] = 0.f;
          }
        } else if constexpr (MODE == 8) {
          #pragma unroll
          for (int j = 0; j < 8; ++j) v[j] = P2[(size_t)(k + j) * 256 + m];
        } else { // 9
          const unsigned short* Ab = (const unsigned short*)A;
          const unsigned short* base = Ab + (size_t)m * 1024 + k;
          bf16x8 r0 = *(const bf16x8*)(base);
          bf16x8 r1 = *(const bf16x8*)(base + 256);
          bf16x8 r2 = *(const bf16x8*)(base + 512);
          bf16x8 r3 = *(const bf16x8*)(base + 768);
          #pragma unroll
          for (int j = 0; j < 8; ++j)
            v[j] = 0.25f * (bf2f((unsigned short)r0[j]) + bf2f((unsigned short)r1[j]) +
                            bf2f((unsigned short)r2[j]) + bf2f((unsigned short)r3[j]));
        }
        #pragma unroll
        for (int j = 0; j < 8; ++j) tv[j] = (short)f2bf(v[j]);
      }
      *(bf16x8*)&As[phys(sg, srow)] = tv;
    }
    if constexpr (BSRC == 0) {
      const unsigned short* Bt = (const unsigned short*)Bsrc;
      *(bf16x8*)&Bs[phys(sg, srow)] =
          *(const bf16x8*)&Bt[(size_t)(n0 + srow) * bstride + k0 + sg * 8];
    } else {
      const float* Bf = (const float*)Bsrc;
      const float4* p = (const float4*)(Bf + (size_t)(n0 + srow) * bstride + k0 + sg * 8);
      float4 a = p[0], b = p[1];
      bf16x8 tv;
      tv[0]=(short)f2bf(a.x); tv[1]=(short)f2bf(a.y); tv[2]=(short)f2bf(a.z); tv[3]=(short)f2bf(a.w);
      tv[4]=(short)f2bf(b.x); tv[5]=(short)f2bf(b.y); tv[6]=(short)f2bf(b.z); tv[7]=(short)f2bf(b.w);
      *(bf16x8*)&Bs[phys(sg, srow)] = tv;
    }
    __syncthreads();

    bf16x8 a0 = *(const bf16x8*)&As[phys(fg, wr * 32 + fr)];
    bf16x8 a1 = *(const bf16x8*)&As[phys(fg, wr * 32 + 16 + fr)];
    bf16x8 b0 = *(const bf16x8*)&Bs[phys(fg, wc * 32 + fr)];
    bf16x8 b1 = *(const bf16x8*)&Bs[phys(fg, wc * 32 + 16 + fr)];
    acc[0][0] = __builtin_amdgcn_mfma_f32_16x16x32_bf16(a0, b0, acc[0][0], 0, 0, 0);
    acc[0][1] = __builtin_amdgcn_mfma_f32_16x16x32_bf16(a0, b1, acc[0][1], 0, 0, 0);
    acc[1][0] = __builtin_amdgcn_mfma_f32_16x16x32_bf16(a1, b0, acc[1][0], 0, 0, 0);
    acc[1][1] = __builtin_amdgcn_mfma_f32_16x16x32_bf16(a1, b1, acc[1][1], 0, 0, 0);
    __syncthreads();
  }

  #pragma unroll
  for (int i = 0; i < 2; ++i) {
    #pragma unroll
    for (int j = 0; j < 2; ++j) {
      int row0 = m0 + wr * 32 + i * 16 + fg * 4;
      int col  = n0 + wc * 32 + j * 16 + fr;
      float bcol = bias ? bias[col] : 0.0f;
      #pragma unroll
      for (int r = 0; r < 4; ++r) {
        float vv = acc[i][j][r] + bcol;
        if constexpr (EPI == 1) vv = gelu_f(vv);
        int row = row0 + r;
        if constexpr (COUT == 0)
          ((float*)C)[(size_t)row * ldC + col] = vv;
        else
          ((unsigned short*)C)[(size_t)row * ldC + col] = f2bf(vv);
      }
    }
  }
}

// ---- fused upd-GEMM + residual + LN; 16-row full-width tile ---------------
// OUTM==3: outp (bf16) += (1-hp[b]) * y
template<int OUTM>
__global__ __launch_bounds__(256)
void gemm_ln(const unsigned short* __restrict__ U, const unsigned short* __restrict__ u2T,
             const float* __restrict__ bias, unsigned short* __restrict__ h,
             const float* __restrict__ g, const float* __restrict__ bb,
             const float* __restrict__ hp, unsigned short* __restrict__ outp)
{
  __shared__ short As[4 * 16 * 8];
  __shared__ short Bs[4 * 256 * 8];
  __shared__ float psum[4][16], pssq[4][16];
  const int m0 = blockIdx.x * 16;
  const int t  = threadIdx.x;
  const int lane = t & 63, w = t >> 6;
  const int fr = lane & 15, fg = lane >> 4;

  f32x4 acc[4] = {};
  for (int k0 = 0; k0 < 256; k0 += 32) {
    if (t < 64) {
      int row = t >> 2, gq = t & 3;
      *(bf16x8*)&As[phys16(gq, row)] =
          *(const bf16x8*)&U[(size_t)(m0 + row) * 256 + k0 + gq * 8];
    }
    const unsigned short* brow = u2T + (size_t)t * 256 + k0;
    #pragma unroll
    for (int gq = 0; gq < 4; ++gq)
      *(bf16x8*)&Bs[((gq << 8) | (t ^ gq)) << 3] = *(const bf16x8*)(brow + gq * 8);
    __syncthreads();
    bf16x8 a = *(const bf16x8*)&As[phys16(fg, fr)];
    #pragma unroll
    for (int j = 0; j < 4; ++j) {
      int n = 64 * w + 16 * j + fr;
      bf16x8 b = *(const bf16x8*)&Bs[((fg << 8) | (n ^ fg)) << 3];
      acc[j] = __builtin_amdgcn_mfma_f32_16x16x32_bf16(a, b, acc[j], 0, 0, 0);
    }
    __syncthreads();
  }

  float bcol[4], gv[4], bv[4];
  #pragma unroll
  for (int j = 0; j < 4; ++j) {
    int col = 64 * w + 16 * j + fr;
    bcol[j] = bias[col]; gv[j] = g[col]; bv[j] = bb[col];
  }
  float vsum[4] = {}, vssq[4] = {};
  #pragma unroll
  for (int j = 0; j < 4; ++j) {
    int col = 64 * w + 16 * j + fr;
    #pragma unroll
    for (int r = 0; r < 4; ++r) {
      int row = m0 + 4 * fg + r;
      float v = acc[j][r] + bcol[j] + bf2f(h[(size_t)row * 256 + col]);
      acc[j][r] = v;
      vsum[r] += v;
      vssq[r] += v * v;
    }
  }
  #pragma unroll
  for (int off = 1; off < 16; off <<= 1) {
    #pragma unroll
    for (int r = 0; r < 4; ++r) {
      vsum[r] += __shfl_xor(vsum[r], off, 64);
      vssq[r] += __shfl_xor(vssq[r], off, 64);
    }
  }
  if (fr == 0) {
    #pragma unroll
    for (int r = 0; r < 4; ++r) {
      psum[w][4 * fg + r] = vsum[r];
      pssq[w][4 * fg + r] = vssq[r];
    }
  }
  __syncthreads();

  float rem = 0.f;
  if constexpr (OUTM == 3) rem = 1.0f - hp[m0 >> 9];
  #pragma unroll
  for (int r = 0; r < 4; ++r) {
    int rr = 4 * fg + r;
    float s  = psum[0][rr] + psum[1][rr] + psum[2][rr] + psum[3][rr];
    float q2 = pssq[0][rr] + pssq[1][rr] + pssq[2][rr] + pssq[3][rr];
    float mean = s * (1.0f / 256.0f);
    float var  = q2 * (1.0f / 256.0f) - mean * mean;
    float inv  = rsqrtf(var + 1e-5f);
    int row = m0 + rr;
    #pragma unroll
    for (int j = 0; j < 4; ++j) {
      int col = 64 * w + 16 * j + fr;
      float y = (acc[j][r] - mean) * inv * gv[j] + bv[j];
      h[(size_t)row * 256 + col] = f2bf(y);
      if constexpr (OUTM == 3) {
        size_t oi = (size_t)row * 256 + col;
        outp[oi] = f2bf(bf2f(outp[oi]) + rem * y);
      }
    }
  }
}

// ---- causal tri-tile scores (bf16 out), XCD-swizzled ----------------------
__global__ __launch_bounds__(256)
void scores_tri(const unsigned short* __restrict__ qkv, unsigned short* __restrict__ sc)
{
  int flat = blockIdx.x;
  int xcd = flat & 7, s = flat >> 3;
  int bhi = s / 36, tile = s - bhi * 36;
  int b = bhi * 8 + xcd;
  int ti = 0;
  while ((ti + 1) * (ti + 2) / 2 <= tile) ++ti;
  int tj = tile - ti * (ti + 1) / 2;
  const int m0 = ti * 64, n0 = tj * 64;
  const unsigned short* Aq = qkv + (size_t)b * N_ * 768;
  const unsigned short* Bk = Aq + 256;

  __shared__ short As[4 * 64 * 8];
  __shared__ short Bs[4 * 64 * 8];
  const int tid  = threadIdx.x;
  const int srow = tid >> 2, sg = tid & 3;
  const int lane = tid & 63, w = tid >> 6;
  const int wr   = w >> 1,  wc = w & 1;
  const int fr   = lane & 15, fg = lane >> 4;

  f32x4 acc[2][2] = {};
  for (int k0 = 0; k0 < 256; k0 += 32) {
    *(bf16x8*)&As[phys(sg, srow)] =
        *(const bf16x8*)&Aq[(size_t)(m0 + srow) * 768 + k0 + sg * 8];
    *(bf16x8*)&Bs[phys(sg, srow)] =
        *(const bf16x8*)&Bk[(size_t)(n0 + srow) * 768 + k0 + sg * 8];
    __syncthreads();
    bf16x8 a0 = *(const bf16x8*)&As[phys(fg, wr * 32 + fr)];
    bf16x8 a1 = *(const bf16x8*)&As[phys(fg, wr * 32 + 16 + fr)];
    bf16x8 b0 = *(const bf16x8*)&Bs[phys(fg, wc * 32 + fr)];
    bf16x8 b1 = *(const bf16x8*)&Bs[phys(fg, wc * 32 + 16 + fr)];
    acc[0][0] = __builtin_amdgcn_mfma_f32_16x16x32_bf16(a0, b0, acc[0][0], 0, 0, 0);
    acc[0][1] = __builtin_amdgcn_mfma_f32_16x16x32_bf16(a0, b1, acc[0][1], 0, 0, 0);
    acc[1][0] = __builtin_amdgcn_mfma_f32_16x16x32_bf16(a1, b0, acc[1][0], 0, 0, 0);
    acc[1][1] = __builtin_amdgcn_mfma_f32_16x16x32_bf16(a1, b1, acc[1][1], 0, 0, 0);
    __syncthreads();
  }
  unsigned short* scb = sc + (size_t)b * N_ * N_;
  #pragma unroll
  for (int i = 0; i < 2; ++i) {
    #pragma unroll
    for (int j = 0; j < 2; ++j) {
      int row0 = m0 + wr * 32 + i * 16 + fg * 4;
      int col  = n0 + wc * 32 + j * 16 + fr;
      #pragma unroll
      for (int r = 0; r < 4; ++r) {
        int row = row0 + r;
        float vv = acc[i][j][r] * 0.0625f;
        if (col > row) vv = -__builtin_inff();
        scb[(size_t)row * N_ + col] = f2bf(vv);
      }
    }
  }
}

// ---- weight prep ----------------------------------------------------------
struct PrepJobs {
  const float* src[12];
  unsigned short* dst[12];
  int rows[12];
  int dstride[12];
  int strt[12];
};
__global__ __launch_bounds__(256)
void prep_w_k(PrepJobs pj)
{
  int jid = blockIdx.y;
  const float* src = pj.src[jid];
  unsigned short* dst = pj.dst[jid];
  int ds = pj.dstride[jid];
  int total = pj.rows[jid] << 8;
  if (pj.strt[jid]) {
    for (int i = blockIdx.x * 256 + threadIdx.x; i < total; i += gridDim.x * 256) {
      int k = i & 255, n = i >> 8;
      dst[(size_t)n * ds + k] = f2bf(src[i]);
    }
  } else {
    for (int i = blockIdx.x * 256 + threadIdx.x; i < total; i += gridDim.x * 256) {
      int k = i & 255, n = i >> 8;
      dst[(size_t)n * ds + k] = f2bf(src[(size_t)k * 256 + n]);
    }
  }
}

// ---- bias prep ------------------------------------------------------------
__global__ __launch_bounds__(256)
void biasprep_k(const float* __restrict__ upd_b1, const float* __restrict__ msg_b2,
                const float* __restrict__ upd_w1, const float* __restrict__ msg_b1,
                const float* __restrict__ o_b, const float* __restrict__ br_w,
                const float* __restrict__ br_b, const float* __restrict__ q_b,
                const float* __restrict__ k_b, const float* __restrict__ v_b,
                float* __restrict__ biasU, float* __restrict__ biasHsn,
                float* __restrict__ biasB2, float* __restrict__ bQKV)
{
  int c = threadIdx.x;
  float s = upd_b1[c];
  for (int k = 0; k < 256; ++k)
    s += msg_b2[k] * upd_w1[(size_t)(256 + k) * 256 + c];
  biasU[c] = s;
  biasHsn[c] = msg_b1[c];
  biasHsn[256 + c] = 0.f;
  float s2 = br_b[c];
  for (int k = 0; k < 256; ++k)
    s2 += o_b[k] * br_w[(size_t)k * 256 + c];
  biasB2[c] = s2;
  bQKV[c] = q_b[c]; bQKV[256 + c] = k_b[c]; bQKV[512 + c] = v_b[c];
}

// ---- GRU pointwise + fused pp-LN (one wave per local row) -----------------
template<int FIRST>
__global__ __launch_bounds__(256)
void gru_pw_k(const unsigned short* __restrict__ gh, const float* __restrict__ bhh,
              const float* __restrict__ embW, const int* __restrict__ x,
              const float* __restrict__ bih,
              const float* __restrict__ lng, const float* __restrict__ lnb,
              unsigned short* __restrict__ h, unsigned short* __restrict__ local, int t)
{
  int i   = blockIdx.x * 256 + threadIdx.x;   // over BN*64 groups
  int row = i >> 6, d0 = (i & 63) << 2;
  int tok = x[row * 4 + t];
  const float* er = embW + (size_t)tok * 768;
  const float* pr = embW + (size_t)(256 + t) * 768;
  float4 e0 = *(const float4*)(er + d0);
  float4 e1 = *(const float4*)(er + 256 + d0);
  float4 e2 = *(const float4*)(er + 512 + d0);
  float4 p0 = *(const float4*)(pr + d0);
  float4 p1 = *(const float4*)(pr + 256 + d0);
  float4 p2 = *(const float4*)(pr + 512 + d0);
  float4 q0 = *(const float4*)(bih + d0);
  float4 q1 = *(const float4*)(bih + 256 + d0);
  float4 q2 = *(const float4*)(bih + 512 + d0);
  float ir[4]  = {e0.x+p0.x+q0.x, e0.y+p0.y+q0.y, e0.z+p0.z+q0.z, e0.w+p0.w+q0.w};
  float iz[4]  = {e1.x+p1.x+q1.x, e1.y+p1.y+q1.y, e1.z+p1.z+q1.z, e1.w+p1.w+q1.w};
  float inn[4] = {e2.x+p2.x+q2.x, e2.y+p2.y+q2.y, e2.z+p2.z+q2.z, e2.w+p2.w+q2.w};
  float hr[4], hz[4], hn[4];
  if constexpr (FIRST) {
    float4 b0 = *(const float4*)(bhh + d0);
    float4 b1 = *(const float4*)(bhh + 256 + d0);
    float4 b2 = *(const float4*)(bhh + 512 + d0);
    hr[0]=b0.x; hr[1]=b0.y; hr[2]=b0.z; hr[3]=b0.w;
    hz[0]=b1.x; hz[1]=b1.y; hz[2]=b1.z; hz[3]=b1.w;
    hn[0]=b2.x; hn[1]=b2.y; hn[2]=b2.z; hn[3]=b2.w;
  } else {
    const unsigned short* gr = gh + (size_t)row * 768;
    ushort4 u0 = *(const ushort4*)(gr + d0);
    ushort4 u1 = *(const ushort4*)(gr + 256 + d0);
    ushort4 u2 = *(const ushort4*)(gr + 512 + d0);
    hr[0]=bf2f(u0.x); hr[1]=bf2f(u0.y); hr[2]=bf2f(u0.z); hr[3]=bf2f(u0.w);
    hz[0]=bf2f(u1.x); hz[1]=bf2f(u1.y); hz[2]=bf2f(u1.z); hz[3]=bf2f(u1.w);
    hn[0]=bf2f(u2.x); hn[1]=bf2f(u2.y); hn[2]=bf2f(u2.z); hn[3]=bf2f(u2.w);
  }
  ushort4 hprev = {0, 0, 0, 0};
  if constexpr (!FIRST) hprev = *(const ushort4*)&h[(size_t)row * 256 + d0];
  float hp4[4] = {bf2f(hprev.x), bf2f(hprev.y), bf2f(hprev.z), bf2f(hprev.w)};
  float hv[4];
  ushort4 oh;
  #pragma unroll
  for (int e = 0; e < 4; ++e) {
    float r  = sigm_f(ir[e] + hr[e]);
    float zg = sigm_f(iz[e] + hz[e]);
    float nn = tanhf(inn[e] + r * hn[e]);
    float hnew;
    if constexpr (FIRST) hnew = (1.0f - zg) * nn;
    else                 hnew = (1.0f - zg) * nn + zg * hp4[e];
    hv[e] = hnew;
    ((unsigned short*)&oh)[e] = f2bf(hnew);
  }
  *(ushort4*)&h[(size_t)row * 256 + d0] = oh;

  // fused pp-LN over this wave's row (64 lanes x 4 elems = 256)
  float s = hv[0] + hv[1] + hv[2] + hv[3];
  #pragma unroll
  for (int off = 1; off < 64; off <<= 1) s += __shfl_xor(s, off, 64);
  float mean = s * (1.0f / 256.0f);
  float ss = 0.f;
  #pragma unroll
  for (int e = 0; e < 4; ++e) { float d = hv[e] - mean; ss += d * d; }
  #pragma unroll
  for (int off = 1; off < 64; off <<= 1) ss += __shfl_xor(ss, off, 64);
  float inv = rsqrtf(ss * (1.0f / 256.0f) + 1e-5f);
  const float4 g4 = *(const float4*)(lng + d0);
  const float4 b4 = *(const float4*)(lnb + d0);
  ushort4 ol;
  ol.x = f2bf((hv[0] - mean) * inv * g4.x + b4.x);
  ol.y = f2bf((hv[1] - mean) * inv * g4.y + b4.y);
  ol.z = f2bf((hv[2] - mean) * inv * g4.z + b4.z);
  ol.w = f2bf((hv[3] - mean) * inv * g4.w + b4.w);
  *(ushort4*)&local[((size_t)row * 4 + t) * 256 + d0] = ol;
}

// ---- S' = rowscale( sum_kk gelu(hs + shift(hn)) ) -> bf16 -----------------
__global__ __launch_bounds__(256)
void smsg_k(const unsigned short* __restrict__ hsn, unsigned short* __restrict__ S)
{
  int i = blockIdx.x * 256 + threadIdx.x;   // BN*64
  int m = i >> 6, d4 = (i & 63) << 2;
  int n = m & (N_ - 1);
  ushort4 hsu = *(const ushort4*)&hsn[(size_t)m * 512 + d4];
  float hs0 = bf2f(hsu.x), hs1 = bf2f(hsu.y), hs2 = bf2f(hsu.z), hs3 = bf2f(hsu.w);
  float a0 = 0.f, a1 = 0.f, a2 = 0.f, a3 = 0.f;
  #pragma unroll
  for (int kk = 0; kk < 5; ++kk) {
    int idx = n + kk - 4;
    if (idx >= 0) {
      ushort4 hv = *(const ushort4*)&hsn[(size_t)(m + kk - 4) * 512 + 256 + d4];
      a0 += gelu_f(hs0 + bf2f(hv.x));
      a1 += gelu_f(hs1 + bf2f(hv.y));
      a2 += gelu_f(hs2 + bf2f(hv.z));
      a3 += gelu_f(hs3 + bf2f(hv.w));
    }
  }
  float sc1 = 1.0f / (float)((n < 4 ? n : 4) + 1);
  ushort4 o = {f2bf(a0 * sc1), f2bf(a1 * sc1), f2bf(a2 * sc1), f2bf(a3 * sc1)};
  *(ushort4*)&S[(size_t)m * 256 + d4] = o;
}

// ---- final LN: local bf16 + broad bf16 -> Abuf bf16 -----------------------
__global__ __launch_bounds__(256)
void ln_cvt_k(const unsigned short* __restrict__ X, const unsigned short* __restrict__ Add,
              const float* __restrict__ g, const float* __restrict__ bb,
              unsigned short* __restrict__ Out)
{
  int wave = threadIdx.x >> 6, lane = threadIdx.x & 63;
  int row  = blockIdx.x * 4 + wave;
  ushort4 u = *(const ushort4*)&X[(size_t)row * 256 + lane * 4];
  ushort4 a = *(const ushort4*)&Add[(size_t)(row >> 2) * 256 + lane * 4];
  float x[4] = {bf2f(u.x) + bf2f(a.x), bf2f(u.y) + bf2f(a.y),
                bf2f(u.z) + bf2f(a.z), bf2f(u.w) + bf2f(a.w)};
  float s = x[0] + x[1] + x[2] + x[3];
  #pragma unroll
  for (int off = 1; off < 64; off <<= 1) s += __shfl_xor(s, off, 64);
  float mean = s * (1.0f / 256.0f);
  float ss = 0.f;
  #pragma unroll
  for (int j = 0; j < 4; ++j) { float d = x[j] - mean; ss += d * d; }
  #pragma unroll
  for (int off = 1; off < 64; off <<= 1) ss += __shfl_xor(ss, off, 64);
  float inv = rsqrtf(ss * (1.0f / 256.0f) + 1e-5f);
  ushort4 o;
  o.x = f2bf((x[0] - mean) * inv * g[lane*4+0] + bb[lane*4+0]);
  o.y = f2bf((x[1] - mean) * inv * g[lane*4+1] + bb[lane*4+1]);
  o.z = f2bf((x[2] - mean) * inv * g[lane*4+2] + bb[lane*4+2]);
  o.w = f2bf((x[3] - mean) * inv * g[lane*4+3] + bb[lane*4+3]);
  *(ushort4*)&Out[(size_t)row * 256 + lane * 4] = o;
}

// ---- halting (h bf16) ------------------------------------------------------
__global__ __launch_bounds__(256)
void halt1_k(const unsigned short* __restrict__ h, const float* __restrict__ hw,
             float* __restrict__ part)
{
  int b = blockIdx.x, s = blockIdx.y, tid = threadIdx.x;
  const unsigned short* p = h + ((size_t)b * N_ + s * 32) * 256;
  float acc = 0.f;
  for (int i = tid * 4; i < 32 * 256; i += 1024) {
    ushort4 u = *(const ushort4*)&p[i];
    const float4 w4 = *(const float4*)&hw[i & 255];
    acc += bf2f(u.x) * w4.x + bf2f(u.y) * w4.y + bf2f(u.z) * w4.z + bf2f(u.w) * w4.w;
  }
  __shared__ float red[256];
  red[tid] = acc; __syncthreads();
  for (int off = 128; off > 0; off >>= 1) {
    if (tid < off) red[tid] += red[tid + off];
    __syncthreads();
  }
  if (tid == 0) part[b * 16 + s] = red[0];
}
__global__ __launch_bounds__(64)
void halt2_k(const float* __restrict__ part, const float* __restrict__ hb,
             float* __restrict__ hp)
{
  int b = threadIdx.x;
  if (b < 32) {
    float s = 0.f;
    for (int i = 0; i < 16; ++i) s += part[b * 16 + i];
    hp[b] = sigm_f(s * (1.0f / (float)N_) + hb[0]);
  }
}
__global__ __launch_bounds__(256)
void out2_k(const unsigned short* __restrict__ h, const float* __restrict__ hp,
            unsigned short* __restrict__ outp)
{
  int i = blockIdx.x * 256 + threadIdx.x;   // groups of 4
  float hpv = hp[i >> 15];
  ushort4 u = *(const ushort4*)&h[(size_t)i * 4];
  ushort4 o;
  o.x = f2bf(hpv * bf2f(u.x));
  o.y = f2bf(hpv * bf2f(u.y));
  o.z = f2bf(hpv * bf2f(u.z));
  o.w = f2bf(hpv * bf2f(u.w));
  *(ushort4*)&outp[(size_t)i * 4] = o;
}

// ---- wave-per-row top-8 + softmax + V gather (sc bf16, qkv stride 768) ----
__global__ __launch_bounds__(256)
void topk_k(const unsigned short* __restrict__ sc, const unsigned short* __restrict__ qkv,
            unsigned short* __restrict__ rpre)
{
  const float NEG = -__builtin_inff();
  int wave = threadIdx.x >> 6, lane = threadIdx.x & 63;
  int rowg = blockIdx.x * 4 + wave;
  int b = rowg >> 9, n = rowg & (N_ - 1);
  const unsigned short* srow = sc + (size_t)rowg * N_;
  float v[8];
  #pragma unroll
  for (int j = 0; j < 8; ++j) {
    int col = lane + j * 64;
    v[j] = (col <= n) ? bf2f(srow[col]) : NEG;
  }
  float tv[8]; int ti[8];
  #pragma unroll
  for (int it = 0; it < 8; ++it) {
    float bv = v[0]; int bi = lane;
    #pragma unroll
    for (int j = 1; j < 8; ++j)
      if (v[j] > bv) { bv = v[j]; bi = lane + j * 64; }
    #pragma unroll
    for (int off = 1; off < 64; off <<= 1) {
      float ov = __shfl_xor(bv, off, 64);
      int   oi = __shfl_xor(bi, off, 64);
      if (ov > bv || (ov == bv && oi < bi)) { bv = ov; bi = oi; }
    }
    tv[it] = bv; ti[it] = bi;
    if ((bi & 63) == lane) v[bi >> 6] = NEG;
  }
  float mx = tv[0];
  float wsum = 0.f, wj[8];
  #pragma unroll
  for (int j = 0; j < 8; ++j) { wj[j] = expf(tv[j] - mx); wsum += wj[j]; }
  float inv = 1.0f / wsum;
  const unsigned short* vb = qkv + 512;
  int d0 = lane * 4;
  float a0 = 0.f, a1 = 0.f, a2 = 0.f, a3 = 0.f;
  #pragma unroll
  for (int j = 0; j < 8; ++j) {
    float wgt = wj[j] * inv;
    ushort4 vv = *(const ushort4*)&vb[((size_t)(b * N_ + ti[j])) * 768 + d0];
    a0 += wgt * bf2f(vv.x); a1 += wgt * bf2f(vv.y);
    a2 += wgt * bf2f(vv.z); a3 += wgt * bf2f(vv.w);
  }
  ushort4 o = {f2bf(a0), f2bf(a1), f2bf(a2), f2bf(a3)};
  *(ushort4*)&rpre[(size_t)rowg * 256 + d0] = o;
}

// ---- KL scalar ------------------------------------------------------------
__global__ void kl_k(const float* __restrict__ hp, float* __restrict__ out)
{
  if (threadIdx.x == 0 && blockIdx.x == 0) {
    float hm = 0.f;
    for (int b = 0; b < 32; ++b) hm += hp[b];
    hm *= (1.0f / 32.0f);
    const float l1e8 = logf(1e-8f);
    float kl = 0.f;
    kl += 0.2f    * (logf(0.2f)    - l1e8);
    kl += 0.16f   * (logf(0.16f)   - l1e8);
    kl += 0.128f  * (logf(0.128f)  - logf(hm + 1e-8f));
    kl += 0.1024f * (logf(0.1024f) - logf(1.0f + 1e-8f));
    out[0] = kl * 0.25f;
  }
}

// ---------------------------------------------------------------------------
extern "C" void kernel_launch(void* const* d_in, const int* in_sizes, int n_in,
                              void* d_out, int out_size, void* d_ws, size_t ws_size,
                              hipStream_t stream)
{
  const int*   x       = (const int*)  d_in[0];
  const float* emb     = (const float*)d_in[1];
  const float* pos     = (const float*)d_in[2];
  const float* gru_wih = (const float*)d_in[3];
  const float* gru_whh = (const float*)d_in[4];
  const float* gru_bih = (const float*)d_in[5];
  const float* gru_bhh = (const float*)d_in[6];
  const float* pp_ln_g = (const float*)d_in[7];
  const float* pp_ln_b = (const float*)d_in[8];
  const float* sum_w   = (const float*)d_in[9];
  const float* sum_b   = (const float*)d_in[10];
  const float* msg_w1  = (const float*)d_in[11];
  const float* msg_b1  = (const float*)d_in[12];
  const float* msg_w2  = (const float*)d_in[13];
  const float* msg_b2  = (const float*)d_in[14];
  const float* upd_w1  = (const float*)d_in[15];
  const float* upd_b1  = (const float*)d_in[16];
  const float* upd_w2  = (const float*)d_in[17];
  const float* upd_b2  = (const float*)d_in[18];
  const float* halt_w  = (const float*)d_in[19];
  const float* halt_b  = (const float*)d_in[20];
  const float* mp_ln_g = (const float*)d_in[21];
  const float* mp_ln_b = (const float*)d_in[22];
  const float* q_w     = (const float*)d_in[23];
  const float* q_b     = (const float*)d_in[24];
  const float* k_w     = (const float*)d_in[25];
  const float* k_b     = (const float*)d_in[26];
  const float* v_w     = (const float*)d_in[27];
  const float* v_b     = (const float*)d_in[28];
  const float* o_w     = (const float*)d_in[29];
  const float* o_b     = (const float*)d_in[30];
  const float* br_w    = (const float*)d_in[31];
  const float* br_b    = (const float*)d_in[32];
  const float* f_ln_g  = (const float*)d_in[33];
  const float* f_ln_b  = (const float*)d_in[34];
  const float* head_w  = (const float*)d_in[35];

  // ---- workspace ----
  constexpr size_t SZ_Q = (size_t)BN_ * 256;
  float* ws     = (float*)d_ws;
  float* R_h    = ws;                  // broad bf16 lives here late
  float* R_outp = R_h    + SZ_Q;       // outp bf16 (lower half)
  float* R_b1   = R_outp + SZ_Q;       // gh lo / hsn bf16 / sc bf16 / Abuf
  float* R_b2   = R_b1   + SZ_Q;       // gh hi / U bf16 / sc hi
  float* R_b3   = R_b2   + SZ_Q;       // S' bf16 + h bf16 / qkv lo
  float* R_rp   = R_b3   + SZ_Q;       // qkv hi + rpre bf16
  unsigned short* R_loc = (unsigned short*)(R_rp + SZ_Q);   // local bf16 (4*SZ_Q shorts)
  unsigned short* wb = R_loc + 4 * SZ_Q;
  unsigned short* sumT  = wb;                  // [256][256]
  unsigned short* W1cT  = sumT  + 65536;       // [512][256]
  unsigned short* u1cT  = W1cT  + 131072;      // [256][512] = [U1a | Wc]
  unsigned short* u2T   = u1cT  + 131072;      // [256][256]
  unsigned short* qkvT  = u2T   + 65536;       // [768][256]
  unsigned short* brWT  = qkvT  + 196608;      // [256][512] = [brW | WobT]
  unsigned short* headT = brWT  + 131072;      // [256][256]
  unsigned short* whhT  = headT + 65536;       // [768][256]
  float* R_embW = (float*)(whhT + 196608);     // [320][768]
  float* R_bU   = R_embW + 320 * 768;
  float* R_bH   = R_bU + 256;
  float* R_bB2  = R_bH + 512;
  float* R_bQKV = R_bB2 + 256;
  float* R_part = R_bQKV + 768;
  float* R_hp   = R_part + 512;

  // bf16 h (GRU recurrence + msg phase): upper half of b3
  unsigned short* R_hb   = ((unsigned short*)R_b3) + SZ_Q;
  // bf16 outp
  unsigned short* R_outB = (unsigned short*)R_outp;

  float* logits = (float*)d_out;
  dim3 blk(256);

  // ---- weight prep ----
  PrepJobs pj;
  const float* srcs[11] = {sum_w, msg_w1, msg_w1 + 65536, upd_w1, upd_w2,
                           q_w, k_w, v_w, br_w, head_w, gru_whh};
  unsigned short* dsts[11] = {sumT, W1cT, W1cT + 65536, u1cT, u2T,
                              qkvT, qkvT + 65536, qkvT + 131072, brWT, headT, whhT};
  int rows[11] = {256,256,256,256,256,256,256,256,256,256,768};
  int dstd[11] = {256,256,256,512,256,256,256,256,512,256,256};
  int strt[11] = {0,0,0,0,0,0,0,0,0,0,1};
  for (int i = 0; i < 11; ++i) {
    pj.src[i]=srcs[i]; pj.dst[i]=dsts[i]; pj.rows[i]=rows[i];
    pj.dstride[i]=dstd[i]; pj.strt[i]=strt[i];
  }
  prep_w_k<<<dim3(64, 11), blk, 0, stream>>>(pj);
  biasprep_k<<<dim3(1), blk, 0, stream>>>(upd_b1, msg_b2, upd_w1, msg_b1,
                                          o_b, br_w, br_b, q_b, k_b, v_b,
                                          R_bU, R_bH, R_bB2, R_bQKV);
  // Wc^T = (msg_w2 @ U1b)^T -> u1cT cols 256..511
  gemm_mfma<8, 1, 0, 1><<<dim3(4, 4), blk, 0, stream>>>(
      nullptr, msg_w2, nullptr, u1cT + 256, 256, 256, 256, 256, 512,
      upd_w1 + 65536, nullptr, nullptr);
  // Wob^T = (o_w @ br_w)^T -> brWT cols 256..511
  gemm_mfma<8, 1, 0, 1><<<dim3(4, 4), blk, 0, stream>>>(
      nullptr, o_w, nullptr, brWT + 256, 256, 256, 256, 256, 512,
      br_w, nullptr, nullptr);
  // embW = [emb; pos] @ wih^T  (nby=5: identity mapping path)
  gemm_mfma<6, 1, 0, 0><<<dim3(12, 5), blk, 0, stream>>>(
      nullptr, gru_wih, nullptr, R_embW, 320, 768, 256, 256, 768,
      nullptr, emb, pos);

  // ---- patch GRU (h bf16 recurrence; pp-LN fused into local store) ----
  unsigned short* ghB = (unsigned short*)R_b1;
  gru_pw_k<1><<<dim3(BN_ / 4), blk, 0, stream>>>(
      nullptr, gru_bhh, R_embW, x, gru_bih, pp_ln_g, pp_ln_b, R_hb, R_loc, 0);
  for (int t = 1; t < 4; ++t) {
    gemm_big<1, 0, 1><<<dim3(6, 128), blk, 0, stream>>>(
        R_hb, whhT, gru_bhh, ghB, BN_, 768, 256, 256, 768);
    gru_pw_k<0><<<dim3(BN_ / 4), blk, 0, stream>>>(
        ghB, gru_bhh, R_embW, x, gru_bih, pp_ln_g, pp_ln_b, R_hb, R_loc, t);
  }

  // summaries -> h (bf16)
  gemm_mfma<9, 0, 0, 1><<<dim3(4, 256), blk, 0, stream>>>(
      (const float*)R_loc, sumT, sum_b, R_hb, BN_, 256, 256, 256, 256,
      nullptr, nullptr, nullptr);

  // ---- message-passing rounds ----
  unsigned short* hsnB = (unsigned short*)R_b1;
  unsigned short* UB   = (unsigned short*)R_b2;
  unsigned short* Sb   = (unsigned short*)R_b3;
  for (int step = 0; step < 4; ++step) {
    gemm_big<1, 0, 1><<<dim3(4, 128), blk, 0, stream>>>(
        R_hb, W1cT, R_bH, hsnB, BN_, 512, 256, 256, 512);
    smsg_k<<<dim3(BN_ / 4), blk, 0, stream>>>(hsnB, Sb);
    gemm_mfma<10, 0, 1, 1><<<dim3(4, 256), blk, 0, stream>>>(
        (const float*)R_hb, u1cT, R_bU, UB, BN_, 256, 512, 512, 256,
        (const float*)Sb, nullptr, nullptr);
    if (step == 3) {
      gemm_ln<3><<<dim3(BN_ / 16), blk, 0, stream>>>(
          UB, u2T, upd_b2, R_hb, mp_ln_g, mp_ln_b, R_hp, R_outB);
    } else {
      gemm_ln<0><<<dim3(BN_ / 16), blk, 0, stream>>>(
          UB, u2T, upd_b2, R_hb, mp_ln_g, mp_ln_b, nullptr, nullptr);
      if (step == 2) {
        halt1_k<<<dim3(32, 16), blk, 0, stream>>>(R_hb, halt_w, R_part);
        halt2_k<<<dim3(1), dim3(64), 0, stream>>>(R_part, halt_b, R_hp);
        out2_k<<<dim3(BN_ / 4), blk, 0, stream>>>(R_hb, R_hp, R_outB);
      }
    }
  }

  // ---- sparse retrieval attention ----
  unsigned short* qkv  = (unsigned short*)R_b3;           // [BN][768] bf16 (h dead)
  unsigned short* rpre = ((unsigned short*)R_rp) + SZ_Q;  // [BN][256] bf16
  unsigned short* sc   = (unsigned short*)R_b1;           // 32x512x512 bf16
  gemm_big<1, 0, 1><<<dim3(6, 128), blk, 0, stream>>>(
      R_outB, qkvT, R_bQKV, qkv, BN_, 768, 256, 256, 768);
  scores_tri<<<dim3(1152), blk, 0, stream>>>(qkv, sc);
  topk_k<<<dim3(BN_ / 4), blk, 0, stream>>>(sc, qkv, rpre);

  // broad = [outp | rpre] @ brWT^T + biasB2  -> bf16 in R_h region
  unsigned short* broadB = (unsigned short*)R_h;
  gemm_mfma<10, 0, 0, 1><<<dim3(4, 256), blk, 0, stream>>>(
      (const float*)R_outB, brWT, R_bB2, broadB, BN_, 256, 512, 512, 256,
      (const float*)rpre, nullptr, nullptr);

  // final LN + convert -> Abuf (in b1, sc dead), head GEMM (128-tile) -> logits
  unsigned short* Abuf = (unsigned short*)R_b1;
  ln_cvt_k<<<dim3(M1_ / 4), blk, 0, stream>>>(R_loc, broadB, f_ln_g, f_ln_b, Abuf);
  gemm_big<1, 0, 0><<<dim3(2, 512), blk, 0, stream>>>(
      Abuf, headT, nullptr, logits, M1_, 256, 256, 256, 256);

  kl_k<<<dim3(1), dim3(64), 0, stream>>>(R_hp, logits + (size_t)M1_ * 256);
}

// Round 20
// 539.992 us; speedup vs baseline: 1.1858x; 1.0155x over previous
//
#include <hip/hip_runtime.h>
#include <cmath>

// ---------------------------------------------------------------------------
// SutraV04 round 19 = round 18 (548 us, best) + out2_k eliminated:
// gemm_ln<4> (final msg step) computes outp = hp*h2 + (1-hp)*y directly in
// its epilogue (h2 = residual operand it already reads), skips the h store
// (h dead after step 3). Removes 1 launch + ~40 MB traffic.
// ---------------------------------------------------------------------------

constexpr int N_   = 512;
constexpr int B_   = 32;
constexpr int BN_  = B_ * N_;   // 16384
constexpr int M1_  = BN_ * 4;   // 65536

typedef short bf16x8 __attribute__((ext_vector_type(8)));
typedef float f32x4  __attribute__((ext_vector_type(4)));

__device__ __forceinline__ float gelu_f(float x) {
  return 0.5f * x * (1.0f + erff(x * 0.70710678118654752440f));
}
__device__ __forceinline__ float sigm_f(float x) {
  return 1.0f / (1.0f + expf(-x));
}
__device__ __forceinline__ unsigned short f2bf(float f) {
  union { float f; unsigned int u; } c; c.f = f;
  unsigned int u = c.u;
  u += 0x7FFFu + ((u >> 16) & 1u);
  return (unsigned short)(u >> 16);
}
__device__ __forceinline__ float bf2f(unsigned short u) {
  union { unsigned int u; float f; } c; c.u = ((unsigned int)u) << 16;
  return c.f;
}
__device__ __forceinline__ int phys(int g, int r) {      // 64-row tiles
  return ((g << 6) | (r ^ g)) << 3;
}
__device__ __forceinline__ int phys128(int g, int r) {   // 128-row tiles
  return ((g << 7) | (r ^ g)) << 3;
}
__device__ __forceinline__ int phys16(int g, int r) {    // 16-row tiles
  return ((g << 4) | (r ^ g)) << 3;
}

// XCD-aware block remap: same-A-panel blocks (all nB of a chunk of mB) land
// on one XCD (flat % 8). Bijective; falls back to identity if nby % 8 != 0.
__device__ __forceinline__ void xcd_map(int& mB, int& nB) {
  int nbx = gridDim.x, nby = gridDim.y;
  if ((nby & 7) == 0) {
    int flat = blockIdx.y * nbx + blockIdx.x;
    int chunk = nby >> 3;
    int xcd = flat & 7, s2 = flat >> 3;
    int q = s2 / nbx;
    mB = xcd * chunk + q;
    nB = s2 - q * nbx;
  } else {
    mB = blockIdx.y; nB = blockIdx.x;
  }
}

// ---- 128x128-tile MFMA GEMM ----------------------------------------------
// AMODE: 0 f32 [m][K]; 1 bf16 [m][K].  EPI: 0 none, 1 gelu. COUT: 0 f32, 1 bf16.
template<int AMODE, int EPI, int COUT>
__global__ __launch_bounds__(256)
void gemm_big(const void* __restrict__ A, const unsigned short* __restrict__ Bt,
              const float* __restrict__ bias, void* __restrict__ C,
              int M, int Nn, int K, int bstride, int ldC)
{
  __shared__ short As[4 * 128 * 8];
  __shared__ short Bs[4 * 128 * 8];
  const int t  = threadIdx.x;
  int mB, nB;
  xcd_map(mB, nB);
  const int m0 = mB * 128, n0 = nB * 128;
  const int lane = t & 63, w = t >> 6;
  const int wr = w >> 1, wc = w & 1;
  const int fr = lane & 15, fg = lane >> 4;

  f32x4 acc[4][4] = {};

  for (int k0 = 0; k0 < K; k0 += 32) {
    #pragma unroll
    for (int c = 0; c < 2; ++c) {
      int idx = t + c * 256;
      int row = idx >> 2, g = idx & 3;
      int kk = k0 + g * 8;
      bf16x8 av;
      if constexpr (AMODE == 1) {
        av = *(const bf16x8*)&((const unsigned short*)A)[(size_t)(m0 + row) * K + kk];
      } else {
        const float4* p = (const float4*)&((const float*)A)[(size_t)(m0 + row) * K + kk];
        float4 a = p[0], b = p[1];
        av[0]=(short)f2bf(a.x); av[1]=(short)f2bf(a.y); av[2]=(short)f2bf(a.z); av[3]=(short)f2bf(a.w);
        av[4]=(short)f2bf(b.x); av[5]=(short)f2bf(b.y); av[6]=(short)f2bf(b.z); av[7]=(short)f2bf(b.w);
      }
      *(bf16x8*)&As[phys128(g, row)] = av;
      *(bf16x8*)&Bs[phys128(g, row)] =
          *(const bf16x8*)&Bt[(size_t)(n0 + row) * bstride + kk];
    }
    __syncthreads();

    bf16x8 a[4], b[4];
    #pragma unroll
    for (int i = 0; i < 4; ++i)
      a[i] = *(const bf16x8*)&As[phys128(fg, wr * 64 + i * 16 + fr)];
    #pragma unroll
    for (int j = 0; j < 4; ++j)
      b[j] = *(const bf16x8*)&Bs[phys128(fg, wc * 64 + j * 16 + fr)];
    #pragma unroll
    for (int i = 0; i < 4; ++i)
      #pragma unroll
      for (int j = 0; j < 4; ++j)
        acc[i][j] = __builtin_amdgcn_mfma_f32_16x16x32_bf16(a[i], b[j], acc[i][j], 0, 0, 0);
    __syncthreads();
  }

  #pragma unroll
  for (int i = 0; i < 4; ++i)
    #pragma unroll
    for (int j = 0; j < 4; ++j) {
      int col = n0 + wc * 64 + j * 16 + fr;
      float bcol = bias ? bias[col] : 0.0f;
      #pragma unroll
      for (int r = 0; r < 4; ++r) {
        int row = m0 + wr * 64 + i * 16 + fg * 4 + r;
        float vv = acc[i][j][r] + bcol;
        if constexpr (EPI == 1) vv = gelu_f(vv);
        if constexpr (COUT == 0)
          ((float*)C)[(size_t)row * ldC + col] = vv;
        else
          ((unsigned short*)C)[(size_t)row * ldC + col] = f2bf(vv);
      }
    }
}

// ---- 64-tile gather GEMM --------------------------------------------------
// MODE: 6 emb/pos rows; 8 transposed f32 gather P2[k*256+m]; 9 bf16 patch-mean;
//       10 concat(bf16 A | bf16 P2); 11 concat(f32 A | bf16 P2)
// BSRC: 0 bf16 Bt; 1 fp32.  EPI: 0 none, 1 gelu.  COUT: 0 f32, 1 bf16.
template<int MODE, int BSRC, int EPI, int COUT>
__global__ __launch_bounds__(256)
void gemm_mfma(const float* __restrict__ A, const void* __restrict__ Bsrc,
               const float* __restrict__ bias, void* __restrict__ C,
               int M, int Nn, int K, int bstride, int ldC,
               const float* __restrict__ P2,
               const float* __restrict__ emb, const float* __restrict__ pos)
{
  __shared__ short As[4 * 64 * 8];
  __shared__ short Bs[4 * 64 * 8];
  const int tid  = threadIdx.x;
  int mB, nB;
  xcd_map(mB, nB);
  const int m0 = mB * 64, n0 = nB * 64;
  const int srow = tid >> 2, sg = tid & 3;
  const int lane = tid & 63, w = tid >> 6;
  const int wr   = w >> 1,  wc = w & 1;
  const int fr   = lane & 15, fg = lane >> 4;

  f32x4 acc[2][2] = {};

  for (int k0 = 0; k0 < K; k0 += 32) {
    {
      int m = m0 + srow, k = k0 + sg * 8;
      bf16x8 tv;
      if constexpr (MODE == 10) {
        if (k < 256)
          tv = *(const bf16x8*)&((const unsigned short*)A)[(size_t)m * 256 + k];
        else
          tv = *(const bf16x8*)&((const unsigned short*)P2)[(size_t)m * 256 + (k - 256)];
      } else if constexpr (MODE == 11) {
        if (k < 256) {
          const float4* p = (const float4*)(A + (size_t)m * 256 + k);
          float4 a = p[0], b = p[1];
          tv[0]=(short)f2bf(a.x); tv[1]=(short)f2bf(a.y); tv[2]=(short)f2bf(a.z); tv[3]=(short)f2bf(a.w);
          tv[4]=(short)f2bf(b.x); tv[5]=(short)f2bf(b.y); tv[6]=(short)f2bf(b.z); tv[7]=(short)f2bf(b.w);
        } else {
          tv = *(const bf16x8*)&((const unsigned short*)P2)[(size_t)m * 256 + (k - 256)];
        }
      } else {
        float v[8];
        if constexpr (MODE == 6) {
          const float* src = nullptr;
          if (m < 256) src = emb + (size_t)m * 256 + k;
          else if (m < 260) src = pos + (size_t)(m - 256) * 256 + k;
          if (src) {
            const float4* p = (const float4*)src;
            float4 a = p[0], b = p[1];
            v[0]=a.x; v[1]=a.y; v[2]=a.z; v[3]=a.w; v[4]=b.x; v[5]=b.y; v[6]=b.z; v[7]=b.w;
          } else {
            #pragma unroll
            for (int j = 0; j < 8; ++j) v[j] = 0.f;
          }
        } else if constexpr (MODE == 8) {
          #pragma unroll
          for (int j = 0; j < 8; ++j) v[j] = P2[(size_t)(k + j) * 256 + m];
        } else { // 9
          const unsigned short* Ab = (const unsigned short*)A;
          const unsigned short* base = Ab + (size_t)m * 1024 + k;
          bf16x8 r0 = *(const bf16x8*)(base);
          bf16x8 r1 = *(const bf16x8*)(base + 256);
          bf16x8 r2 = *(const bf16x8*)(base + 512);
          bf16x8 r3 = *(const bf16x8*)(base + 768);
          #pragma unroll
          for (int j = 0; j < 8; ++j)
            v[j] = 0.25f * (bf2f((unsigned short)r0[j]) + bf2f((unsigned short)r1[j]) +
                            bf2f((unsigned short)r2[j]) + bf2f((unsigned short)r3[j]));
        }
        #pragma unroll
        for (int j = 0; j < 8; ++j) tv[j] = (short)f2bf(v[j]);
      }
      *(bf16x8*)&As[phys(sg, srow)] = tv;
    }
    if constexpr (BSRC == 0) {
      const unsigned short* Bt = (const unsigned short*)Bsrc;
      *(bf16x8*)&Bs[phys(sg, srow)] =
          *(const bf16x8*)&Bt[(size_t)(n0 + srow) * bstride + k0 + sg * 8];
    } else {
      const float* Bf = (const float*)Bsrc;
      const float4* p = (const float4*)(Bf + (size_t)(n0 + srow) * bstride + k0 + sg * 8);
      float4 a = p[0], b = p[1];
      bf16x8 tv;
      tv[0]=(short)f2bf(a.x); tv[1]=(short)f2bf(a.y); tv[2]=(short)f2bf(a.z); tv[3]=(short)f2bf(a.w);
      tv[4]=(short)f2bf(b.x); tv[5]=(short)f2bf(b.y); tv[6]=(short)f2bf(b.z); tv[7]=(short)f2bf(b.w);
      *(bf16x8*)&Bs[phys(sg, srow)] = tv;
    }
    __syncthreads();

    bf16x8 a0 = *(const bf16x8*)&As[phys(fg, wr * 32 + fr)];
    bf16x8 a1 = *(const bf16x8*)&As[phys(fg, wr * 32 + 16 + fr)];
    bf16x8 b0 = *(const bf16x8*)&Bs[phys(fg, wc * 32 + fr)];
    bf16x8 b1 = *(const bf16x8*)&Bs[phys(fg, wc * 32 + 16 + fr)];
    acc[0][0] = __builtin_amdgcn_mfma_f32_16x16x32_bf16(a0, b0, acc[0][0], 0, 0, 0);
    acc[0][1] = __builtin_amdgcn_mfma_f32_16x16x32_bf16(a0, b1, acc[0][1], 0, 0, 0);
    acc[1][0] = __builtin_amdgcn_mfma_f32_16x16x32_bf16(a1, b0, acc[1][0], 0, 0, 0);
    acc[1][1] = __builtin_amdgcn_mfma_f32_16x16x32_bf16(a1, b1, acc[1][1], 0, 0, 0);
    __syncthreads();
  }

  #pragma unroll
  for (int i = 0; i < 2; ++i) {
    #pragma unroll
    for (int j = 0; j < 2; ++j) {
      int row0 = m0 + wr * 32 + i * 16 + fg * 4;
      int col  = n0 + wc * 32 + j * 16 + fr;
      float bcol = bias ? bias[col] : 0.0f;
      #pragma unroll
      for (int r = 0; r < 4; ++r) {
        float vv = acc[i][j][r] + bcol;
        if constexpr (EPI == 1) vv = gelu_f(vv);
        int row = row0 + r;
        if constexpr (COUT == 0)
          ((float*)C)[(size_t)row * ldC + col] = vv;
        else
          ((unsigned short*)C)[(size_t)row * ldC + col] = f2bf(vv);
      }
    }
  }
}

// ---- fused upd-GEMM + residual + LN; 16-row full-width tile ---------------
// OUTM==0: h = LN(h + upd).
// OUTM==4: final step: outp = hp*h2 + (1-hp)*LN(h2+upd); h NOT written.
template<int OUTM>
__global__ __launch_bounds__(256)
void gemm_ln(const unsigned short* __restrict__ U, const unsigned short* __restrict__ u2T,
             const float* __restrict__ bias, unsigned short* __restrict__ h,
             const float* __restrict__ g, const float* __restrict__ bb,
             const float* __restrict__ hp, unsigned short* __restrict__ outp)
{
  __shared__ short As[4 * 16 * 8];
  __shared__ short Bs[4 * 256 * 8];
  __shared__ float psum[4][16], pssq[4][16];
  const int m0 = blockIdx.x * 16;
  const int t  = threadIdx.x;
  const int lane = t & 63, w = t >> 6;
  const int fr = lane & 15, fg = lane >> 4;

  f32x4 acc[4] = {};
  for (int k0 = 0; k0 < 256; k0 += 32) {
    if (t < 64) {
      int row = t >> 2, gq = t & 3;
      *(bf16x8*)&As[phys16(gq, row)] =
          *(const bf16x8*)&U[(size_t)(m0 + row) * 256 + k0 + gq * 8];
    }
    const unsigned short* brow = u2T + (size_t)t * 256 + k0;
    #pragma unroll
    for (int gq = 0; gq < 4; ++gq)
      *(bf16x8*)&Bs[((gq << 8) | (t ^ gq)) << 3] = *(const bf16x8*)(brow + gq * 8);
    __syncthreads();
    bf16x8 a = *(const bf16x8*)&As[phys16(fg, fr)];
    #pragma unroll
    for (int j = 0; j < 4; ++j) {
      int n = 64 * w + 16 * j + fr;
      bf16x8 b = *(const bf16x8*)&Bs[((fg << 8) | (n ^ fg)) << 3];
      acc[j] = __builtin_amdgcn_mfma_f32_16x16x32_bf16(a, b, acc[j], 0, 0, 0);
    }
    __syncthreads();
  }

  float bcol[4], gv[4], bv[4];
  #pragma unroll
  for (int j = 0; j < 4; ++j) {
    int col = 64 * w + 16 * j + fr;
    bcol[j] = bias[col]; gv[j] = g[col]; bv[j] = bb[col];
  }
  float hold[4][4];
  float vsum[4] = {}, vssq[4] = {};
  #pragma unroll
  for (int j = 0; j < 4; ++j) {
    int col = 64 * w + 16 * j + fr;
    #pragma unroll
    for (int r = 0; r < 4; ++r) {
      int row = m0 + 4 * fg + r;
      float h2v = bf2f(h[(size_t)row * 256 + col]);
      hold[j][r] = h2v;
      float v = acc[j][r] + bcol[j] + h2v;
      acc[j][r] = v;
      vsum[r] += v;
      vssq[r] += v * v;
    }
  }
  #pragma unroll
  for (int off = 1; off < 16; off <<= 1) {
    #pragma unroll
    for (int r = 0; r < 4; ++r) {
      vsum[r] += __shfl_xor(vsum[r], off, 64);
      vssq[r] += __shfl_xor(vssq[r], off, 64);
    }
  }
  if (fr == 0) {
    #pragma unroll
    for (int r = 0; r < 4; ++r) {
      psum[w][4 * fg + r] = vsum[r];
      pssq[w][4 * fg + r] = vssq[r];
    }
  }
  __syncthreads();

  float hpv = 0.f, rem = 0.f;
  if constexpr (OUTM == 4) { hpv = hp[m0 >> 9]; rem = 1.0f - hpv; }
  #pragma unroll
  for (int r = 0; r < 4; ++r) {
    int rr = 4 * fg + r;
    float s  = psum[0][rr] + psum[1][rr] + psum[2][rr] + psum[3][rr];
    float q2 = pssq[0][rr] + pssq[1][rr] + pssq[2][rr] + pssq[3][rr];
    float mean = s * (1.0f / 256.0f);
    float var  = q2 * (1.0f / 256.0f) - mean * mean;
    float inv  = rsqrtf(var + 1e-5f);
    int row = m0 + rr;
    #pragma unroll
    for (int j = 0; j < 4; ++j) {
      int col = 64 * w + 16 * j + fr;
      float y = (acc[j][r] - mean) * inv * gv[j] + bv[j];
      if constexpr (OUTM == 4) {
        outp[(size_t)row * 256 + col] = f2bf(hpv * hold[j][r] + rem * y);
      } else {
        h[(size_t)row * 256 + col] = f2bf(y);
      }
    }
  }
}

// ---- causal tri-tile scores (bf16 out), XCD-swizzled ----------------------
__global__ __launch_bounds__(256)
void scores_tri(const unsigned short* __restrict__ qkv, unsigned short* __restrict__ sc)
{
  int flat = blockIdx.x;
  int xcd = flat & 7, s = flat >> 3;
  int bhi = s / 36, tile = s - bhi * 36;
  int b = bhi * 8 + xcd;
  int ti = 0;
  while ((ti + 1) * (ti + 2) / 2 <= tile) ++ti;
  int tj = tile - ti * (ti + 1) / 2;
  const int m0 = ti * 64, n0 = tj * 64;
  const unsigned short* Aq = qkv + (size_t)b * N_ * 768;
  const unsigned short* Bk = Aq + 256;

  __shared__ short As[4 * 64 * 8];
  __shared__ short Bs[4 * 64 * 8];
  const int tid  = threadIdx.x;
  const int srow = tid >> 2, sg = tid & 3;
  const int lane = tid & 63, w = tid >> 6;
  const int wr   = w >> 1,  wc = w & 1;
  const int fr   = lane & 15, fg = lane >> 4;

  f32x4 acc[2][2] = {};
  for (int k0 = 0; k0 < 256; k0 += 32) {
    *(bf16x8*)&As[phys(sg, srow)] =
        *(const bf16x8*)&Aq[(size_t)(m0 + srow) * 768 + k0 + sg * 8];
    *(bf16x8*)&Bs[phys(sg, srow)] =
        *(const bf16x8*)&Bk[(size_t)(n0 + srow) * 768 + k0 + sg * 8];
    __syncthreads();
    bf16x8 a0 = *(const bf16x8*)&As[phys(fg, wr * 32 + fr)];
    bf16x8 a1 = *(const bf16x8*)&As[phys(fg, wr * 32 + 16 + fr)];
    bf16x8 b0 = *(const bf16x8*)&Bs[phys(fg, wc * 32 + fr)];
    bf16x8 b1 = *(const bf16x8*)&Bs[phys(fg, wc * 32 + 16 + fr)];
    acc[0][0] = __builtin_amdgcn_mfma_f32_16x16x32_bf16(a0, b0, acc[0][0], 0, 0, 0);
    acc[0][1] = __builtin_amdgcn_mfma_f32_16x16x32_bf16(a0, b1, acc[0][1], 0, 0, 0);
    acc[1][0] = __builtin_amdgcn_mfma_f32_16x16x32_bf16(a1, b0, acc[1][0], 0, 0, 0);
    acc[1][1] = __builtin_amdgcn_mfma_f32_16x16x32_bf16(a1, b1, acc[1][1], 0, 0, 0);
    __syncthreads();
  }
  unsigned short* scb = sc + (size_t)b * N_ * N_;
  #pragma unroll
  for (int i = 0; i < 2; ++i) {
    #pragma unroll
    for (int j = 0; j < 2; ++j) {
      int row0 = m0 + wr * 32 + i * 16 + fg * 4;
      int col  = n0 + wc * 32 + j * 16 + fr;
      #pragma unroll
      for (int r = 0; r < 4; ++r) {
        int row = row0 + r;
        float vv = acc[i][j][r] * 0.0625f;
        if (col > row) vv = -__builtin_inff();
        scb[(size_t)row * N_ + col] = f2bf(vv);
      }
    }
  }
}

// ---- weight prep ----------------------------------------------------------
struct PrepJobs {
  const float* src[12];
  unsigned short* dst[12];
  int rows[12];
  int dstride[12];
  int strt[12];
};
__global__ __launch_bounds__(256)
void prep_w_k(PrepJobs pj)
{
  int jid = blockIdx.y;
  const float* src = pj.src[jid];
  unsigned short* dst = pj.dst[jid];
  int ds = pj.dstride[jid];
  int total = pj.rows[jid] << 8;
  if (pj.strt[jid]) {
    for (int i = blockIdx.x * 256 + threadIdx.x; i < total; i += gridDim.x * 256) {
      int k = i & 255, n = i >> 8;
      dst[(size_t)n * ds + k] = f2bf(src[i]);
    }
  } else {
    for (int i = blockIdx.x * 256 + threadIdx.x; i < total; i += gridDim.x * 256) {
      int k = i & 255, n = i >> 8;
      dst[(size_t)n * ds + k] = f2bf(src[(size_t)k * 256 + n]);
    }
  }
}

// ---- bias prep ------------------------------------------------------------
__global__ __launch_bounds__(256)
void biasprep_k(const float* __restrict__ upd_b1, const float* __restrict__ msg_b2,
                const float* __restrict__ upd_w1, const float* __restrict__ msg_b1,
                const float* __restrict__ o_b, const float* __restrict__ br_w,
                const float* __restrict__ br_b, const float* __restrict__ q_b,
                const float* __restrict__ k_b, const float* __restrict__ v_b,
                float* __restrict__ biasU, float* __restrict__ biasHsn,
                float* __restrict__ biasB2, float* __restrict__ bQKV)
{
  int c = threadIdx.x;
  float s = upd_b1[c];
  for (int k = 0; k < 256; ++k)
    s += msg_b2[k] * upd_w1[(size_t)(256 + k) * 256 + c];
  biasU[c] = s;
  biasHsn[c] = msg_b1[c];
  biasHsn[256 + c] = 0.f;
  float s2 = br_b[c];
  for (int k = 0; k < 256; ++k)
    s2 += o_b[k] * br_w[(size_t)k * 256 + c];
  biasB2[c] = s2;
  bQKV[c] = q_b[c]; bQKV[256 + c] = k_b[c]; bQKV[512 + c] = v_b[c];
}

// ---- GRU pointwise + fused pp-LN (one wave per local row) -----------------
template<int FIRST>
__global__ __launch_bounds__(256)
void gru_pw_k(const unsigned short* __restrict__ gh, const float* __restrict__ bhh,
              const float* __restrict__ embW, const int* __restrict__ x,
              const float* __restrict__ bih,
              const float* __restrict__ lng, const float* __restrict__ lnb,
              unsigned short* __restrict__ h, unsigned short* __restrict__ local, int t)
{
  int i   = blockIdx.x * 256 + threadIdx.x;   // over BN*64 groups
  int row = i >> 6, d0 = (i & 63) << 2;
  int tok = x[row * 4 + t];
  const float* er = embW + (size_t)tok * 768;
  const float* pr = embW + (size_t)(256 + t) * 768;
  float4 e0 = *(const float4*)(er + d0);
  float4 e1 = *(const float4*)(er + 256 + d0);
  float4 e2 = *(const float4*)(er + 512 + d0);
  float4 p0 = *(const float4*)(pr + d0);
  float4 p1 = *(const float4*)(pr + 256 + d0);
  float4 p2 = *(const float4*)(pr + 512 + d0);
  float4 q0 = *(const float4*)(bih + d0);
  float4 q1 = *(const float4*)(bih + 256 + d0);
  float4 q2 = *(const float4*)(bih + 512 + d0);
  float ir[4]  = {e0.x+p0.x+q0.x, e0.y+p0.y+q0.y, e0.z+p0.z+q0.z, e0.w+p0.w+q0.w};
  float iz[4]  = {e1.x+p1.x+q1.x, e1.y+p1.y+q1.y, e1.z+p1.z+q1.z, e1.w+p1.w+q1.w};
  float inn[4] = {e2.x+p2.x+q2.x, e2.y+p2.y+q2.y, e2.z+p2.z+q2.z, e2.w+p2.w+q2.w};
  float hr[4], hz[4], hn[4];
  if constexpr (FIRST) {
    float4 b0 = *(const float4*)(bhh + d0);
    float4 b1 = *(const float4*)(bhh + 256 + d0);
    float4 b2 = *(const float4*)(bhh + 512 + d0);
    hr[0]=b0.x; hr[1]=b0.y; hr[2]=b0.z; hr[3]=b0.w;
    hz[0]=b1.x; hz[1]=b1.y; hz[2]=b1.z; hz[3]=b1.w;
    hn[0]=b2.x; hn[1]=b2.y; hn[2]=b2.z; hn[3]=b2.w;
  } else {
    const unsigned short* gr = gh + (size_t)row * 768;
    ushort4 u0 = *(const ushort4*)(gr + d0);
    ushort4 u1 = *(const ushort4*)(gr + 256 + d0);
    ushort4 u2 = *(const ushort4*)(gr + 512 + d0);
    hr[0]=bf2f(u0.x); hr[1]=bf2f(u0.y); hr[2]=bf2f(u0.z); hr[3]=bf2f(u0.w);
    hz[0]=bf2f(u1.x); hz[1]=bf2f(u1.y); hz[2]=bf2f(u1.z); hz[3]=bf2f(u1.w);
    hn[0]=bf2f(u2.x); hn[1]=bf2f(u2.y); hn[2]=bf2f(u2.z); hn[3]=bf2f(u2.w);
  }
  ushort4 hprev = {0, 0, 0, 0};
  if constexpr (!FIRST) hprev = *(const ushort4*)&h[(size_t)row * 256 + d0];
  float hp4[4] = {bf2f(hprev.x), bf2f(hprev.y), bf2f(hprev.z), bf2f(hprev.w)};
  float hv[4];
  ushort4 oh;
  #pragma unroll
  for (int e = 0; e < 4; ++e) {
    float r  = sigm_f(ir[e] + hr[e]);
    float zg = sigm_f(iz[e] + hz[e]);
    float nn = tanhf(inn[e] + r * hn[e]);
    float hnew;
    if constexpr (FIRST) hnew = (1.0f - zg) * nn;
    else                 hnew = (1.0f - zg) * nn + zg * hp4[e];
    hv[e] = hnew;
    ((unsigned short*)&oh)[e] = f2bf(hnew);
  }
  *(ushort4*)&h[(size_t)row * 256 + d0] = oh;

  // fused pp-LN over this wave's row (64 lanes x 4 elems = 256)
  float s = hv[0] + hv[1] + hv[2] + hv[3];
  #pragma unroll
  for (int off = 1; off < 64; off <<= 1) s += __shfl_xor(s, off, 64);
  float mean = s * (1.0f / 256.0f);
  float ss = 0.f;
  #pragma unroll
  for (int e = 0; e < 4; ++e) { float d = hv[e] - mean; ss += d * d; }
  #pragma unroll
  for (int off = 1; off < 64; off <<= 1) ss += __shfl_xor(ss, off, 64);
  float inv = rsqrtf(ss * (1.0f / 256.0f) + 1e-5f);
  const float4 g4 = *(const float4*)(lng + d0);
  const float4 b4 = *(const float4*)(lnb + d0);
  ushort4 ol;
  ol.x = f2bf((hv[0] - mean) * inv * g4.x + b4.x);
  ol.y = f2bf((hv[1] - mean) * inv * g4.y + b4.y);
  ol.z = f2bf((hv[2] - mean) * inv * g4.z + b4.z);
  ol.w = f2bf((hv[3] - mean) * inv * g4.w + b4.w);
  *(ushort4*)&local[((size_t)row * 4 + t) * 256 + d0] = ol;
}

// ---- S' = rowscale( sum_kk gelu(hs + shift(hn)) ) -> bf16 -----------------
__global__ __launch_bounds__(256)
void smsg_k(const unsigned short* __restrict__ hsn, unsigned short* __restrict__ S)
{
  int i = blockIdx.x * 256 + threadIdx.x;   // BN*64
  int m = i >> 6, d4 = (i & 63) << 2;
  int n = m & (N_ - 1);
  ushort4 hsu = *(const ushort4*)&hsn[(size_t)m * 512 + d4];
  float hs0 = bf2f(hsu.x), hs1 = bf2f(hsu.y), hs2 = bf2f(hsu.z), hs3 = bf2f(hsu.w);
  float a0 = 0.f, a1 = 0.f, a2 = 0.f, a3 = 0.f;
  #pragma unroll
  for (int kk = 0; kk < 5; ++kk) {
    int idx = n + kk - 4;
    if (idx >= 0) {
      ushort4 hv = *(const ushort4*)&hsn[(size_t)(m + kk - 4) * 512 + 256 + d4];
      a0 += gelu_f(hs0 + bf2f(hv.x));
      a1 += gelu_f(hs1 + bf2f(hv.y));
      a2 += gelu_f(hs2 + bf2f(hv.z));
      a3 += gelu_f(hs3 + bf2f(hv.w));
    }
  }
  float sc1 = 1.0f / (float)((n < 4 ? n : 4) + 1);
  ushort4 o = {f2bf(a0 * sc1), f2bf(a1 * sc1), f2bf(a2 * sc1), f2bf(a3 * sc1)};
  *(ushort4*)&S[(size_t)m * 256 + d4] = o;
}

// ---- final LN: local bf16 + broad bf16 -> Abuf bf16 -----------------------
__global__ __launch_bounds__(256)
void ln_cvt_k(const unsigned short* __restrict__ X, const unsigned short* __restrict__ Add,
              const float* __restrict__ g, const float* __restrict__ bb,
              unsigned short* __restrict__ Out)
{
  int wave = threadIdx.x >> 6, lane = threadIdx.x & 63;
  int row  = blockIdx.x * 4 + wave;
  ushort4 u = *(const ushort4*)&X[(size_t)row * 256 + lane * 4];
  ushort4 a = *(const ushort4*)&Add[(size_t)(row >> 2) * 256 + lane * 4];
  float x[4] = {bf2f(u.x) + bf2f(a.x), bf2f(u.y) + bf2f(a.y),
                bf2f(u.z) + bf2f(a.z), bf2f(u.w) + bf2f(a.w)};
  float s = x[0] + x[1] + x[2] + x[3];
  #pragma unroll
  for (int off = 1; off < 64; off <<= 1) s += __shfl_xor(s, off, 64);
  float mean = s * (1.0f / 256.0f);
  float ss = 0.f;
  #pragma unroll
  for (int j = 0; j < 4; ++j) { float d = x[j] - mean; ss += d * d; }
  #pragma unroll
  for (int off = 1; off < 64; off <<= 1) ss += __shfl_xor(ss, off, 64);
  float inv = rsqrtf(ss * (1.0f / 256.0f) + 1e-5f);
  ushort4 o;
  o.x = f2bf((x[0] - mean) * inv * g[lane*4+0] + bb[lane*4+0]);
  o.y = f2bf((x[1] - mean) * inv * g[lane*4+1] + bb[lane*4+1]);
  o.z = f2bf((x[2] - mean) * inv * g[lane*4+2] + bb[lane*4+2]);
  o.w = f2bf((x[3] - mean) * inv * g[lane*4+3] + bb[lane*4+3]);
  *(ushort4*)&Out[(size_t)row * 256 + lane * 4] = o;
}

// ---- halting (h bf16) ------------------------------------------------------
__global__ __launch_bounds__(256)
void halt1_k(const unsigned short* __restrict__ h, const float* __restrict__ hw,
             float* __restrict__ part)
{
  int b = blockIdx.x, s = blockIdx.y, tid = threadIdx.x;
  const unsigned short* p = h + ((size_t)b * N_ + s * 32) * 256;
  float acc = 0.f;
  for (int i = tid * 4; i < 32 * 256; i += 1024) {
    ushort4 u = *(const ushort4*)&p[i];
    const float4 w4 = *(const float4*)&hw[i & 255];
    acc += bf2f(u.x) * w4.x + bf2f(u.y) * w4.y + bf2f(u.z) * w4.z + bf2f(u.w) * w4.w;
  }
  __shared__ float red[256];
  red[tid] = acc; __syncthreads();
  for (int off = 128; off > 0; off >>= 1) {
    if (tid < off) red[tid] += red[tid + off];
    __syncthreads();
  }
  if (tid == 0) part[b * 16 + s] = red[0];
}
__global__ __launch_bounds__(64)
void halt2_k(const float* __restrict__ part, const float* __restrict__ hb,
             float* __restrict__ hp)
{
  int b = threadIdx.x;
  if (b < 32) {
    float s = 0.f;
    for (int i = 0; i < 16; ++i) s += part[b * 16 + i];
    hp[b] = sigm_f(s * (1.0f / (float)N_) + hb[0]);
  }
}

// ---- wave-per-row top-8 + softmax + V gather (sc bf16, qkv stride 768) ----
__global__ __launch_bounds__(256)
void topk_k(const unsigned short* __restrict__ sc, const unsigned short* __restrict__ qkv,
            unsigned short* __restrict__ rpre)
{
  const float NEG = -__builtin_inff();
  int wave = threadIdx.x >> 6, lane = threadIdx.x & 63;
  int rowg = blockIdx.x * 4 + wave;
  int b = rowg >> 9, n = rowg & (N_ - 1);
  const unsigned short* srow = sc + (size_t)rowg * N_;
  float v[8];
  #pragma unroll
  for (int j = 0; j < 8; ++j) {
    int col = lane + j * 64;
    v[j] = (col <= n) ? bf2f(srow[col]) : NEG;
  }
  float tv[8]; int ti[8];
  #pragma unroll
  for (int it = 0; it < 8; ++it) {
    float bv = v[0]; int bi = lane;
    #pragma unroll
    for (int j = 1; j < 8; ++j)
      if (v[j] > bv) { bv = v[j]; bi = lane + j * 64; }
    #pragma unroll
    for (int off = 1; off < 64; off <<= 1) {
      float ov = __shfl_xor(bv, off, 64);
      int   oi = __shfl_xor(bi, off, 64);
      if (ov > bv || (ov == bv && oi < bi)) { bv = ov; bi = oi; }
    }
    tv[it] = bv; ti[it] = bi;
    if ((bi & 63) == lane) v[bi >> 6] = NEG;
  }
  float mx = tv[0];
  float wsum = 0.f, wj[8];
  #pragma unroll
  for (int j = 0; j < 8; ++j) { wj[j] = expf(tv[j] - mx); wsum += wj[j]; }
  float inv = 1.0f / wsum;
  const unsigned short* vb = qkv + 512;
  int d0 = lane * 4;
  float a0 = 0.f, a1 = 0.f, a2 = 0.f, a3 = 0.f;
  #pragma unroll
  for (int j = 0; j < 8; ++j) {
    float wgt = wj[j] * inv;
    ushort4 vv = *(const ushort4*)&vb[((size_t)(b * N_ + ti[j])) * 768 + d0];
    a0 += wgt * bf2f(vv.x); a1 += wgt * bf2f(vv.y);
    a2 += wgt * bf2f(vv.z); a3 += wgt * bf2f(vv.w);
  }
  ushort4 o = {f2bf(a0), f2bf(a1), f2bf(a2), f2bf(a3)};
  *(ushort4*)&rpre[(size_t)rowg * 256 + d0] = o;
}

// ---- KL scalar ------------------------------------------------------------
__global__ void kl_k(const float* __restrict__ hp, float* __restrict__ out)
{
  if (threadIdx.x == 0 && blockIdx.x == 0) {
    float hm = 0.f;
    for (int b = 0; b < 32; ++b) hm += hp[b];
    hm *= (1.0f / 32.0f);
    const float l1e8 = logf(1e-8f);
    float kl = 0.f;
    kl += 0.2f    * (logf(0.2f)    - l1e8);
    kl += 0.16f   * (logf(0.16f)   - l1e8);
    kl += 0.128f  * (logf(0.128f)  - logf(hm + 1e-8f));
    kl += 0.1024f * (logf(0.1024f) - logf(1.0f + 1e-8f));
    out[0] = kl * 0.25f;
  }
}

// ---------------------------------------------------------------------------
extern "C" void kernel_launch(void* const* d_in, const int* in_sizes, int n_in,
                              void* d_out, int out_size, void* d_ws, size_t ws_size,
                              hipStream_t stream)
{
  const int*   x       = (const int*)  d_in[0];
  const float* emb     = (const float*)d_in[1];
  const float* pos     = (const float*)d_in[2];
  const float* gru_wih = (const float*)d_in[3];
  const float* gru_whh = (const float*)d_in[4];
  const float* gru_bih = (const float*)d_in[5];
  const float* gru_bhh = (const float*)d_in[6];
  const float* pp_ln_g = (const float*)d_in[7];
  const float* pp_ln_b = (const float*)d_in[8];
  const float* sum_w   = (const float*)d_in[9];
  const float* sum_b   = (const float*)d_in[10];
  const float* msg_w1  = (const float*)d_in[11];
  const float* msg_b1  = (const float*)d_in[12];
  const float* msg_w2  = (const float*)d_in[13];
  const float* msg_b2  = (const float*)d_in[14];
  const float* upd_w1  = (const float*)d_in[15];
  const float* upd_b1  = (const float*)d_in[16];
  const float* upd_w2  = (const float*)d_in[17];
  const float* upd_b2  = (const float*)d_in[18];
  const float* halt_w  = (const float*)d_in[19];
  const float* halt_b  = (const float*)d_in[20];
  const float* mp_ln_g = (const float*)d_in[21];
  const float* mp_ln_b = (const float*)d_in[22];
  const float* q_w     = (const float*)d_in[23];
  const float* q_b     = (const float*)d_in[24];
  const float* k_w     = (const float*)d_in[25];
  const float* k_b     = (const float*)d_in[26];
  const float* v_w     = (const float*)d_in[27];
  const float* v_b     = (const float*)d_in[28];
  const float* o_w     = (const float*)d_in[29];
  const float* o_b     = (const float*)d_in[30];
  const float* br_w    = (const float*)d_in[31];
  const float* br_b    = (const float*)d_in[32];
  const float* f_ln_g  = (const float*)d_in[33];
  const float* f_ln_b  = (const float*)d_in[34];
  const float* head_w  = (const float*)d_in[35];

  // ---- workspace ----
  constexpr size_t SZ_Q = (size_t)BN_ * 256;
  float* ws     = (float*)d_ws;
  float* R_h    = ws;                  // broad bf16 lives here late
  float* R_outp = R_h    + SZ_Q;       // outp bf16 (lower half)
  float* R_b1   = R_outp + SZ_Q;       // gh lo / hsn bf16 / sc bf16 / Abuf
  float* R_b2   = R_b1   + SZ_Q;       // gh hi / U bf16 / sc hi
  float* R_b3   = R_b2   + SZ_Q;       // S' bf16 + h bf16 / qkv lo
  float* R_rp   = R_b3   + SZ_Q;       // qkv hi + rpre bf16
  unsigned short* R_loc = (unsigned short*)(R_rp + SZ_Q);   // local bf16 (4*SZ_Q shorts)
  unsigned short* wb = R_loc + 4 * SZ_Q;
  unsigned short* sumT  = wb;                  // [256][256]
  unsigned short* W1cT  = sumT  + 65536;       // [512][256]
  unsigned short* u1cT  = W1cT  + 131072;      // [256][512] = [U1a | Wc]
  unsigned short* u2T   = u1cT  + 131072;      // [256][256]
  unsigned short* qkvT  = u2T   + 65536;       // [768][256]
  unsigned short* brWT  = qkvT  + 196608;      // [256][512] = [brW | WobT]
  unsigned short* headT = brWT  + 131072;      // [256][256]
  unsigned short* whhT  = headT + 65536;       // [768][256]
  float* R_embW = (float*)(whhT + 196608);     // [320][768]
  float* R_bU   = R_embW + 320 * 768;
  float* R_bH   = R_bU + 256;
  float* R_bB2  = R_bH + 512;
  float* R_bQKV = R_bB2 + 256;
  float* R_part = R_bQKV + 768;
  float* R_hp   = R_part + 512;

  // bf16 h (GRU recurrence + msg phase): upper half of b3
  unsigned short* R_hb   = ((unsigned short*)R_b3) + SZ_Q;
  // bf16 outp
  unsigned short* R_outB = (unsigned short*)R_outp;

  float* logits = (float*)d_out;
  dim3 blk(256);

  // ---- weight prep ----
  PrepJobs pj;
  const float* srcs[11] = {sum_w, msg_w1, msg_w1 + 65536, upd_w1, upd_w2,
                           q_w, k_w, v_w, br_w, head_w, gru_whh};
  unsigned short* dsts[11] = {sumT, W1cT, W1cT + 65536, u1cT, u2T,
                              qkvT, qkvT + 65536, qkvT + 131072, brWT, headT, whhT};
  int rows[11] = {256,256,256,256,256,256,256,256,256,256,768};
  int dstd[11] = {256,256,256,512,256,256,256,256,512,256,256};
  int strt[11] = {0,0,0,0,0,0,0,0,0,0,1};
  for (int i = 0; i < 11; ++i) {
    pj.src[i]=srcs[i]; pj.dst[i]=dsts[i]; pj.rows[i]=rows[i];
    pj.dstride[i]=dstd[i]; pj.strt[i]=strt[i];
  }
  prep_w_k<<<dim3(64, 11), blk, 0, stream>>>(pj);
  biasprep_k<<<dim3(1), blk, 0, stream>>>(upd_b1, msg_b2, upd_w1, msg_b1,
                                          o_b, br_w, br_b, q_b, k_b, v_b,
                                          R_bU, R_bH, R_bB2, R_bQKV);
  // Wc^T = (msg_w2 @ U1b)^T -> u1cT cols 256..511
  gemm_mfma<8, 1, 0, 1><<<dim3(4, 4), blk, 0, stream>>>(
      nullptr, msg_w2, nullptr, u1cT + 256, 256, 256, 256, 256, 512,
      upd_w1 + 65536, nullptr, nullptr);
  // Wob^T = (o_w @ br_w)^T -> brWT cols 256..511
  gemm_mfma<8, 1, 0, 1><<<dim3(4, 4), blk, 0, stream>>>(
      nullptr, o_w, nullptr, brWT + 256, 256, 256, 256, 256, 512,
      br_w, nullptr, nullptr);
  // embW = [emb; pos] @ wih^T  (nby=5: identity mapping path)
  gemm_mfma<6, 1, 0, 0><<<dim3(12, 5), blk, 0, stream>>>(
      nullptr, gru_wih, nullptr, R_embW, 320, 768, 256, 256, 768,
      nullptr, emb, pos);

  // ---- patch GRU (h bf16 recurrence; pp-LN fused into local store) ----
  unsigned short* ghB = (unsigned short*)R_b1;
  gru_pw_k<1><<<dim3(BN_ / 4), blk, 0, stream>>>(
      nullptr, gru_bhh, R_embW, x, gru_bih, pp_ln_g, pp_ln_b, R_hb, R_loc, 0);
  for (int t = 1; t < 4; ++t) {
    gemm_big<1, 0, 1><<<dim3(6, 128), blk, 0, stream>>>(
        R_hb, whhT, gru_bhh, ghB, BN_, 768, 256, 256, 768);
    gru_pw_k<0><<<dim3(BN_ / 4), blk, 0, stream>>>(
        ghB, gru_bhh, R_embW, x, gru_bih, pp_ln_g, pp_ln_b, R_hb, R_loc, t);
  }

  // summaries -> h (bf16)
  gemm_mfma<9, 0, 0, 1><<<dim3(4, 256), blk, 0, stream>>>(
      (const float*)R_loc, sumT, sum_b, R_hb, BN_, 256, 256, 256, 256,
      nullptr, nullptr, nullptr);

  // ---- message-passing rounds ----
  unsigned short* hsnB = (unsigned short*)R_b1;
  unsigned short* UB   = (unsigned short*)R_b2;
  unsigned short* Sb   = (unsigned short*)R_b3;
  for (int step = 0; step < 4; ++step) {
    gemm_big<1, 0, 1><<<dim3(4, 128), blk, 0, stream>>>(
        R_hb, W1cT, R_bH, hsnB, BN_, 512, 256, 256, 512);
    smsg_k<<<dim3(BN_ / 4), blk, 0, stream>>>(hsnB, Sb);
    gemm_mfma<10, 0, 1, 1><<<dim3(4, 256), blk, 0, stream>>>(
        (const float*)R_hb, u1cT, R_bU, UB, BN_, 256, 512, 512, 256,
        (const float*)Sb, nullptr, nullptr);
    if (step == 3) {
      // outp = hp*h2 + (1-hp)*LN(h2+upd); h not written (dead)
      gemm_ln<4><<<dim3(BN_ / 16), blk, 0, stream>>>(
          UB, u2T, upd_b2, R_hb, mp_ln_g, mp_ln_b, R_hp, R_outB);
    } else {
      gemm_ln<0><<<dim3(BN_ / 16), blk, 0, stream>>>(
          UB, u2T, upd_b2, R_hb, mp_ln_g, mp_ln_b, nullptr, nullptr);
      if (step == 2) {
        halt1_k<<<dim3(32, 16), blk, 0, stream>>>(R_hb, halt_w, R_part);
        halt2_k<<<dim3(1), dim3(64), 0, stream>>>(R_part, halt_b, R_hp);
      }
    }
  }

  // ---- sparse retrieval attention ----
  unsigned short* qkv  = (unsigned short*)R_b3;           // [BN][768] bf16 (h dead)
  unsigned short* rpre = ((unsigned short*)R_rp) + SZ_Q;  // [BN][256] bf16
  unsigned short* sc   = (unsigned short*)R_b1;           // 32x512x512 bf16
  gemm_big<1, 0, 1><<<dim3(6, 128), blk, 0, stream>>>(
      R_outB, qkvT, R_bQKV, qkv, BN_, 768, 256, 256, 768);
  scores_tri<<<dim3(1152), blk, 0, stream>>>(qkv, sc);
  topk_k<<<dim3(BN_ / 4), blk, 0, stream>>>(sc, qkv, rpre);

  // broad = [outp | rpre] @ brWT^T + biasB2  -> bf16 in R_h region
  unsigned short* broadB = (unsigned short*)R_h;
  gemm_mfma<10, 0, 0, 1><<<dim3(4, 256), blk, 0, stream>>>(
      (const float*)R_outB, brWT, R_bB2, broadB, BN_, 256, 512, 512, 256,
      (const float*)rpre, nullptr, nullptr);

  // final LN + convert -> Abuf (in b1, sc dead), head GEMM (128-tile) -> logits
  unsigned short* Abuf = (unsigned short*)R_b1;
  ln_cvt_k<<<dim3(M1_ / 4), blk, 0, stream>>>(R_loc, broadB, f_ln_g, f_ln_b, Abuf);
  gemm_big<1, 0, 0><<<dim3(2, 512), blk, 0, stream>>>(
      Abuf, headT, nullptr, logits, M1_, 256, 256, 256, 256);

  kl_k<<<dim3(1), dim3(64), 0, stream>>>(R_hp, logits + (size_t)M1_ * 256);
}